// Round 13
// baseline (1949.232 us; speedup 1.0000x reference)
//
#include <hip/hip_runtime.h>
#include <math.h>

#define H 1024
#define V 32000
#define B 256
#define S 64
#define T 10

#define GBK 32
#define NWG 256

typedef __attribute__((ext_vector_type(8))) short bf16x8;
typedef __attribute__((ext_vector_type(4))) float f32x4;

static __device__ __forceinline__ unsigned short f2bf(float f) {
  unsigned int u = __float_as_uint(f);
  u += 0x7fff + ((u >> 16) & 1);   // round-to-nearest-even
  return (unsigned short)(u >> 16);
}
static __device__ __forceinline__ float bf2f(unsigned short u) {
  return __uint_as_float(((unsigned int)u) << 16);
}
static __device__ __forceinline__ float fast_tanh(float x) {
  float e = __expf(2.f * x);
  return 1.f - 2.f * __builtin_amdgcn_rcpf(e + 1.f);
}
static __device__ __forceinline__ float fast_sigmoid(float x) {
  return __builtin_amdgcn_rcpf(1.f + __expf(-x));
}

static __device__ __forceinline__ void load_lds16(const void* g, void* l) {
  __builtin_amdgcn_global_load_lds(
      (const __attribute__((address_space(1))) unsigned int*)g,
      (__attribute__((address_space(3))) unsigned int*)l, 16, 0, 0);
}

// swizzled element offset within one LDS tile: row stride 32 elems (64 B).
static __device__ __forceinline__ int lds_off(int row, int g) {
  return row * GBK + ((g ^ ((row >> 1) & 3)) * 8);
}

// ---------------------------------------------------------------------------
// device-scope grid barrier, RELAXED-POLL version.
// Round-9 failure mode: acquire-ordered polls emit an L2 invalidate per poll
// -> continuous invalidate storm across all XCDs. Fix: relaxed spin (agent
// atomics resolve at the coherent point, no invalidate), release-store the
// generation bump (orders the cnt reset before it), ONE acquire fence after
// exit (single invalidate; needed anyway for cross-XCD data visibility).
// ---------------------------------------------------------------------------
static __device__ __forceinline__ void gbar(unsigned* cnt, unsigned* gen) {
  __syncthreads();  // all lanes done; compiler drains counters
  if (threadIdx.x == 0) {
    // release this WG's phase writes to the agent before signaling
    __builtin_amdgcn_fence(__ATOMIC_RELEASE, "agent");
    unsigned g =
        __hip_atomic_load(gen, __ATOMIC_RELAXED, __HIP_MEMORY_SCOPE_AGENT);
    unsigned a = __hip_atomic_fetch_add(cnt, 1u, __ATOMIC_RELAXED,
                                        __HIP_MEMORY_SCOPE_AGENT);
    if (a == NWG - 1) {
      __hip_atomic_store(cnt, 0u, __ATOMIC_RELAXED, __HIP_MEMORY_SCOPE_AGENT);
      // release store: cnt reset ordered before gen bump
      __hip_atomic_store(gen, g + 1, __ATOMIC_RELEASE,
                         __HIP_MEMORY_SCOPE_AGENT);
    } else {
      while (__hip_atomic_load(gen, __ATOMIC_RELAXED,
                               __HIP_MEMORY_SCOPE_AGENT) == g)
        __builtin_amdgcn_s_sleep(4);
    }
    // one acquire per barrier: invalidate stale L1/L2 for phase-data reads
    __builtin_amdgcn_fence(__ATOMIC_ACQUIRE, "agent");
  }
  __syncthreads();
}

// ---------------------------------------------------------------------------
// 64x64-tile GEMM phase body (K=H, 4 waves of 32x32, 3-stage counted pipeline)
// MODE 0: C = acc + aux[col]     MODE 2: C = acc + aux[row*ldc+col]
// ---------------------------------------------------------------------------
template <int MODE>
static __device__ void gemm64_dev(
    const unsigned short* __restrict__ A, const unsigned short* __restrict__ W,
    const float* __restrict__ aux, float* __restrict__ C, int ldc,
    int mBase, int nBase,
    unsigned short (&lsA)[3][64 * GBK], unsigned short (&lsB)[3][64 * GBK]) {
  const int tid = threadIdx.x;
  const int lane = tid & 63;
  const int w = tid >> 6;
  const int rowBase = (w >> 1) * 32;
  const int colBase = (w & 1) * 32;
  const int fr = lane & 15;
  const int fkU = lane >> 4;
  const int fg = lane >> 4;

  f32x4 acc[2][2] = {};

  auto STAGE = [&](int buf, int k0) {
    int row = tid >> 2;
    int u = tid & 3;
    int col = (u ^ ((row >> 1) & 3)) * 8;
    load_lds16(A + (size_t)(mBase + row) * H + k0 + col, &lsA[buf][tid * 8]);
    load_lds16(W + (size_t)(nBase + row) * H + k0 + col, &lsB[buf][tid * 8]);
  };

  // other phases' loads/stores share the vmcnt counter -> drain first
  asm volatile("s_waitcnt vmcnt(0)" ::: "memory");
  const int NT = H / GBK;
  STAGE(0, 0);
  STAGE(1, GBK);
  int cb = 0;
  for (int t = 0; t < NT; ++t) {
    if (t + 1 < NT) {
      asm volatile("s_waitcnt vmcnt(2)\n\ts_barrier" ::: "memory");
    } else {
      asm volatile("s_waitcnt vmcnt(0)\n\ts_barrier" ::: "memory");
    }
    if (t + 2 < NT) STAGE((cb + 2) % 3, (t + 2) * GBK);

    bf16x8 af[2], bfr[2];
#pragma unroll
    for (int m = 0; m < 2; ++m)
      af[m] = *(const bf16x8*)&lsA[cb][lds_off(rowBase + m * 16 + fr, fkU)];
#pragma unroll
    for (int n = 0; n < 2; ++n)
      bfr[n] = *(const bf16x8*)&lsB[cb][lds_off(colBase + n * 16 + fr, fkU)];
#pragma unroll
    for (int m = 0; m < 2; ++m)
#pragma unroll
      for (int n = 0; n < 2; ++n)
        acc[m][n] = __builtin_amdgcn_mfma_f32_16x16x32_bf16(
            af[m], bfr[n], acc[m][n], 0, 0, 0);
    cb = (cb + 1) % 3;
  }

#pragma unroll
  for (int m = 0; m < 2; ++m)
#pragma unroll
    for (int n = 0; n < 2; ++n) {
      const int colg = nBase + colBase + n * 16 + fr;
#pragma unroll
      for (int r = 0; r < 4; ++r) {
        const int rowg = mBase + rowBase + m * 16 + fg * 4 + r;
        float v;
        if constexpr (MODE == 2)
          v = acc[m][n][r] + aux[(size_t)rowg * ldc + colg];
        else
          v = acc[m][n][r] + aux[colg];
        C[(size_t)rowg * ldc + colg] = v;
      }
    }
}

// ---------------------------------------------------------------------------
// Persistent recurrent-loop kernel: all T steps, 4 phases/step, grid barriers.
// grid = NWG(256) x 256 threads.
// ---------------------------------------------------------------------------
__global__ __launch_bounds__(256) void decoder_loop_kernel(
    unsigned short* __restrict__ hAll,          // [(T+1), B, H] bf16
    const unsigned short* __restrict__ fusedW,  // [4H, H]
    const float* __restrict__ fusedB,           // [4H]
    const unsigned short* __restrict__ Uk_bf,   // [B,S,H]
    const unsigned short* __restrict__ keys_bf, // [B,S,H]
    const float* __restrict__ Va_w, const float* __restrict__ Va_b,
    const unsigned short* __restrict__ Wctx_bf, // [3H, H]
    const float* __restrict__ giE,              // [T,B,3H]
    const float* __restrict__ enc_hidden,       // [B,H] fp32
    float* __restrict__ hA, float* __restrict__ hB,
    float* __restrict__ wqgh,                   // [B,4H]
    unsigned short* __restrict__ ctx_bf,        // [B,H]
    float* __restrict__ gi,                     // [B,3H]
    float* __restrict__ out_attn,               // [B,T,S]
    float* __restrict__ out_h,                  // [B,H]
    unsigned* __restrict__ bar) {               // [2]: cnt, gen
  __shared__ unsigned short lsA[3][64 * GBK];   // 12 KB
  __shared__ unsigned short lsB[3][64 * GBK];   // 12 KB
  __shared__ float wqs[H];                      // 4 KB
  __shared__ float vas[H];                      // 4 KB
  __shared__ float sw[S];

  const int g = blockIdx.x;
  const int tid = threadIdx.x;
  unsigned* cnt = bar;
  unsigned* gen = bar + 1;

  for (int t = 0; t < T; ++t) {
    const unsigned short* hbf_in = hAll + (size_t)t * B * H;
    unsigned short* hbf_out = hAll + (size_t)(t + 1) * B * H;
    const float* h_in = (t == 0) ? enc_hidden : ((t & 1) ? hA : hB);
    float* h_out = (t & 1) ? hB : hA;

    // ---- Phase A: wqgh = h @ [Wa_w; w_hh]^T + [Wa_b; b_hh]  (4 x 64 tiles)
    gemm64_dev<0>(hbf_in, fusedW, fusedB, wqgh, 4 * H, (g & 3) * 64,
                  (g >> 2) * 64, lsA, lsB);
    gbar(cnt, gen);

    // ---- Phase B: attention for b = g
    {
      const int b = g;
      ((float4*)wqs)[tid] = ((const float4*)(wqgh + (size_t)b * 4 * H))[tid];
      ((float4*)vas)[tid] = ((const float4*)Va_w)[tid];
      __syncthreads();

      const int s = tid >> 2;
      const int hc = (tid & 3) * 256;
      const unsigned short* uk = Uk_bf + ((size_t)b * S + s) * H + hc;
      float sum = 0.f;
#pragma unroll 4
      for (int i = 0; i < 256; i += 8) {
        bf16x8 u = *(const bf16x8*)&uk[i];
#pragma unroll
        for (int j = 0; j < 8; ++j) {
          float e = fast_tanh(wqs[hc + i + j] + bf2f((unsigned short)u[j]));
          sum += e * vas[hc + i + j];
        }
      }
      sum += __shfl_xor(sum, 1, 64);
      sum += __shfl_xor(sum, 2, 64);
      if ((tid & 3) == 0) sw[s] = sum + Va_b[0];
      __syncthreads();

      if (tid < 64) {
        float v = sw[tid];
        float m = v;
        for (int off = 32; off > 0; off >>= 1)
          m = fmaxf(m, __shfl_xor(m, off, 64));
        float e = __expf(v - m);
        float sm = e;
        for (int off = 32; off > 0; off >>= 1) sm += __shfl_xor(sm, off, 64);
        float wv = e / sm;
        sw[tid] = wv;
        out_attn[((size_t)b * T + t) * S + tid] = wv;
      }
      __syncthreads();

      const unsigned short* kb = keys_bf + (size_t)b * S * H + tid * 4;
      float c0 = 0.f, c1 = 0.f, c2 = 0.f, c3 = 0.f;
#pragma unroll 8
      for (int s2 = 0; s2 < S; ++s2) {
        float wv = sw[s2];
        ushort4 kv = *(const ushort4*)&kb[(size_t)s2 * H];
        c0 += wv * bf2f(kv.x);
        c1 += wv * bf2f(kv.y);
        c2 += wv * bf2f(kv.z);
        c3 += wv * bf2f(kv.w);
      }
      ushort4 o;
      o.x = f2bf(c0); o.y = f2bf(c1); o.z = f2bf(c2); o.w = f2bf(c3);
      *(ushort4*)&ctx_bf[(size_t)b * H + tid * 4] = o;
    }
    gbar(cnt, gen);

    // ---- Phase C: gi = giE[t] + ctx @ Wctx^T  (4 x 48 tiles, 192 WGs)
    if (g < 192) {
      gemm64_dev<2>(ctx_bf, Wctx_bf, giE + (size_t)t * B * 3 * H, gi, 3 * H,
                    (g & 3) * 64, (g >> 2) * 64, lsA, lsB);
    }
    gbar(cnt, gen);

    // ---- Phase D: GRU combine; 4 consecutive elems per thread
    {
      const int idx = (g * 256 + tid) * 4;   // < B*H = 262144
      const int b = idx >> 10;
      const int j = idx & (H - 1);
      const float* gib = gi + (size_t)b * 3 * H;
      const float* ghb = wqgh + (size_t)b * 4 * H + H;
      float4 gr4 = *(const float4*)&gib[j];
      float4 gz4 = *(const float4*)&gib[H + j];
      float4 gn4 = *(const float4*)&gib[2 * H + j];
      float4 hr4 = *(const float4*)&ghb[j];
      float4 hz4 = *(const float4*)&ghb[H + j];
      float4 hn4 = *(const float4*)&ghb[2 * H + j];
      float4 hp4 = *(const float4*)&h_in[idx];
      float4 ho4;
      ushort4 hb4;
      {
        float r0 = fast_sigmoid(gr4.x + hr4.x);
        float z0 = fast_sigmoid(gz4.x + hz4.x);
        float n0 = fast_tanh(gn4.x + r0 * hn4.x);
        ho4.x = (1.f - z0) * n0 + z0 * hp4.x;
        float r1 = fast_sigmoid(gr4.y + hr4.y);
        float z1 = fast_sigmoid(gz4.y + hz4.y);
        float n1 = fast_tanh(gn4.y + r1 * hn4.y);
        ho4.y = (1.f - z1) * n1 + z1 * hp4.y;
        float r2 = fast_sigmoid(gr4.z + hr4.z);
        float z2 = fast_sigmoid(gz4.z + hz4.z);
        float n2 = fast_tanh(gn4.z + r2 * hn4.z);
        ho4.z = (1.f - z2) * n2 + z2 * hp4.z;
        float r3 = fast_sigmoid(gr4.w + hr4.w);
        float z3 = fast_sigmoid(gz4.w + hz4.w);
        float n3 = fast_tanh(gn4.w + r3 * hn4.w);
        ho4.w = (1.f - z3) * n3 + z3 * hp4.w;
      }
      hb4.x = f2bf(ho4.x); hb4.y = f2bf(ho4.y);
      hb4.z = f2bf(ho4.z); hb4.w = f2bf(ho4.w);
      *(float4*)&h_out[idx] = ho4;
      *(ushort4*)&hbf_out[idx] = hb4;
      if (t == T - 1) *(float4*)&out_h[idx] = ho4;
    }
    if (t != T - 1) gbar(cnt, gen);
  }
}

// ---------------------------------------------------------------------------
// bf16 MFMA GEMM (standalone), TMxTN tile, BK=32, 4 waves, STAGES pipeline.
// ---------------------------------------------------------------------------
template <int TM, int TN, int MODE, int GRIDMODE, int STAGES>
__global__ __launch_bounds__(256) void gemm_mfma(
    const unsigned short* __restrict__ A, const unsigned short* __restrict__ W,
    const float* __restrict__ aux, float* __restrict__ C,
    unsigned short* __restrict__ Cb, float* __restrict__ partials,
    int M, int N, int K, int ldc, int pstride) {
  constexpr int FM = TM / 32;
  constexpr int FN = TN / 32;
  constexpr int CA = TM / 64;
  constexpr int CB = TN / 64;
  constexpr int LOADS = CA + CB;
  constexpr int F = (STAGES >= 3) ? (STAGES - 2) : 0;

  __shared__ unsigned short lsA[STAGES][TM * GBK];
  __shared__ unsigned short lsB[STAGES][TN * GBK];
  const int tid = threadIdx.x;
  const int lane = tid & 63;
  const int w = tid >> 6;

  int mIdx, nIdx;
  if constexpr (GRIDMODE == 1) {
    const int nwg = gridDim.x * gridDim.y;
    const int orig = blockIdx.y * gridDim.x + blockIdx.x;
    const int q = nwg >> 3, rr = nwg & 7;
    const int xcd = orig & 7, rest = orig >> 3;
    const int wgid =
        (xcd < rr ? xcd * (q + 1) : rr * (q + 1) + (xcd - rr) * q) + rest;
    mIdx = wgid % gridDim.x;
    nIdx = wgid / gridDim.x;
  } else {
    mIdx = blockIdx.y;
    nIdx = blockIdx.x;
  }
  const int mBase = mIdx * TM;
  const int nBase = nIdx * TN;
  const int rowBase = (w >> 1) * (TM / 2);
  const int colBase = (w & 1) * (TN / 2);

  const int fr = lane & 15;
  const int fkU = lane >> 4;
  const int fg = lane >> 4;

  f32x4 acc[FM][FN] = {};

  auto STAGE = [&](int buf, int k0) {
#pragma unroll
    for (int i = 0; i < CA; ++i) {
      int chunk = i * 256 + tid;
      int row = chunk >> 2;
      int u = chunk & 3;
      int col = (u ^ ((row >> 1) & 3)) * 8;
      load_lds16(A + (size_t)(mBase + row) * K + k0 + col,
                 &lsA[buf][chunk * 8]);
    }
#pragma unroll
    for (int i = 0; i < CB; ++i) {
      int chunk = i * 256 + tid;
      int row = chunk >> 2;
      int u = chunk & 3;
      int col = (u ^ ((row >> 1) & 3)) * 8;
      load_lds16(W + (size_t)(nBase + row) * K + k0 + col,
                 &lsB[buf][chunk * 8]);
    }
  };

  const int NT = K / GBK;
  for (int s = 0; s <= F && s < NT; ++s) STAGE(s % STAGES, s * GBK);

  for (int t = 0; t < NT; ++t) {
    const int rem = NT - 1 - t;
    if (rem >= F) {
      asm volatile("s_waitcnt vmcnt(%0)\n\ts_barrier" :: "i"(F * LOADS)
                   : "memory");
    } else if (rem == 2) {
      asm volatile("s_waitcnt vmcnt(%0)\n\ts_barrier" :: "i"(2 * LOADS)
                   : "memory");
    } else if (rem == 1) {
      asm volatile("s_waitcnt vmcnt(%0)\n\ts_barrier" :: "i"(1 * LOADS)
                   : "memory");
    } else {
      asm volatile("s_waitcnt vmcnt(0)\n\ts_barrier" ::: "memory");
    }
    if (t + F + 1 < NT) STAGE((t + F + 1) % STAGES, (t + F + 1) * GBK);

    const int cb = t % STAGES;
    bf16x8 af[FM], bfr[FN];
#pragma unroll
    for (int m = 0; m < FM; ++m)
      af[m] = *(const bf16x8*)&lsA[cb][lds_off(rowBase + m * 16 + fr, fkU)];
#pragma unroll
    for (int n = 0; n < FN; ++n)
      bfr[n] = *(const bf16x8*)&lsB[cb][lds_off(colBase + n * 16 + fr, fkU)];
#pragma unroll
    for (int m = 0; m < FM; ++m)
#pragma unroll
      for (int n = 0; n < FN; ++n)
        acc[m][n] = __builtin_amdgcn_mfma_f32_16x16x32_bf16(
            af[m], bfr[n], acc[m][n], 0, 0, 0);
  }

#pragma unroll
  for (int m = 0; m < FM; ++m) {
    int colg[FN];
    float bv[FN];
#pragma unroll
    for (int n = 0; n < FN; ++n) {
      colg[n] = nBase + colBase + n * 16 + fr;
      if constexpr (MODE != 2) bv[n] = aux[colg[n]];
    }
#pragma unroll
    for (int r = 0; r < 4; ++r) {
      const int rowg = mBase + rowBase + m * 16 + fg * 4 + r;
      float v[FN];
#pragma unroll
      for (int n = 0; n < FN; ++n) {
        if constexpr (MODE == 2)
          v[n] = acc[m][n][r] + aux[(size_t)rowg * ldc + colg[n]];
        else
          v[n] = acc[m][n][r] + bv[n];
        if constexpr (MODE == 1 || MODE == 3)
          Cb[(size_t)rowg * ldc + colg[n]] = f2bf(v[n]);
        else
          C[(size_t)rowg * ldc + colg[n]] = v[n];
      }
      if constexpr (MODE == 3) {
        float mx = fmaxf(fmaxf(v[0], v[1]), fmaxf(v[2], v[3]));
        mx = fmaxf(mx, __shfl_xor(mx, 1, 64));
        mx = fmaxf(mx, __shfl_xor(mx, 2, 64));
        mx = fmaxf(mx, __shfl_xor(mx, 4, 64));
        mx = fmaxf(mx, __shfl_xor(mx, 8, 64));
        float se = __expf(v[0] - mx) + __expf(v[1] - mx) +
                   __expf(v[2] - mx) + __expf(v[3] - mx);
        se += __shfl_xor(se, 1, 64);
        se += __shfl_xor(se, 2, 64);
        se += __shfl_xor(se, 4, 64);
        se += __shfl_xor(se, 8, 64);
        if (fr == 0) {
          float2* pp = (float2*)partials;
          pp[(size_t)rowg * pstride + nIdx * 2 + (w & 1)] =
              make_float2(mx, se);
        }
      }
    }
  }
}

// ---------------------------------------------------------------------------
__global__ __launch_bounds__(256) void cvt_bf16_kernel(
    const float* __restrict__ src, unsigned short* __restrict__ dst) {
  size_t i = ((size_t)blockIdx.x * 256 + threadIdx.x) * 8;
  float4 a = *(const float4*)&src[i];
  float4 b = *(const float4*)&src[i + 4];
  ushort4 lo, hi;
  lo.x = f2bf(a.x); lo.y = f2bf(a.y); lo.z = f2bf(a.z); lo.w = f2bf(a.w);
  hi.x = f2bf(b.x); hi.y = f2bf(b.y); hi.z = f2bf(b.z); hi.w = f2bf(b.w);
  *(ushort4*)&dst[i] = lo;
  *(ushort4*)&dst[i + 4] = hi;
}

__global__ __launch_bounds__(256) void cvt_split_wih(
    const float* __restrict__ w_ih, unsigned short* __restrict__ Wemb,
    unsigned short* __restrict__ Wctx) {
  size_t base = ((size_t)blockIdx.x * 256 + threadIdx.x) * 8;
  int row = (int)(base >> 11);
  int col = (int)(base & 2047);
  float4 a = *(const float4*)&w_ih[base];
  float4 b = *(const float4*)&w_ih[base + 4];
  ushort4 lo, hi;
  lo.x = f2bf(a.x); lo.y = f2bf(a.y); lo.z = f2bf(a.z); lo.w = f2bf(a.w);
  hi.x = f2bf(b.x); hi.y = f2bf(b.y); hi.z = f2bf(b.z); hi.w = f2bf(b.w);
  unsigned short* dst = (col < H) ? (Wemb + (size_t)row * H + col)
                                  : (Wctx + (size_t)row * H + col - H);
  *(ushort4*)dst = lo;
  *(ushort4*)(dst + 4) = hi;
}

__global__ __launch_bounds__(256) void build_fused_bias(
    const float* __restrict__ Wa_b, const float* __restrict__ b_hh,
    float* __restrict__ fb) {
  int i = blockIdx.x * 256 + threadIdx.x;
  fb[i] = (i < H) ? Wa_b[i] : b_hh[i - H];
}

__global__ __launch_bounds__(256) void embed_all_kernel(
    const int* __restrict__ target, const float* __restrict__ emb,
    unsigned short* __restrict__ embAll) {
  int idx = blockIdx.x * 256 + threadIdx.x;  // over T*B*(H/8)
  int h8 = (idx & 127) * 8;
  int tb = idx >> 7;
  int t = tb >> 8;
  int b = tb & 255;
  int tok = (t == 0) ? 0 : target[b * T + (t - 1)];
  const float* e = emb + (size_t)tok * H + h8;
  float4 a = *(const float4*)e;
  float4 c = *(const float4*)(e + 4);
  ushort4 lo, hi;
  lo.x = f2bf(a.x); lo.y = f2bf(a.y); lo.z = f2bf(a.z); lo.w = f2bf(a.w);
  hi.x = f2bf(c.x); hi.y = f2bf(c.y); hi.z = f2bf(c.z); hi.w = f2bf(c.w);
  unsigned short* d = embAll + (size_t)tb * H + h8;
  *(ushort4*)d = lo;
  *(ushort4*)(d + 4) = hi;
}

// ---------------------------------------------------------------------------
__global__ __launch_bounds__(256) void logsm_reduce_kernel(
    const float* __restrict__ partials, float* __restrict__ ls, int P) {
  const int row = blockIdx.x;
  const int tid = threadIdx.x;
  const float2* pp = (const float2*)partials + (size_t)row * P;
  __shared__ float red[256];
  float mx = -INFINITY;
  for (int i = tid; i < P; i += 256) mx = fmaxf(mx, pp[i].x);
  red[tid] = mx;
  __syncthreads();
  for (int off = 128; off > 0; off >>= 1) {
    if (tid < off) red[tid] = fmaxf(red[tid], red[tid + off]);
    __syncthreads();
  }
  mx = red[0];
  __syncthreads();
  float sm = 0.f;
  for (int i = tid; i < P; i += 256) sm += pp[i].y * __expf(pp[i].x - mx);
  red[tid] = sm;
  __syncthreads();
  for (int off = 128; off > 0; off >>= 1) {
    if (tid < off) red[tid] += red[tid + off];
    __syncthreads();
  }
  if (tid == 0) ls[row] = mx + __logf(red[0]);
}

// dec[b, t, :] = bf2f(logits_bf[tb, :]) - ls[tb];  tb = t*B + b
__global__ __launch_bounds__(256) void logsm_sub_kernel(
    const unsigned short* __restrict__ logits_bf, const float* __restrict__ ls,
    float* __restrict__ dec) {
  const int tb = blockIdx.y;
  const int t = tb >> 8;         // B = 256
  const int b = tb & 255;
  const int i8 = (blockIdx.x * 256 + threadIdx.x) * 8;
  if (i8 < V) {
    float l = ls[tb];
    const unsigned short* src = logits_bf + (size_t)tb * V + i8;
    bf16x8 u = *(const bf16x8*)src;
    float* d = dec + (size_t)b * T * V + (size_t)t * V + i8;
    float4 o0, o1;
    o0.x = bf2f((unsigned short)u[0]) - l; o0.y = bf2f((unsigned short)u[1]) - l;
    o0.z = bf2f((unsigned short)u[2]) - l; o0.w = bf2f((unsigned short)u[3]) - l;
    o1.x = bf2f((unsigned short)u[4]) - l; o1.y = bf2f((unsigned short)u[5]) - l;
    o1.z = bf2f((unsigned short)u[6]) - l; o1.w = bf2f((unsigned short)u[7]) - l;
    *(float4*)d = o0;
    *(float4*)(d + 4) = o1;
  }
}

// ---------------------------------------------------------------------------
extern "C" void kernel_launch(void* const* d_in, const int* in_sizes, int n_in,
                              void* d_out, int out_size, void* d_ws, size_t ws_size,
                              hipStream_t stream) {
  const float* keys       = (const float*)d_in[0];
  const float* enc_hidden = (const float*)d_in[1];
  const int*   target     = (const int*)d_in[2];
  const float* embedding  = (const float*)d_in[3];
  const float* Wa_w = (const float*)d_in[4];
  const float* Wa_b = (const float*)d_in[5];
  const float* Ua_w = (const float*)d_in[6];
  const float* Ua_b = (const float*)d_in[7];
  const float* Va_w = (const float*)d_in[8];
  const float* Va_b = (const float*)d_in[9];
  const float* gru_w_ih = (const float*)d_in[10];
  const float* gru_w_hh = (const float*)d_in[11];
  const float* gru_b_ih = (const float*)d_in[12];
  const float* gru_b_hh = (const float*)d_in[13];
  const float* out_w = (const float*)d_in[14];
  const float* out_b = (const float*)d_in[15];

  float* out = (float*)d_out;
  float* out_dec  = out;
  float* out_h    = out + (size_t)B * T * V;
  float* out_attn = out + (size_t)B * T * V + (size_t)B * H;

  // ---- workspace ----
  char* p = (char*)d_ws;
  unsigned short* keys_bf = (unsigned short*)p; p += (size_t)B * S * H * 2;
  unsigned short* outw_bf = (unsigned short*)p; p += (size_t)V * H * 2;
  unsigned short* Uaw_bf  = (unsigned short*)p; p += (size_t)H * H * 2;
  unsigned short* fusedW  = (unsigned short*)p; p += (size_t)4 * H * H * 2;
  float*          fusedB  = (float*)p;          p += (size_t)4 * H * 4;
  unsigned short* Wemb_bf = (unsigned short*)p; p += (size_t)3 * H * H * 2;
  unsigned short* Wctx_bf = (unsigned short*)p; p += (size_t)3 * H * H * 2;
  unsigned short* embAll  = (unsigned short*)p; p += (size_t)T * B * H * 2;
  unsigned short* Uk_bf   = (unsigned short*)p; p += (size_t)B * S * H * 2;
  float*          giE     = (float*)p;          p += (size_t)T * B * 3 * H * 4;
  float*          wqgh    = (float*)p;          p += (size_t)B * 4 * H * 4;
  unsigned short* ctx_bf  = (unsigned short*)p; p += (size_t)B * H * 2;
  float*          gi      = (float*)p;          p += (size_t)B * 3 * H * 4;
  float*          hA      = (float*)p;          p += (size_t)B * H * 4;
  float*          hB      = (float*)p;          p += (size_t)B * H * 4;
  unsigned short* hAll    = (unsigned short*)p; p += (size_t)(T + 1) * B * H * 2;
  unsigned short* logits_bf = (unsigned short*)p; p += (size_t)T * B * V * 2;
  float*          parts   = (float*)p;          p += (size_t)T * B * 500 * 2 * 4;
  float*          ls      = (float*)p;          p += (size_t)T * B * 4;
  unsigned*       barrier = (unsigned*)p;       p += 256;

  // barrier state must be zero at kernel start (deterministic per call)
  (void)hipMemsetAsync(barrier, 0, 256, stream);

  // ---- one-time prep ----
  cvt_bf16_kernel<<<(B * S * H) / 2048, 256, 0, stream>>>(keys, keys_bf);
  cvt_bf16_kernel<<<((size_t)V * H) / 2048, 256, 0, stream>>>(out_w, outw_bf);
  cvt_bf16_kernel<<<(H * H) / 2048, 256, 0, stream>>>(Ua_w, Uaw_bf);
  cvt_bf16_kernel<<<(H * H) / 2048, 256, 0, stream>>>(Wa_w, fusedW);
  cvt_bf16_kernel<<<(3 * H * H) / 2048, 256, 0, stream>>>(gru_w_hh,
                                                          fusedW + (size_t)H * H);
  build_fused_bias<<<(4 * H) / 256, 256, 0, stream>>>(Wa_b, gru_b_hh, fusedB);
  cvt_split_wih<<<(3 * H * 2 * H) / 2048, 256, 0, stream>>>(gru_w_ih, Wemb_bf,
                                                            Wctx_bf);
  embed_all_kernel<<<(T * B * H / 8) / 256, 256, 0, stream>>>(target, embedding,
                                                              embAll);
  cvt_bf16_kernel<<<(B * H) / 2048, 256, 0, stream>>>(enc_hidden, hAll);

  // Uk_bf = bf16(keys @ Ua_w^T + Ua_b)
  gemm_mfma<128, 128, 1, 0, 2>
      <<<dim3(H / 128, (B * S) / 128), 256, 0, stream>>>(
          keys_bf, Uaw_bf, Ua_b, nullptr, Uk_bf, nullptr, B * S, H, H, H, 0);
  // giE = embAll @ Wemb^T + b_ih
  gemm_mfma<128, 128, 0, 1, 2>
      <<<dim3((T * B) / 128, 3 * H / 128), 256, 0, stream>>>(
          embAll, Wemb_bf, gru_b_ih, giE, nullptr, nullptr, T * B, 3 * H, H,
          3 * H, 0);

  // ---- the entire recurrent loop: one persistent kernel ----
  decoder_loop_kernel<<<NWG, 256, 0, stream>>>(
      hAll, fusedW, fusedB, Uk_bf, keys_bf, Va_w, Va_b, Wctx_bf, giE,
      enc_hidden, hA, hB, wqgh, ctx_bf, gi, out_attn, out_h, barrier);

  // batched vocab projection over all steps: A rows tb = t*B + b -> h_{t+1}
  gemm_mfma<128, 128, 3, 1, 2>
      <<<dim3((T * B) / 128, V / 128), 256, 0, stream>>>(
          hAll + (size_t)B * H, outw_bf, out_b, nullptr, logits_bf, parts,
          T * B, V, H, V, 500);
  logsm_reduce_kernel<<<T * B, 256, 0, stream>>>(parts, ls, 500);
  logsm_sub_kernel<<<dim3((V + 2047) / 2048, T * B), 256, 0, stream>>>(
      logits_bf, ls, out_dec);
}

// Round 14
// 1076.204 us; speedup vs baseline: 1.8112x; 1.8112x over previous
//
#include <hip/hip_runtime.h>
#include <math.h>

#define H 1024
#define V 32000
#define B 256
#define S 64
#define T 10

#define GBK 32

typedef __attribute__((ext_vector_type(8))) short bf16x8;
typedef __attribute__((ext_vector_type(4))) float f32x4;

static __device__ __forceinline__ unsigned short f2bf(float f) {
  unsigned int u = __float_as_uint(f);
  u += 0x7fff + ((u >> 16) & 1);   // round-to-nearest-even
  return (unsigned short)(u >> 16);
}
static __device__ __forceinline__ float bf2f(unsigned short u) {
  return __uint_as_float(((unsigned int)u) << 16);
}
static __device__ __forceinline__ float fast_tanh(float x) {
  float e = __expf(2.f * x);
  return 1.f - 2.f * __builtin_amdgcn_rcpf(e + 1.f);
}
static __device__ __forceinline__ float fast_sigmoid(float x) {
  return __builtin_amdgcn_rcpf(1.f + __expf(-x));
}

static __device__ __forceinline__ void load_lds16(const void* g, void* l) {
  __builtin_amdgcn_global_load_lds(
      (const __attribute__((address_space(1))) unsigned int*)g,
      (__attribute__((address_space(3))) unsigned int*)l, 16, 0, 0);
}

// swizzled element offset within one LDS tile: row stride 32 elems (64 B).
static __device__ __forceinline__ int lds_off(int row, int g) {
  return row * GBK + ((g ^ ((row >> 1) & 3)) * 8);
}

// ---------------------------------------------------------------------------
// bf16 MFMA GEMM, TMxTN tile, BK=32, 4 waves (2x2), STAGES-deep pipeline with
// counted vmcnt + raw barrier.  C = A @ W^T (+ epilogue).
// F = STAGES-2 stages stay in flight across barriers (F=0 for STAGES=2).
// GRIDMODE 0: grid (N/TN, M/TM).
// GRIDMODE 1: grid (M/TM, N/TN) + bijective XCD swizzle (m204).
// MODE 0: C fp32 = acc + bias[col]
// MODE 1: Cb bf16 = acc + bias[col]
// MODE 2: C fp32 = acc + aux[row*ldc + col]
// MODE 3: Cb bf16 = acc + bias[col]; per-row (max,sumexp) partials ->
//         partials[row][nIdx*2 + (w&1)]                (TN=128 only)
// ---------------------------------------------------------------------------
template <int TM, int TN, int MODE, int GRIDMODE, int STAGES>
__global__ __launch_bounds__(256) void gemm_mfma(
    const unsigned short* __restrict__ A, const unsigned short* __restrict__ W,
    const float* __restrict__ aux, float* __restrict__ C,
    unsigned short* __restrict__ Cb, float* __restrict__ partials,
    int M, int N, int K, int ldc, int pstride) {
  constexpr int FM = TM / 32;
  constexpr int FN = TN / 32;
  constexpr int CA = TM / 64;
  constexpr int CB = TN / 64;
  constexpr int LOADS = CA + CB;
  constexpr int F = (STAGES >= 3) ? (STAGES - 2) : 0;

  __shared__ unsigned short lsA[STAGES][TM * GBK];
  __shared__ unsigned short lsB[STAGES][TN * GBK];
  const int tid = threadIdx.x;
  const int lane = tid & 63;
  const int w = tid >> 6;

  int mIdx, nIdx;
  if constexpr (GRIDMODE == 1) {
    const int nwg = gridDim.x * gridDim.y;
    const int orig = blockIdx.y * gridDim.x + blockIdx.x;
    const int q = nwg >> 3, rr = nwg & 7;
    const int xcd = orig & 7, rest = orig >> 3;
    const int wgid =
        (xcd < rr ? xcd * (q + 1) : rr * (q + 1) + (xcd - rr) * q) + rest;
    mIdx = wgid % gridDim.x;
    nIdx = wgid / gridDim.x;
  } else {
    mIdx = blockIdx.y;
    nIdx = blockIdx.x;
  }
  const int mBase = mIdx * TM;
  const int nBase = nIdx * TN;
  const int rowBase = (w >> 1) * (TM / 2);
  const int colBase = (w & 1) * (TN / 2);

  const int fr = lane & 15;
  const int fkU = lane >> 4;
  const int fg = lane >> 4;

  f32x4 acc[FM][FN] = {};

  auto STAGE = [&](int buf, int k0) {
#pragma unroll
    for (int i = 0; i < CA; ++i) {
      int chunk = i * 256 + tid;
      int row = chunk >> 2;
      int u = chunk & 3;
      int col = (u ^ ((row >> 1) & 3)) * 8;
      load_lds16(A + (size_t)(mBase + row) * K + k0 + col,
                 &lsA[buf][chunk * 8]);
    }
#pragma unroll
    for (int i = 0; i < CB; ++i) {
      int chunk = i * 256 + tid;
      int row = chunk >> 2;
      int u = chunk & 3;
      int col = (u ^ ((row >> 1) & 3)) * 8;
      load_lds16(W + (size_t)(nBase + row) * K + k0 + col,
                 &lsB[buf][chunk * 8]);
    }
  };

  const int NT = K / GBK;
  for (int s = 0; s <= F && s < NT; ++s) STAGE(s % STAGES, s * GBK);

  for (int t = 0; t < NT; ++t) {
    const int rem = NT - 1 - t;
    if (rem >= F) {
      asm volatile("s_waitcnt vmcnt(%0)\n\ts_barrier" :: "i"(F * LOADS)
                   : "memory");
    } else if (rem == 2) {
      asm volatile("s_waitcnt vmcnt(%0)\n\ts_barrier" :: "i"(2 * LOADS)
                   : "memory");
    } else if (rem == 1) {
      asm volatile("s_waitcnt vmcnt(%0)\n\ts_barrier" :: "i"(1 * LOADS)
                   : "memory");
    } else {
      asm volatile("s_waitcnt vmcnt(0)\n\ts_barrier" ::: "memory");
    }
    if (t + F + 1 < NT) STAGE((t + F + 1) % STAGES, (t + F + 1) * GBK);

    const int cb = t % STAGES;
    bf16x8 af[FM], bfr[FN];
#pragma unroll
    for (int m = 0; m < FM; ++m)
      af[m] = *(const bf16x8*)&lsA[cb][lds_off(rowBase + m * 16 + fr, fkU)];
#pragma unroll
    for (int n = 0; n < FN; ++n)
      bfr[n] = *(const bf16x8*)&lsB[cb][lds_off(colBase + n * 16 + fr, fkU)];
#pragma unroll
    for (int m = 0; m < FM; ++m)
#pragma unroll
      for (int n = 0; n < FN; ++n)
        acc[m][n] = __builtin_amdgcn_mfma_f32_16x16x32_bf16(
            af[m], bfr[n], acc[m][n], 0, 0, 0);
  }

#pragma unroll
  for (int m = 0; m < FM; ++m) {
    int colg[FN];
    float bv[FN];
#pragma unroll
    for (int n = 0; n < FN; ++n) {
      colg[n] = nBase + colBase + n * 16 + fr;
      if constexpr (MODE != 2) bv[n] = aux[colg[n]];
    }
#pragma unroll
    for (int r = 0; r < 4; ++r) {
      const int rowg = mBase + rowBase + m * 16 + fg * 4 + r;
      float v[FN];
#pragma unroll
      for (int n = 0; n < FN; ++n) {
        if constexpr (MODE == 2)
          v[n] = acc[m][n][r] + aux[(size_t)rowg * ldc + colg[n]];
        else
          v[n] = acc[m][n][r] + bv[n];
        if constexpr (MODE == 1 || MODE == 3)
          Cb[(size_t)rowg * ldc + colg[n]] = f2bf(v[n]);
        else
          C[(size_t)rowg * ldc + colg[n]] = v[n];
      }
      if constexpr (MODE == 3) {
        float mx = fmaxf(fmaxf(v[0], v[1]), fmaxf(v[2], v[3]));
        mx = fmaxf(mx, __shfl_xor(mx, 1, 64));
        mx = fmaxf(mx, __shfl_xor(mx, 2, 64));
        mx = fmaxf(mx, __shfl_xor(mx, 4, 64));
        mx = fmaxf(mx, __shfl_xor(mx, 8, 64));
        float se = __expf(v[0] - mx) + __expf(v[1] - mx) +
                   __expf(v[2] - mx) + __expf(v[3] - mx);
        se += __shfl_xor(se, 1, 64);
        se += __shfl_xor(se, 2, 64);
        se += __shfl_xor(se, 4, 64);
        se += __shfl_xor(se, 8, 64);
        if (fr == 0) {
          float2* pp = (float2*)partials;
          pp[(size_t)rowg * pstride + nIdx * 2 + (w & 1)] =
              make_float2(mx, se);
        }
      }
    }
  }
}

// ---------------------------------------------------------------------------
__global__ __launch_bounds__(256) void cvt_bf16_kernel(
    const float* __restrict__ src, unsigned short* __restrict__ dst) {
  size_t i = ((size_t)blockIdx.x * 256 + threadIdx.x) * 8;
  float4 a = *(const float4*)&src[i];
  float4 b = *(const float4*)&src[i + 4];
  ushort4 lo, hi;
  lo.x = f2bf(a.x); lo.y = f2bf(a.y); lo.z = f2bf(a.z); lo.w = f2bf(a.w);
  hi.x = f2bf(b.x); hi.y = f2bf(b.y); hi.z = f2bf(b.z); hi.w = f2bf(b.w);
  *(ushort4*)&dst[i] = lo;
  *(ushort4*)&dst[i + 4] = hi;
}

__global__ __launch_bounds__(256) void cvt_split_wih(
    const float* __restrict__ w_ih, unsigned short* __restrict__ Wemb,
    unsigned short* __restrict__ Wctx) {
  size_t base = ((size_t)blockIdx.x * 256 + threadIdx.x) * 8;
  int row = (int)(base >> 11);
  int col = (int)(base & 2047);
  float4 a = *(const float4*)&w_ih[base];
  float4 b = *(const float4*)&w_ih[base + 4];
  ushort4 lo, hi;
  lo.x = f2bf(a.x); lo.y = f2bf(a.y); lo.z = f2bf(a.z); lo.w = f2bf(a.w);
  hi.x = f2bf(b.x); hi.y = f2bf(b.y); hi.z = f2bf(b.z); hi.w = f2bf(b.w);
  unsigned short* dst = (col < H) ? (Wemb + (size_t)row * H + col)
                                  : (Wctx + (size_t)row * H + col - H);
  *(ushort4*)dst = lo;
  *(ushort4*)(dst + 4) = hi;
}

__global__ __launch_bounds__(256) void build_fused_bias(
    const float* __restrict__ Wa_b, const float* __restrict__ b_hh,
    float* __restrict__ fb) {
  int i = blockIdx.x * 256 + threadIdx.x;
  fb[i] = (i < H) ? Wa_b[i] : b_hh[i - H];
}

__global__ __launch_bounds__(256) void embed_all_kernel(
    const int* __restrict__ target, const float* __restrict__ emb,
    unsigned short* __restrict__ embAll) {
  int idx = blockIdx.x * 256 + threadIdx.x;  // over T*B*(H/8)
  int h8 = (idx & 127) * 8;
  int tb = idx >> 7;
  int t = tb >> 8;
  int b = tb & 255;
  int tok = (t == 0) ? 0 : target[b * T + (t - 1)];
  const float* e = emb + (size_t)tok * H + h8;
  float4 a = *(const float4*)e;
  float4 c = *(const float4*)(e + 4);
  ushort4 lo, hi;
  lo.x = f2bf(a.x); lo.y = f2bf(a.y); lo.z = f2bf(a.z); lo.w = f2bf(a.w);
  hi.x = f2bf(c.x); hi.y = f2bf(c.y); hi.z = f2bf(c.z); hi.w = f2bf(c.w);
  unsigned short* d = embAll + (size_t)tb * H + h8;
  *(ushort4*)d = lo;
  *(ushort4*)(d + 4) = hi;
}

// ---------------------------------------------------------------------------
// Fused attention: scores -> softmax -> ctx, one block per b.
// ---------------------------------------------------------------------------
__global__ __launch_bounds__(256) void attn_fused_kernel(
    const float* __restrict__ wqgh, const unsigned short* __restrict__ Uk_bf,
    const unsigned short* __restrict__ keys_bf,
    const float* __restrict__ Va_w, const float* __restrict__ Va_b,
    float* __restrict__ out_attn, unsigned short* __restrict__ ctx_bf, int t) {
  const int b = blockIdx.x;
  const int tid = threadIdx.x;
  __shared__ float wqs[H];
  __shared__ float vas[H];
  __shared__ float sw[S];

  ((float4*)wqs)[tid] = ((const float4*)(wqgh + (size_t)b * 4 * H))[tid];
  ((float4*)vas)[tid] = ((const float4*)Va_w)[tid];
  __syncthreads();

  const int s = tid >> 2;
  const int hc = (tid & 3) * 256;
  const unsigned short* uk = Uk_bf + ((size_t)b * S + s) * H + hc;
  float sum = 0.f;
#pragma unroll 4
  for (int i = 0; i < 256; i += 8) {
    bf16x8 u = *(const bf16x8*)&uk[i];
#pragma unroll
    for (int j = 0; j < 8; ++j) {
      float e = fast_tanh(wqs[hc + i + j] + bf2f((unsigned short)u[j]));
      sum += e * vas[hc + i + j];
    }
  }
  sum += __shfl_xor(sum, 1, 64);
  sum += __shfl_xor(sum, 2, 64);
  if ((tid & 3) == 0) sw[s] = sum + Va_b[0];
  __syncthreads();

  if (tid < 64) {
    float v = sw[tid];
    float m = v;
    for (int off = 32; off > 0; off >>= 1) m = fmaxf(m, __shfl_xor(m, off, 64));
    float e = __expf(v - m);
    float sm = e;
    for (int off = 32; off > 0; off >>= 1) sm += __shfl_xor(sm, off, 64);
    float wv = e / sm;
    sw[tid] = wv;
    out_attn[((size_t)b * T + t) * S + tid] = wv;
  }
  __syncthreads();

  const unsigned short* kb = keys_bf + (size_t)b * S * H + tid * 4;
  float c0 = 0.f, c1 = 0.f, c2 = 0.f, c3 = 0.f;
#pragma unroll 8
  for (int s2 = 0; s2 < S; ++s2) {
    float wv = sw[s2];
    ushort4 kv = *(const ushort4*)&kb[(size_t)s2 * H];
    c0 += wv * bf2f(kv.x);
    c1 += wv * bf2f(kv.y);
    c2 += wv * bf2f(kv.z);
    c3 += wv * bf2f(kv.w);
  }
  ushort4 o;
  o.x = f2bf(c0); o.y = f2bf(c1); o.z = f2bf(c2); o.w = f2bf(c3);
  *(ushort4*)&ctx_bf[(size_t)b * H + tid * 4] = o;
}

// ---------------------------------------------------------------------------
__global__ __launch_bounds__(256) void gru_kernel(
    const float* __restrict__ gi, const float* __restrict__ wqgh,
    const float* __restrict__ h_in, float* __restrict__ h_out,
    unsigned short* __restrict__ h_out_bf) {
  int idx = blockIdx.x * 256 + threadIdx.x;
  int b = idx >> 10;
  int j = idx & (H - 1);
  const float* gib = gi + (size_t)b * 3 * H;
  const float* ghb = wqgh + (size_t)b * 4 * H + H;
  float r = fast_sigmoid(gib[j] + ghb[j]);
  float z = fast_sigmoid(gib[H + j] + ghb[H + j]);
  float n = fast_tanh(gib[2 * H + j] + r * ghb[2 * H + j]);
  float hp = h_in[idx];
  float ho = (1.f - z) * n + z * hp;
  h_out[idx] = ho;
  h_out_bf[idx] = f2bf(ho);
}

// ---------------------------------------------------------------------------
// batched log-softmax: reduce partials -> ls[row] for all T*B rows
// ---------------------------------------------------------------------------
__global__ __launch_bounds__(256) void logsm_reduce_kernel(
    const float* __restrict__ partials, float* __restrict__ ls, int P) {
  const int row = blockIdx.x;
  const int tid = threadIdx.x;
  const float2* pp = (const float2*)partials + (size_t)row * P;
  __shared__ float red[256];
  float mx = -INFINITY;
  for (int i = tid; i < P; i += 256) mx = fmaxf(mx, pp[i].x);
  red[tid] = mx;
  __syncthreads();
  for (int off = 128; off > 0; off >>= 1) {
    if (tid < off) red[tid] = fmaxf(red[tid], red[tid + off]);
    __syncthreads();
  }
  mx = red[0];
  __syncthreads();
  float sm = 0.f;
  for (int i = tid; i < P; i += 256) sm += pp[i].y * __expf(pp[i].x - mx);
  red[tid] = sm;
  __syncthreads();
  for (int off = 128; off > 0; off >>= 1) {
    if (tid < off) red[tid] += red[tid + off];
    __syncthreads();
  }
  if (tid == 0) ls[row] = mx + __logf(red[0]);
}

// dec[b, t, :] = bf2f(logits_bf[tb, :]) - ls[tb];  tb = t*B + b
__global__ __launch_bounds__(256) void logsm_sub_kernel(
    const unsigned short* __restrict__ logits_bf, const float* __restrict__ ls,
    float* __restrict__ dec) {
  const int tb = blockIdx.y;
  const int t = tb >> 8;         // B = 256
  const int b = tb & 255;
  const int i8 = (blockIdx.x * 256 + threadIdx.x) * 8;
  if (i8 < V) {
    float l = ls[tb];
    const unsigned short* src = logits_bf + (size_t)tb * V + i8;
    bf16x8 u = *(const bf16x8*)src;
    float* d = dec + (size_t)b * T * V + (size_t)t * V + i8;
    float4 o0, o1;
    o0.x = bf2f((unsigned short)u[0]) - l; o0.y = bf2f((unsigned short)u[1]) - l;
    o0.z = bf2f((unsigned short)u[2]) - l; o0.w = bf2f((unsigned short)u[3]) - l;
    o1.x = bf2f((unsigned short)u[4]) - l; o1.y = bf2f((unsigned short)u[5]) - l;
    o1.z = bf2f((unsigned short)u[6]) - l; o1.w = bf2f((unsigned short)u[7]) - l;
    *(float4*)d = o0;
    *(float4*)(d + 4) = o1;
  }
}

__global__ __launch_bounds__(256) void copy_kernel(
    const float* __restrict__ src, float* __restrict__ dst, int n) {
  int i = blockIdx.x * 256 + threadIdx.x;
  if (i < n) dst[i] = src[i];
}

// ---------------------------------------------------------------------------
extern "C" void kernel_launch(void* const* d_in, const int* in_sizes, int n_in,
                              void* d_out, int out_size, void* d_ws, size_t ws_size,
                              hipStream_t stream) {
  const float* keys       = (const float*)d_in[0];
  const float* enc_hidden = (const float*)d_in[1];
  const int*   target     = (const int*)d_in[2];
  const float* embedding  = (const float*)d_in[3];
  const float* Wa_w = (const float*)d_in[4];
  const float* Wa_b = (const float*)d_in[5];
  const float* Ua_w = (const float*)d_in[6];
  const float* Ua_b = (const float*)d_in[7];
  const float* Va_w = (const float*)d_in[8];
  const float* Va_b = (const float*)d_in[9];
  const float* gru_w_ih = (const float*)d_in[10];
  const float* gru_w_hh = (const float*)d_in[11];
  const float* gru_b_ih = (const float*)d_in[12];
  const float* gru_b_hh = (const float*)d_in[13];
  const float* out_w = (const float*)d_in[14];
  const float* out_b = (const float*)d_in[15];

  float* out = (float*)d_out;
  float* out_dec  = out;
  float* out_h    = out + (size_t)B * T * V;
  float* out_attn = out + (size_t)B * T * V + (size_t)B * H;

  // ---- workspace ----
  char* p = (char*)d_ws;
  unsigned short* keys_bf = (unsigned short*)p; p += (size_t)B * S * H * 2;
  unsigned short* outw_bf = (unsigned short*)p; p += (size_t)V * H * 2;
  unsigned short* Uaw_bf  = (unsigned short*)p; p += (size_t)H * H * 2;
  unsigned short* fusedW  = (unsigned short*)p; p += (size_t)4 * H * H * 2;
  float*          fusedB  = (float*)p;          p += (size_t)4 * H * 4;
  unsigned short* Wemb_bf = (unsigned short*)p; p += (size_t)3 * H * H * 2;
  unsigned short* Wctx_bf = (unsigned short*)p; p += (size_t)3 * H * H * 2;
  unsigned short* embAll  = (unsigned short*)p; p += (size_t)T * B * H * 2;
  unsigned short* Uk_bf   = (unsigned short*)p; p += (size_t)B * S * H * 2;
  float*          giE     = (float*)p;          p += (size_t)T * B * 3 * H * 4;
  float*          wqgh    = (float*)p;          p += (size_t)B * 4 * H * 4;
  unsigned short* ctx_bf  = (unsigned short*)p; p += (size_t)B * H * 2;
  float*          gi      = (float*)p;          p += (size_t)B * 3 * H * 4;
  float*          hA      = (float*)p;          p += (size_t)B * H * 4;
  float*          hB      = (float*)p;          p += (size_t)B * H * 4;
  unsigned short* hAll    = (unsigned short*)p; p += (size_t)(T + 1) * B * H * 2;
  unsigned short* logits_bf = (unsigned short*)p; p += (size_t)T * B * V * 2;
  float*          parts   = (float*)p;          p += (size_t)T * B * 500 * 2 * 4;
  float*          ls      = (float*)p;          p += (size_t)T * B * 4;

  // ---- one-time prep ----
  cvt_bf16_kernel<<<(B * S * H) / 2048, 256, 0, stream>>>(keys, keys_bf);
  cvt_bf16_kernel<<<((size_t)V * H) / 2048, 256, 0, stream>>>(out_w, outw_bf);
  cvt_bf16_kernel<<<(H * H) / 2048, 256, 0, stream>>>(Ua_w, Uaw_bf);
  cvt_bf16_kernel<<<(H * H) / 2048, 256, 0, stream>>>(Wa_w, fusedW);
  cvt_bf16_kernel<<<(3 * H * H) / 2048, 256, 0, stream>>>(gru_w_hh,
                                                          fusedW + (size_t)H * H);
  build_fused_bias<<<(4 * H) / 256, 256, 0, stream>>>(Wa_b, gru_b_hh, fusedB);
  cvt_split_wih<<<(3 * H * 2 * H) / 2048, 256, 0, stream>>>(gru_w_ih, Wemb_bf,
                                                            Wctx_bf);
  embed_all_kernel<<<(T * B * H / 8) / 256, 256, 0, stream>>>(target, embedding,
                                                              embAll);
  cvt_bf16_kernel<<<(B * H) / 2048, 256, 0, stream>>>(enc_hidden, hAll);

  // Uk_bf = bf16(keys @ Ua_w^T + Ua_b)
  gemm_mfma<128, 128, 1, 0, 2>
      <<<dim3(H / 128, (B * S) / 128), 256, 0, stream>>>(
          keys_bf, Uaw_bf, Ua_b, nullptr, Uk_bf, nullptr, B * S, H, H, H, 0);
  // giE = embAll @ Wemb^T + b_ih
  gemm_mfma<128, 128, 0, 1, 2>
      <<<dim3((T * B) / 128, 3 * H / 128), 256, 0, stream>>>(
          embAll, Wemb_bf, gru_b_ih, giE, nullptr, nullptr, T * B, 3 * H, H,
          3 * H, 0);

  const float* h_in = enc_hidden;
  float* hbufs[2] = {hA, hB};

  for (int t = 0; t < T; ++t) {
    const unsigned short* hbf_in = hAll + (size_t)t * B * H;
    unsigned short* hbf_out = hAll + (size_t)(t + 1) * B * H;
    float* h_out = hbufs[t & 1];

    // wq | gh = h @ [Wa_w; w_hh]^T + [Wa_b; b_hh]
    gemm_mfma<64, 64, 0, 1, 5><<<dim3(B / 64, 4 * H / 64), 256, 0, stream>>>(
        hbf_in, fusedW, fusedB, wqgh, nullptr, nullptr, B, 4 * H, H, 4 * H, 0);
    attn_fused_kernel<<<B, 256, 0, stream>>>(
        wqgh, Uk_bf, keys_bf, Va_w, Va_b, out_attn, ctx_bf, t);
    // gi = giE[t] + ctx @ Wctx^T
    gemm_mfma<64, 64, 2, 1, 5><<<dim3(B / 64, 3 * H / 64), 256, 0, stream>>>(
        ctx_bf, Wctx_bf, giE + (size_t)t * B * 3 * H, gi, nullptr, nullptr,
        B, 3 * H, H, 3 * H, 0);
    gru_kernel<<<(B * H) / 256, 256, 0, stream>>>(gi, wqgh, h_in, h_out,
                                                  hbf_out);

    h_in = h_out;
  }

  // batched vocab projection over all steps: TM=64 tile for occupancy (10000
  // blocks, 24 KB LDS -> ~6 blocks/CU) — latency-hiding experiment
  gemm_mfma<64, 128, 3, 1, 2>
      <<<dim3((T * B) / 64, V / 128), 256, 0, stream>>>(
          hAll + (size_t)B * H, outw_bf, out_b, nullptr, logits_bf, parts,
          T * B, V, H, V, 500);
  logsm_reduce_kernel<<<T * B, 256, 0, stream>>>(parts, ls, 500);
  logsm_sub_kernel<<<dim3((V + 2047) / 2048, T * B), 256, 0, stream>>>(
      logits_bf, ls, out_dec);

  copy_kernel<<<(B * H + 255) / 256, 256, 0, stream>>>(h_in, out_h, B * H);
}

// Round 15
// 981.387 us; speedup vs baseline: 1.9862x; 1.0966x over previous
//
#include <hip/hip_runtime.h>
#include <math.h>

#define H 1024
#define V 32000
#define B 256
#define S 64
#define T 10

#define GBK 32

typedef __attribute__((ext_vector_type(8))) short bf16x8;
typedef __attribute__((ext_vector_type(4))) float f32x4;

static __device__ __forceinline__ unsigned short f2bf(float f) {
  unsigned int u = __float_as_uint(f);
  u += 0x7fff + ((u >> 16) & 1);   // round-to-nearest-even
  return (unsigned short)(u >> 16);
}
static __device__ __forceinline__ float bf2f(unsigned short u) {
  return __uint_as_float(((unsigned int)u) << 16);
}
static __device__ __forceinline__ float fast_tanh(float x) {
  float e = __expf(2.f * x);
  return 1.f - 2.f * __builtin_amdgcn_rcpf(e + 1.f);
}
static __device__ __forceinline__ float fast_sigmoid(float x) {
  return __builtin_amdgcn_rcpf(1.f + __expf(-x));
}

static __device__ __forceinline__ void load_lds16(const void* g, void* l) {
  __builtin_amdgcn_global_load_lds(
      (const __attribute__((address_space(1))) unsigned int*)g,
      (__attribute__((address_space(3))) unsigned int*)l, 16, 0, 0);
}

// swizzled element offset within one bf16 LDS tile (row stride 32 elems/64B)
static __device__ __forceinline__ int lds_off(int row, int g) {
  return row * GBK + ((g ^ ((row >> 1) & 3)) * 8);
}

// ---------------------------------------------------------------------------
// bf16 MFMA GEMM, TMxTN tile, BK=32, 4 waves (2x2), STAGES-deep pipeline with
// counted vmcnt + raw barrier.  C = A @ W^T (+ epilogue).
// F = STAGES-2 stages stay in flight across barriers (F=0 for STAGES=2).
// GRIDMODE 0: grid (N/TN, M/TM).
// GRIDMODE 1: grid (M/TM, N/TN) + bijective XCD swizzle (m204).
// MODE 0: C fp32 = acc + bias[col]
// MODE 1: Cb bf16 = acc + bias[col]
// MODE 2: C fp32 = acc + aux[row*ldc + col]
// ---------------------------------------------------------------------------
template <int TM, int TN, int MODE, int GRIDMODE, int STAGES>
__global__ __launch_bounds__(256) void gemm_mfma(
    const unsigned short* __restrict__ A, const unsigned short* __restrict__ W,
    const float* __restrict__ aux, float* __restrict__ C,
    unsigned short* __restrict__ Cb,
    int M, int N, int K, int ldc) {
  constexpr int FM = TM / 32;
  constexpr int FN = TN / 32;
  constexpr int CA = TM / 64;
  constexpr int CB = TN / 64;
  constexpr int LOADS = CA + CB;
  constexpr int F = (STAGES >= 3) ? (STAGES - 2) : 0;

  __shared__ unsigned short lsA[STAGES][TM * GBK];
  __shared__ unsigned short lsB[STAGES][TN * GBK];
  const int tid = threadIdx.x;
  const int lane = tid & 63;
  const int w = tid >> 6;

  int mIdx, nIdx;
  if constexpr (GRIDMODE == 1) {
    const int nwg = gridDim.x * gridDim.y;
    const int orig = blockIdx.y * gridDim.x + blockIdx.x;
    const int q = nwg >> 3, rr = nwg & 7;
    const int xcd = orig & 7, rest = orig >> 3;
    const int wgid =
        (xcd < rr ? xcd * (q + 1) : rr * (q + 1) + (xcd - rr) * q) + rest;
    mIdx = wgid % gridDim.x;
    nIdx = wgid / gridDim.x;
  } else {
    mIdx = blockIdx.y;
    nIdx = blockIdx.x;
  }
  const int mBase = mIdx * TM;
  const int nBase = nIdx * TN;
  const int rowBase = (w >> 1) * (TM / 2);
  const int colBase = (w & 1) * (TN / 2);

  const int fr = lane & 15;
  const int fkU = lane >> 4;
  const int fg = lane >> 4;

  f32x4 acc[FM][FN] = {};

  auto STAGE = [&](int buf, int k0) {
#pragma unroll
    for (int i = 0; i < CA; ++i) {
      int chunk = i * 256 + tid;
      int row = chunk >> 2;
      int u = chunk & 3;
      int col = (u ^ ((row >> 1) & 3)) * 8;
      load_lds16(A + (size_t)(mBase + row) * K + k0 + col,
                 &lsA[buf][chunk * 8]);
    }
#pragma unroll
    for (int i = 0; i < CB; ++i) {
      int chunk = i * 256 + tid;
      int row = chunk >> 2;
      int u = chunk & 3;
      int col = (u ^ ((row >> 1) & 3)) * 8;
      load_lds16(W + (size_t)(nBase + row) * K + k0 + col,
                 &lsB[buf][chunk * 8]);
    }
  };

  const int NT = K / GBK;
  for (int s = 0; s <= F && s < NT; ++s) STAGE(s % STAGES, s * GBK);

  for (int t = 0; t < NT; ++t) {
    const int rem = NT - 1 - t;
    if (rem >= F) {
      asm volatile("s_waitcnt vmcnt(%0)\n\ts_barrier" :: "i"(F * LOADS)
                   : "memory");
    } else if (rem == 2) {
      asm volatile("s_waitcnt vmcnt(%0)\n\ts_barrier" :: "i"(2 * LOADS)
                   : "memory");
    } else if (rem == 1) {
      asm volatile("s_waitcnt vmcnt(%0)\n\ts_barrier" :: "i"(1 * LOADS)
                   : "memory");
    } else {
      asm volatile("s_waitcnt vmcnt(0)\n\ts_barrier" ::: "memory");
    }
    if (t + F + 1 < NT) STAGE((t + F + 1) % STAGES, (t + F + 1) * GBK);

    const int cb = t % STAGES;
    bf16x8 af[FM], bfr[FN];
#pragma unroll
    for (int m = 0; m < FM; ++m)
      af[m] = *(const bf16x8*)&lsA[cb][lds_off(rowBase + m * 16 + fr, fkU)];
#pragma unroll
    for (int n = 0; n < FN; ++n)
      bfr[n] = *(const bf16x8*)&lsB[cb][lds_off(colBase + n * 16 + fr, fkU)];
#pragma unroll
    for (int m = 0; m < FM; ++m)
#pragma unroll
      for (int n = 0; n < FN; ++n)
        acc[m][n] = __builtin_amdgcn_mfma_f32_16x16x32_bf16(
            af[m], bfr[n], acc[m][n], 0, 0, 0);
  }

#pragma unroll
  for (int m = 0; m < FM; ++m) {
    int colg[FN];
    float bv[FN];
#pragma unroll
    for (int n = 0; n < FN; ++n) {
      colg[n] = nBase + colBase + n * 16 + fr;
      if constexpr (MODE != 2) bv[n] = aux[colg[n]];
    }
#pragma unroll
    for (int r = 0; r < 4; ++r) {
      const int rowg = mBase + rowBase + m * 16 + fg * 4 + r;
      float v[FN];
#pragma unroll
      for (int n = 0; n < FN; ++n) {
        if constexpr (MODE == 2)
          v[n] = acc[m][n][r] + aux[(size_t)rowg * ldc + colg[n]];
        else
          v[n] = acc[m][n][r] + bv[n];
        if constexpr (MODE == 1)
          Cb[(size_t)rowg * ldc + colg[n]] = f2bf(v[n]);
        else
          C[(size_t)rowg * ldc + colg[n]] = v[n];
      }
    }
  }
}

// ---------------------------------------------------------------------------
// fp8 e4m3 MFMA GEMM for the vocab projection. 128x128 tile, BK=64, 2-stage.
// A8:[M,K] fp8, W8:[N,K] fp8. Writes Cb bf16 logits + per-row (max,sumexp)
// partials (MODE-3 semantics). GRIDMODE-1 XCD swizzle.
// LDS tile: row stride 64 B; 16B-unit u swizzled with (row&3).
// ---------------------------------------------------------------------------
__global__ __launch_bounds__(256) void gemm_fp8_logits(
    const unsigned char* __restrict__ A8, const unsigned char* __restrict__ W8,
    const float* __restrict__ bias, unsigned short* __restrict__ Cb,
    float* __restrict__ partials, int M, int N, int K, int ldc, int pstride) {
  constexpr int BK = 64;
  __shared__ __align__(16) unsigned char lsA[2][128 * BK];  // 8 KB each
  __shared__ __align__(16) unsigned char lsB[2][128 * BK];
  const int tid = threadIdx.x;
  const int lane = tid & 63;
  const int w = tid >> 6;

  const int nwg = gridDim.x * gridDim.y;
  const int orig = blockIdx.y * gridDim.x + blockIdx.x;
  const int q = nwg >> 3, rr = nwg & 7;
  const int xcd = orig & 7, rest = orig >> 3;
  const int wgid =
      (xcd < rr ? xcd * (q + 1) : rr * (q + 1) + (xcd - rr) * q) + rest;
  const int mIdx = wgid % gridDim.x;
  const int nIdx = wgid / gridDim.x;
  const int mBase = mIdx * 128;
  const int nBase = nIdx * 128;
  const int rowBase = (w >> 1) * 64;
  const int colBase = (w & 1) * 64;
  const int fr = lane & 15;
  const int fkU = lane >> 4;   // 0..3 -> k-offset fkU*8 within 32-k-subtile
  const int fg = lane >> 4;

  f32x4 acc[4][4] = {};

  auto STAGE = [&](int buf, int k0) {
#pragma unroll
    for (int i = 0; i < 2; ++i) {
      int c = i * 256 + tid;        // 512 chunks of 16B = 128 rows x 64 B
      int row = c >> 2;
      int u = c & 3;
      int col = (u ^ (row & 3)) * 16;   // pre-swizzled global source
      load_lds16(A8 + (size_t)(mBase + row) * K + k0 + col, &lsA[buf][c * 16]);
    }
#pragma unroll
    for (int i = 0; i < 2; ++i) {
      int c = i * 256 + tid;
      int row = c >> 2;
      int u = c & 3;
      int col = (u ^ (row & 3)) * 16;
      load_lds16(W8 + (size_t)(nBase + row) * K + k0 + col, &lsB[buf][c * 16]);
    }
  };

  const int NT = K / BK;   // 16
  STAGE(0, 0);
  int cb = 0;
  for (int t = 0; t < NT; ++t) {
    asm volatile("s_waitcnt vmcnt(0)\n\ts_barrier" ::: "memory");
    if (t + 1 < NT) STAGE(cb ^ 1, (t + 1) * BK);
#pragma unroll
    for (int ks = 0; ks < 2; ++ks) {
      const int u = ks * 2 + (fkU >> 1);
      const int sub = (fkU & 1) * 8;
      long long af[4], bf[4];
#pragma unroll
      for (int m = 0; m < 4; ++m) {
        int row = rowBase + m * 16 + fr;
        af[m] = *(const long long*)
            &lsA[cb][row * BK + ((u ^ (row & 3)) << 4) + sub];
      }
#pragma unroll
      for (int n = 0; n < 4; ++n) {
        int row = colBase + n * 16 + fr;
        bf[n] = *(const long long*)
            &lsB[cb][row * BK + ((u ^ (row & 3)) << 4) + sub];
      }
#pragma unroll
      for (int m = 0; m < 4; ++m)
#pragma unroll
        for (int n = 0; n < 4; ++n)
          acc[m][n] = __builtin_amdgcn_mfma_f32_16x16x32_fp8_fp8(
              af[m], bf[n], acc[m][n], 0, 0, 0);
    }
    cb ^= 1;
  }

#pragma unroll
  for (int m = 0; m < 4; ++m) {
    int colg[4];
    float bv[4];
#pragma unroll
    for (int n = 0; n < 4; ++n) {
      colg[n] = nBase + colBase + n * 16 + fr;
      bv[n] = bias[colg[n]];
    }
#pragma unroll
    for (int r = 0; r < 4; ++r) {
      const int rowg = mBase + rowBase + m * 16 + fg * 4 + r;
      float v[4];
#pragma unroll
      for (int n = 0; n < 4; ++n) {
        v[n] = acc[m][n][r] + bv[n];
        Cb[(size_t)rowg * ldc + colg[n]] = f2bf(v[n]);
      }
      float mx = fmaxf(fmaxf(v[0], v[1]), fmaxf(v[2], v[3]));
      mx = fmaxf(mx, __shfl_xor(mx, 1, 64));
      mx = fmaxf(mx, __shfl_xor(mx, 2, 64));
      mx = fmaxf(mx, __shfl_xor(mx, 4, 64));
      mx = fmaxf(mx, __shfl_xor(mx, 8, 64));
      float se = __expf(v[0] - mx) + __expf(v[1] - mx) +
                 __expf(v[2] - mx) + __expf(v[3] - mx);
      se += __shfl_xor(se, 1, 64);
      se += __shfl_xor(se, 2, 64);
      se += __shfl_xor(se, 4, 64);
      se += __shfl_xor(se, 8, 64);
      if (fr == 0) {
        float2* pp = (float2*)partials;
        pp[(size_t)rowg * pstride + nIdx * 2 + (w & 1)] = make_float2(mx, se);
      }
    }
  }
}

// ---------------------------------------------------------------------------
__global__ __launch_bounds__(256) void cvt_bf16_kernel(
    const float* __restrict__ src, unsigned short* __restrict__ dst) {
  size_t i = ((size_t)blockIdx.x * 256 + threadIdx.x) * 8;
  float4 a = *(const float4*)&src[i];
  float4 b = *(const float4*)&src[i + 4];
  ushort4 lo, hi;
  lo.x = f2bf(a.x); lo.y = f2bf(a.y); lo.z = f2bf(a.z); lo.w = f2bf(a.w);
  hi.x = f2bf(b.x); hi.y = f2bf(b.y); hi.z = f2bf(b.z); hi.w = f2bf(b.w);
  *(ushort4*)&dst[i] = lo;
  *(ushort4*)&dst[i + 4] = hi;
}

// fp32 -> fp8 e4m3, 8 elems/thread
__global__ __launch_bounds__(256) void cvt_fp8_kernel(
    const float* __restrict__ src, unsigned int* __restrict__ dst) {
  size_t i = (size_t)blockIdx.x * 256 + threadIdx.x;   // per 8 elems
  float4 a = ((const float4*)src)[i * 2];
  float4 b = ((const float4*)src)[i * 2 + 1];
  int lo = __builtin_amdgcn_cvt_pk_fp8_f32(a.x, a.y, 0, false);
  lo = __builtin_amdgcn_cvt_pk_fp8_f32(a.z, a.w, lo, true);
  int hi = __builtin_amdgcn_cvt_pk_fp8_f32(b.x, b.y, 0, false);
  hi = __builtin_amdgcn_cvt_pk_fp8_f32(b.z, b.w, hi, true);
  ((int2*)dst)[i] = make_int2(lo, hi);
}

__global__ __launch_bounds__(256) void cvt_split_wih(
    const float* __restrict__ w_ih, unsigned short* __restrict__ Wemb,
    unsigned short* __restrict__ Wctx) {
  size_t base = ((size_t)blockIdx.x * 256 + threadIdx.x) * 8;
  int row = (int)(base >> 11);
  int col = (int)(base & 2047);
  float4 a = *(const float4*)&w_ih[base];
  float4 b = *(const float4*)&w_ih[base + 4];
  ushort4 lo, hi;
  lo.x = f2bf(a.x); lo.y = f2bf(a.y); lo.z = f2bf(a.z); lo.w = f2bf(a.w);
  hi.x = f2bf(b.x); hi.y = f2bf(b.y); hi.z = f2bf(b.z); hi.w = f2bf(b.w);
  unsigned short* dst = (col < H) ? (Wemb + (size_t)row * H + col)
                                  : (Wctx + (size_t)row * H + col - H);
  *(ushort4*)dst = lo;
  *(ushort4*)(dst + 4) = hi;
}

__global__ __launch_bounds__(256) void build_fused_bias(
    const float* __restrict__ Wa_b, const float* __restrict__ b_hh,
    float* __restrict__ fb) {
  int i = blockIdx.x * 256 + threadIdx.x;
  fb[i] = (i < H) ? Wa_b[i] : b_hh[i - H];
}

__global__ __launch_bounds__(256) void embed_all_kernel(
    const int* __restrict__ target, const float* __restrict__ emb,
    unsigned short* __restrict__ embAll) {
  int idx = blockIdx.x * 256 + threadIdx.x;  // over T*B*(H/8)
  int h8 = (idx & 127) * 8;
  int tb = idx >> 7;
  int t = tb >> 8;
  int b = tb & 255;
  int tok = (t == 0) ? 0 : target[b * T + (t - 1)];
  const float* e = emb + (size_t)tok * H + h8;
  float4 a = *(const float4*)e;
  float4 c = *(const float4*)(e + 4);
  ushort4 lo, hi;
  lo.x = f2bf(a.x); lo.y = f2bf(a.y); lo.z = f2bf(a.z); lo.w = f2bf(a.w);
  hi.x = f2bf(c.x); hi.y = f2bf(c.y); hi.z = f2bf(c.z); hi.w = f2bf(c.w);
  unsigned short* d = embAll + (size_t)tb * H + h8;
  *(ushort4*)d = lo;
  *(ushort4*)(d + 4) = hi;
}

// ---------------------------------------------------------------------------
// Fused attention: scores -> softmax -> ctx, one block per b.
// ---------------------------------------------------------------------------
__global__ __launch_bounds__(256) void attn_fused_kernel(
    const float* __restrict__ wqgh, const unsigned short* __restrict__ Uk_bf,
    const unsigned short* __restrict__ keys_bf,
    const float* __restrict__ Va_w, const float* __restrict__ Va_b,
    float* __restrict__ out_attn, unsigned short* __restrict__ ctx_bf, int t) {
  const int b = blockIdx.x;
  const int tid = threadIdx.x;
  __shared__ float wqs[H];
  __shared__ float vas[H];
  __shared__ float sw[S];

  ((float4*)wqs)[tid] = ((const float4*)(wqgh + (size_t)b * 4 * H))[tid];
  ((float4*)vas)[tid] = ((const float4*)Va_w)[tid];
  __syncthreads();

  const int s = tid >> 2;
  const int hc = (tid & 3) * 256;
  const unsigned short* uk = Uk_bf + ((size_t)b * S + s) * H + hc;
  float sum = 0.f;
#pragma unroll 4
  for (int i = 0; i < 256; i += 8) {
    bf16x8 u = *(const bf16x8*)&uk[i];
#pragma unroll
    for (int j = 0; j < 8; ++j) {
      float e = fast_tanh(wqs[hc + i + j] + bf2f((unsigned short)u[j]));
      sum += e * vas[hc + i + j];
    }
  }
  sum += __shfl_xor(sum, 1, 64);
  sum += __shfl_xor(sum, 2, 64);
  if ((tid & 3) == 0) sw[s] = sum + Va_b[0];
  __syncthreads();

  if (tid < 64) {
    float v = sw[tid];
    float m = v;
    for (int off = 32; off > 0; off >>= 1) m = fmaxf(m, __shfl_xor(m, off, 64));
    float e = __expf(v - m);
    float sm = e;
    for (int off = 32; off > 0; off >>= 1) sm += __shfl_xor(sm, off, 64);
    float wv = e / sm;
    sw[tid] = wv;
    out_attn[((size_t)b * T + t) * S + tid] = wv;
  }
  __syncthreads();

  const unsigned short* kb = keys_bf + (size_t)b * S * H + tid * 4;
  float c0 = 0.f, c1 = 0.f, c2 = 0.f, c3 = 0.f;
#pragma unroll 8
  for (int s2 = 0; s2 < S; ++s2) {
    float wv = sw[s2];
    ushort4 kv = *(const ushort4*)&kb[(size_t)s2 * H];
    c0 += wv * bf2f(kv.x);
    c1 += wv * bf2f(kv.y);
    c2 += wv * bf2f(kv.z);
    c3 += wv * bf2f(kv.w);
  }
  ushort4 o;
  o.x = f2bf(c0); o.y = f2bf(c1); o.z = f2bf(c2); o.w = f2bf(c3);
  *(ushort4*)&ctx_bf[(size_t)b * H + tid * 4] = o;
}

// ---------------------------------------------------------------------------
// GRU combine, 4 elems/thread; writes h fp32 + bf16 + fp8 (for vocab GEMM)
// ---------------------------------------------------------------------------
__global__ __launch_bounds__(256) void gru_kernel(
    const float* __restrict__ gi, const float* __restrict__ wqgh,
    const float* __restrict__ h_in, float* __restrict__ h_out,
    unsigned short* __restrict__ h_out_bf, unsigned int* __restrict__ h_out_f8) {
  int idx = (blockIdx.x * 256 + threadIdx.x) * 4;
  int b = idx >> 10;
  int j = idx & (H - 1);
  const float* gib = gi + (size_t)b * 3 * H;
  const float* ghb = wqgh + (size_t)b * 4 * H + H;
  float4 gr4 = *(const float4*)&gib[j];
  float4 gz4 = *(const float4*)&gib[H + j];
  float4 gn4 = *(const float4*)&gib[2 * H + j];
  float4 hr4 = *(const float4*)&ghb[j];
  float4 hz4 = *(const float4*)&ghb[H + j];
  float4 hn4 = *(const float4*)&ghb[2 * H + j];
  float4 hp4 = *(const float4*)&h_in[idx];
  float4 ho4;
  {
    float r0 = fast_sigmoid(gr4.x + hr4.x);
    float z0 = fast_sigmoid(gz4.x + hz4.x);
    float n0 = fast_tanh(gn4.x + r0 * hn4.x);
    ho4.x = (1.f - z0) * n0 + z0 * hp4.x;
    float r1 = fast_sigmoid(gr4.y + hr4.y);
    float z1 = fast_sigmoid(gz4.y + hz4.y);
    float n1 = fast_tanh(gn4.y + r1 * hn4.y);
    ho4.y = (1.f - z1) * n1 + z1 * hp4.y;
    float r2 = fast_sigmoid(gr4.z + hr4.z);
    float z2 = fast_sigmoid(gz4.z + hz4.z);
    float n2 = fast_tanh(gn4.z + r2 * hn4.z);
    ho4.z = (1.f - z2) * n2 + z2 * hp4.z;
    float r3 = fast_sigmoid(gr4.w + hr4.w);
    float z3 = fast_sigmoid(gz4.w + hz4.w);
    float n3 = fast_tanh(gn4.w + r3 * hn4.w);
    ho4.w = (1.f - z3) * n3 + z3 * hp4.w;
  }
  ushort4 hb4;
  hb4.x = f2bf(ho4.x); hb4.y = f2bf(ho4.y);
  hb4.z = f2bf(ho4.z); hb4.w = f2bf(ho4.w);
  int p8 = __builtin_amdgcn_cvt_pk_fp8_f32(ho4.x, ho4.y, 0, false);
  p8 = __builtin_amdgcn_cvt_pk_fp8_f32(ho4.z, ho4.w, p8, true);
  *(float4*)&h_out[idx] = ho4;
  *(ushort4*)&h_out_bf[idx] = hb4;
  h_out_f8[idx >> 2] = (unsigned int)p8;
}

// ---------------------------------------------------------------------------
// batched log-softmax: reduce partials -> ls[row] for all T*B rows
// ---------------------------------------------------------------------------
__global__ __launch_bounds__(256) void logsm_reduce_kernel(
    const float* __restrict__ partials, float* __restrict__ ls, int P) {
  const int row = blockIdx.x;
  const int tid = threadIdx.x;
  const float2* pp = (const float2*)partials + (size_t)row * P;
  __shared__ float red[256];
  float mx = -INFINITY;
  for (int i = tid; i < P; i += 256) mx = fmaxf(mx, pp[i].x);
  red[tid] = mx;
  __syncthreads();
  for (int off = 128; off > 0; off >>= 1) {
    if (tid < off) red[tid] = fmaxf(red[tid], red[tid + off]);
    __syncthreads();
  }
  mx = red[0];
  __syncthreads();
  float sm = 0.f;
  for (int i = tid; i < P; i += 256) sm += pp[i].y * __expf(pp[i].x - mx);
  red[tid] = sm;
  __syncthreads();
  for (int off = 128; off > 0; off >>= 1) {
    if (tid < off) red[tid] += red[tid + off];
    __syncthreads();
  }
  if (tid == 0) ls[row] = mx + __logf(red[0]);
}

// dec[b, t, :] = bf2f(logits_bf[tb, :]) - ls[tb];  tb = t*B + b
__global__ __launch_bounds__(256) void logsm_sub_kernel(
    const unsigned short* __restrict__ logits_bf, const float* __restrict__ ls,
    float* __restrict__ dec) {
  const int tb = blockIdx.y;
  const int t = tb >> 8;         // B = 256
  const int b = tb & 255;
  const int i8 = (blockIdx.x * 256 + threadIdx.x) * 8;
  if (i8 < V) {
    float l = ls[tb];
    const unsigned short* src = logits_bf + (size_t)tb * V + i8;
    bf16x8 u = *(const bf16x8*)src;
    float* d = dec + (size_t)b * T * V + (size_t)t * V + i8;
    float4 o0, o1;
    o0.x = bf2f((unsigned short)u[0]) - l; o0.y = bf2f((unsigned short)u[1]) - l;
    o0.z = bf2f((unsigned short)u[2]) - l; o0.w = bf2f((unsigned short)u[3]) - l;
    o1.x = bf2f((unsigned short)u[4]) - l; o1.y = bf2f((unsigned short)u[5]) - l;
    o1.z = bf2f((unsigned short)u[6]) - l; o1.w = bf2f((unsigned short)u[7]) - l;
    *(float4*)d = o0;
    *(float4*)(d + 4) = o1;
  }
}

__global__ __launch_bounds__(256) void copy_kernel(
    const float* __restrict__ src, float* __restrict__ dst, int n) {
  int i = blockIdx.x * 256 + threadIdx.x;
  if (i < n) dst[i] = src[i];
}

// ---------------------------------------------------------------------------
extern "C" void kernel_launch(void* const* d_in, const int* in_sizes, int n_in,
                              void* d_out, int out_size, void* d_ws, size_t ws_size,
                              hipStream_t stream) {
  const float* keys       = (const float*)d_in[0];
  const float* enc_hidden = (const float*)d_in[1];
  const int*   target     = (const int*)d_in[2];
  const float* embedding  = (const float*)d_in[3];
  const float* Wa_w = (const float*)d_in[4];
  const float* Wa_b = (const float*)d_in[5];
  const float* Ua_w = (const float*)d_in[6];
  const float* Ua_b = (const float*)d_in[7];
  const float* Va_w = (const float*)d_in[8];
  const float* Va_b = (const float*)d_in[9];
  const float* gru_w_ih = (const float*)d_in[10];
  const float* gru_w_hh = (const float*)d_in[11];
  const float* gru_b_ih = (const float*)d_in[12];
  const float* gru_b_hh = (const float*)d_in[13];
  const float* out_w = (const float*)d_in[14];
  const float* out_b = (const float*)d_in[15];

  float* out = (float*)d_out;
  float* out_dec  = out;
  float* out_h    = out + (size_t)B * T * V;
  float* out_attn = out + (size_t)B * T * V + (size_t)B * H;

  // ---- workspace ----
  char* p = (char*)d_ws;
  unsigned short* keys_bf = (unsigned short*)p; p += (size_t)B * S * H * 2;
  unsigned char*  outw8   = (unsigned char*)p;  p += (size_t)V * H;
  unsigned short* Uaw_bf  = (unsigned short*)p; p += (size_t)H * H * 2;
  unsigned short* fusedW  = (unsigned short*)p; p += (size_t)4 * H * H * 2;
  float*          fusedB  = (float*)p;          p += (size_t)4 * H * 4;
  unsigned short* Wemb_bf = (unsigned short*)p; p += (size_t)3 * H * H * 2;
  unsigned short* Wctx_bf = (unsigned short*)p; p += (size_t)3 * H * H * 2;
  unsigned short* embAll  = (unsigned short*)p; p += (size_t)T * B * H * 2;
  unsigned short* Uk_bf   = (unsigned short*)p; p += (size_t)B * S * H * 2;
  float*          giE     = (float*)p;          p += (size_t)T * B * 3 * H * 4;
  float*          wqgh    = (float*)p;          p += (size_t)B * 4 * H * 4;
  unsigned short* ctx_bf  = (unsigned short*)p; p += (size_t)B * H * 2;
  float*          gi      = (float*)p;          p += (size_t)B * 3 * H * 4;
  float*          hA      = (float*)p;          p += (size_t)B * H * 4;
  float*          hB      = (float*)p;          p += (size_t)B * H * 4;
  unsigned short* hAll    = (unsigned short*)p; p += (size_t)(T + 1) * B * H * 2;
  unsigned char*  hAll8   = (unsigned char*)p;  p += (size_t)T * B * H;
  unsigned short* logits_bf = (unsigned short*)p; p += (size_t)T * B * V * 2;
  float*          parts   = (float*)p;          p += (size_t)T * B * 500 * 2 * 4;
  float*          ls      = (float*)p;          p += (size_t)T * B * 4;

  // ---- one-time prep ----
  cvt_bf16_kernel<<<(B * S * H) / 2048, 256, 0, stream>>>(keys, keys_bf);
  cvt_fp8_kernel<<<((size_t)V * H) / 2048, 256, 0, stream>>>(
      out_w, (unsigned int*)outw8);
  cvt_bf16_kernel<<<(H * H) / 2048, 256, 0, stream>>>(Ua_w, Uaw_bf);
  cvt_bf16_kernel<<<(H * H) / 2048, 256, 0, stream>>>(Wa_w, fusedW);
  cvt_bf16_kernel<<<(3 * H * H) / 2048, 256, 0, stream>>>(gru_w_hh,
                                                          fusedW + (size_t)H * H);
  build_fused_bias<<<(4 * H) / 256, 256, 0, stream>>>(Wa_b, gru_b_hh, fusedB);
  cvt_split_wih<<<(3 * H * 2 * H) / 2048, 256, 0, stream>>>(gru_w_ih, Wemb_bf,
                                                            Wctx_bf);
  embed_all_kernel<<<(T * B * H / 8) / 256, 256, 0, stream>>>(target, embedding,
                                                              embAll);
  cvt_bf16_kernel<<<(B * H) / 2048, 256, 0, stream>>>(enc_hidden, hAll);

  // Uk_bf = bf16(keys @ Ua_w^T + Ua_b)
  gemm_mfma<128, 128, 1, 0, 2>
      <<<dim3(H / 128, (B * S) / 128), 256, 0, stream>>>(
          keys_bf, Uaw_bf, Ua_b, nullptr, Uk_bf, B * S, H, H, H);
  // giE = embAll @ Wemb^T + b_ih
  gemm_mfma<128, 128, 0, 1, 2>
      <<<dim3((T * B) / 128, 3 * H / 128), 256, 0, stream>>>(
          embAll, Wemb_bf, gru_b_ih, giE, nullptr, T * B, 3 * H, H, 3 * H);

  const float* h_in = enc_hidden;
  float* hbufs[2] = {hA, hB};

  for (int t = 0; t < T; ++t) {
    const unsigned short* hbf_in = hAll + (size_t)t * B * H;
    unsigned short* hbf_out = hAll + (size_t)(t + 1) * B * H;
    unsigned int* h8_out = (unsigned int*)(hAll8 + (size_t)t * B * H);
    float* h_out = hbufs[t & 1];

    // wq | gh = h @ [Wa_w; w_hh]^T + [Wa_b; b_hh]
    gemm_mfma<64, 64, 0, 1, 5><<<dim3(B / 64, 4 * H / 64), 256, 0, stream>>>(
        hbf_in, fusedW, fusedB, wqgh, nullptr, B, 4 * H, H, 4 * H);
    attn_fused_kernel<<<B, 256, 0, stream>>>(
        wqgh, Uk_bf, keys_bf, Va_w, Va_b, out_attn, ctx_bf, t);
    // gi = giE[t] + ctx @ Wctx^T
    gemm_mfma<64, 64, 2, 1, 5><<<dim3(B / 64, 3 * H / 64), 256, 0, stream>>>(
        ctx_bf, Wctx_bf, giE + (size_t)t * B * 3 * H, gi, nullptr,
        B, 3 * H, H, 3 * H);
    gru_kernel<<<(B * H / 4) / 256, 256, 0, stream>>>(gi, wqgh, h_in, h_out,
                                                      hbf_out, h8_out);

    h_in = h_out;
  }

  // batched vocab projection over all steps, fp8 e4m3 inputs (BK=64, NT=16):
  // halves LDS-read bytes per MFMA (the measured bottleneck) + halves barriers
  gemm_fp8_logits<<<dim3((T * B) / 128, V / 128), 256, 0, stream>>>(
      hAll8, outw8, out_b, logits_bf, parts, T * B, V, H, V, 500);
  logsm_reduce_kernel<<<T * B, 256, 0, stream>>>(parts, ls, 500);
  logsm_sub_kernel<<<dim3((V + 2047) / 2048, T * B), 256, 0, stream>>>(
      logits_bf, ls, out_dec);

  copy_kernel<<<(B * H + 255) / 256, 256, 0, stream>>>(h_in, out_h, B * H);
}

// Round 16
// 942.406 us; speedup vs baseline: 2.0684x; 1.0414x over previous
//
#include <hip/hip_runtime.h>
#include <math.h>

#define H 1024
#define V 32000
#define B 256
#define S 64
#define T 10

#define GBK 32

typedef __attribute__((ext_vector_type(8))) short bf16x8;
typedef __attribute__((ext_vector_type(4))) float f32x4;

static __device__ __forceinline__ unsigned short f2bf(float f) {
  unsigned int u = __float_as_uint(f);
  u += 0x7fff + ((u >> 16) & 1);   // round-to-nearest-even
  return (unsigned short)(u >> 16);
}
static __device__ __forceinline__ float bf2f(unsigned short u) {
  return __uint_as_float(((unsigned int)u) << 16);
}
static __device__ __forceinline__ float fast_tanh(float x) {
  float e = __expf(2.f * x);
  return 1.f - 2.f * __builtin_amdgcn_rcpf(e + 1.f);
}
static __device__ __forceinline__ float fast_sigmoid(float x) {
  return __builtin_amdgcn_rcpf(1.f + __expf(-x));
}

static __device__ __forceinline__ void load_lds16(const void* g, void* l) {
  __builtin_amdgcn_global_load_lds(
      (const __attribute__((address_space(1))) unsigned int*)g,
      (__attribute__((address_space(3))) unsigned int*)l, 16, 0, 0);
}

// swizzled element offset within one bf16 LDS tile (row stride 32 elems/64B)
static __device__ __forceinline__ int lds_off(int row, int g) {
  return row * GBK + ((g ^ ((row >> 1) & 3)) * 8);
}

// ---------------------------------------------------------------------------
// bf16 MFMA GEMM, TMxTN tile, BK=32, 4 waves (2x2), STAGES-deep pipeline with
// counted vmcnt + raw barrier.  C = A @ W^T (+ epilogue).
// F = STAGES-2 stages stay in flight across barriers (F=0 for STAGES=2).
// GRIDMODE 0: grid (N/TN, M/TM).
// GRIDMODE 1: grid (M/TM, N/TN) + bijective XCD swizzle (m204).
// MODE 0: C fp32 = acc + bias[col]
// MODE 1: Cb bf16 = acc + bias[col]
// MODE 2: C fp32 = acc + aux[row*ldc + col]
// ---------------------------------------------------------------------------
template <int TM, int TN, int MODE, int GRIDMODE, int STAGES>
__global__ __launch_bounds__(256) void gemm_mfma(
    const unsigned short* __restrict__ A, const unsigned short* __restrict__ W,
    const float* __restrict__ aux, float* __restrict__ C,
    unsigned short* __restrict__ Cb,
    int M, int N, int K, int ldc) {
  constexpr int FM = TM / 32;
  constexpr int FN = TN / 32;
  constexpr int CA = TM / 64;
  constexpr int CB = TN / 64;
  constexpr int LOADS = CA + CB;
  constexpr int F = (STAGES >= 3) ? (STAGES - 2) : 0;

  __shared__ unsigned short lsA[STAGES][TM * GBK];
  __shared__ unsigned short lsB[STAGES][TN * GBK];
  const int tid = threadIdx.x;
  const int lane = tid & 63;
  const int w = tid >> 6;

  int mIdx, nIdx;
  if constexpr (GRIDMODE == 1) {
    const int nwg = gridDim.x * gridDim.y;
    const int orig = blockIdx.y * gridDim.x + blockIdx.x;
    const int q = nwg >> 3, rr = nwg & 7;
    const int xcd = orig & 7, rest = orig >> 3;
    const int wgid =
        (xcd < rr ? xcd * (q + 1) : rr * (q + 1) + (xcd - rr) * q) + rest;
    mIdx = wgid % gridDim.x;
    nIdx = wgid / gridDim.x;
  } else {
    mIdx = blockIdx.y;
    nIdx = blockIdx.x;
  }
  const int mBase = mIdx * TM;
  const int nBase = nIdx * TN;
  const int rowBase = (w >> 1) * (TM / 2);
  const int colBase = (w & 1) * (TN / 2);

  const int fr = lane & 15;
  const int fkU = lane >> 4;
  const int fg = lane >> 4;

  f32x4 acc[FM][FN] = {};

  auto STAGE = [&](int buf, int k0) {
#pragma unroll
    for (int i = 0; i < CA; ++i) {
      int chunk = i * 256 + tid;
      int row = chunk >> 2;
      int u = chunk & 3;
      int col = (u ^ ((row >> 1) & 3)) * 8;
      load_lds16(A + (size_t)(mBase + row) * K + k0 + col,
                 &lsA[buf][chunk * 8]);
    }
#pragma unroll
    for (int i = 0; i < CB; ++i) {
      int chunk = i * 256 + tid;
      int row = chunk >> 2;
      int u = chunk & 3;
      int col = (u ^ ((row >> 1) & 3)) * 8;
      load_lds16(W + (size_t)(nBase + row) * K + k0 + col,
                 &lsB[buf][chunk * 8]);
    }
  };

  const int NT = K / GBK;
  for (int s = 0; s <= F && s < NT; ++s) STAGE(s % STAGES, s * GBK);

  for (int t = 0; t < NT; ++t) {
    const int rem = NT - 1 - t;
    if (rem >= F) {
      asm volatile("s_waitcnt vmcnt(%0)\n\ts_barrier" :: "i"(F * LOADS)
                   : "memory");
    } else if (rem == 2) {
      asm volatile("s_waitcnt vmcnt(%0)\n\ts_barrier" :: "i"(2 * LOADS)
                   : "memory");
    } else if (rem == 1) {
      asm volatile("s_waitcnt vmcnt(%0)\n\ts_barrier" :: "i"(1 * LOADS)
                   : "memory");
    } else {
      asm volatile("s_waitcnt vmcnt(0)\n\ts_barrier" ::: "memory");
    }
    if (t + F + 1 < NT) STAGE((t + F + 1) % STAGES, (t + F + 1) * GBK);

    const int cb = t % STAGES;
    bf16x8 af[FM], bfr[FN];
#pragma unroll
    for (int m = 0; m < FM; ++m)
      af[m] = *(const bf16x8*)&lsA[cb][lds_off(rowBase + m * 16 + fr, fkU)];
#pragma unroll
    for (int n = 0; n < FN; ++n)
      bfr[n] = *(const bf16x8*)&lsB[cb][lds_off(colBase + n * 16 + fr, fkU)];
#pragma unroll
    for (int m = 0; m < FM; ++m)
#pragma unroll
      for (int n = 0; n < FN; ++n)
        acc[m][n] = __builtin_amdgcn_mfma_f32_16x16x32_bf16(
            af[m], bfr[n], acc[m][n], 0, 0, 0);
  }

#pragma unroll
  for (int m = 0; m < FM; ++m) {
    int colg[FN];
    float bv[FN];
#pragma unroll
    for (int n = 0; n < FN; ++n) {
      colg[n] = nBase + colBase + n * 16 + fr;
      if constexpr (MODE != 2) bv[n] = aux[colg[n]];
    }
#pragma unroll
    for (int r = 0; r < 4; ++r) {
      const int rowg = mBase + rowBase + m * 16 + fg * 4 + r;
      float v[FN];
#pragma unroll
      for (int n = 0; n < FN; ++n) {
        if constexpr (MODE == 2)
          v[n] = acc[m][n][r] + aux[(size_t)rowg * ldc + colg[n]];
        else
          v[n] = acc[m][n][r] + bv[n];
        if constexpr (MODE == 1)
          Cb[(size_t)rowg * ldc + colg[n]] = f2bf(v[n]);
        else
          C[(size_t)rowg * ldc + colg[n]] = v[n];
      }
    }
  }
}

// ---------------------------------------------------------------------------
// fp8 e4m3 MFMA GEMM for the vocab projection. 128x128 tile, BK=64, 2-stage.
// A8:[M,K] fp8, W8:[N,K] fp8. Writes Cb bf16 logits + per-row (max,sumexp)
// partials. GRIDMODE-1 XCD swizzle.
// LDS tile: row stride 64 B; 16B-unit u swizzled with f(row)=(row>>1)&3 —
// start bank = (16*row + 4*(u^f)) mod 32: even rows {0,4,8,12}, odd rows
// {16,20,24,28}, each 2-way (free). (round-15 bug: f=row&3 -> 4-way.)
// ---------------------------------------------------------------------------
__global__ __launch_bounds__(256) void gemm_fp8_logits(
    const unsigned char* __restrict__ A8, const unsigned char* __restrict__ W8,
    const float* __restrict__ bias, unsigned short* __restrict__ Cb,
    float* __restrict__ partials, int M, int N, int K, int ldc, int pstride) {
  constexpr int BK = 64;
  __shared__ __align__(16) unsigned char lsA[2][128 * BK];  // 8 KB each
  __shared__ __align__(16) unsigned char lsB[2][128 * BK];
  const int tid = threadIdx.x;
  const int lane = tid & 63;
  const int w = tid >> 6;

  const int nwg = gridDim.x * gridDim.y;
  const int orig = blockIdx.y * gridDim.x + blockIdx.x;
  const int q = nwg >> 3, rr = nwg & 7;
  const int xcd = orig & 7, rest = orig >> 3;
  const int wgid =
      (xcd < rr ? xcd * (q + 1) : rr * (q + 1) + (xcd - rr) * q) + rest;
  const int mIdx = wgid % gridDim.x;
  const int nIdx = wgid / gridDim.x;
  const int mBase = mIdx * 128;
  const int nBase = nIdx * 128;
  const int rowBase = (w >> 1) * 64;
  const int colBase = (w & 1) * 64;
  const int fr = lane & 15;
  const int fkU = lane >> 4;   // 0..3
  const int fg = lane >> 4;

  f32x4 acc[4][4] = {};

  auto STAGE = [&](int buf, int k0) {
#pragma unroll
    for (int i = 0; i < 2; ++i) {
      int c = i * 256 + tid;        // 512 chunks of 16B = 128 rows x 64 B
      int row = c >> 2;
      int u = c & 3;
      int col = (u ^ ((row >> 1) & 3)) * 16;   // pre-swizzled global source
      load_lds16(A8 + (size_t)(mBase + row) * K + k0 + col, &lsA[buf][c * 16]);
    }
#pragma unroll
    for (int i = 0; i < 2; ++i) {
      int c = i * 256 + tid;
      int row = c >> 2;
      int u = c & 3;
      int col = (u ^ ((row >> 1) & 3)) * 16;
      load_lds16(W8 + (size_t)(nBase + row) * K + k0 + col, &lsB[buf][c * 16]);
    }
  };

  const int NT = K / BK;   // 16
  STAGE(0, 0);
  int cb = 0;
  for (int t = 0; t < NT; ++t) {
    asm volatile("s_waitcnt vmcnt(0)\n\ts_barrier" ::: "memory");
    if (t + 1 < NT) STAGE(cb ^ 1, (t + 1) * BK);
#pragma unroll
    for (int ks = 0; ks < 2; ++ks) {
      const int u = ks * 2 + (fkU >> 1);
      const int sub = (fkU & 1) * 8;
      long long af[4], bf[4];
#pragma unroll
      for (int m = 0; m < 4; ++m) {
        int row = rowBase + m * 16 + fr;
        af[m] = *(const long long*)
            &lsA[cb][row * BK + ((u ^ ((row >> 1) & 3)) << 4) + sub];
      }
#pragma unroll
      for (int n = 0; n < 4; ++n) {
        int row = colBase + n * 16 + fr;
        bf[n] = *(const long long*)
            &lsB[cb][row * BK + ((u ^ ((row >> 1) & 3)) << 4) + sub];
      }
#pragma unroll
      for (int m = 0; m < 4; ++m)
#pragma unroll
        for (int n = 0; n < 4; ++n)
          acc[m][n] = __builtin_amdgcn_mfma_f32_16x16x32_fp8_fp8(
              af[m], bf[n], acc[m][n], 0, 0, 0);
    }
    cb ^= 1;
  }

#pragma unroll
  for (int m = 0; m < 4; ++m) {
    int colg[4];
    float bv[4];
#pragma unroll
    for (int n = 0; n < 4; ++n) {
      colg[n] = nBase + colBase + n * 16 + fr;
      bv[n] = bias[colg[n]];
    }
#pragma unroll
    for (int r = 0; r < 4; ++r) {
      const int rowg = mBase + rowBase + m * 16 + fg * 4 + r;
      float v[4];
#pragma unroll
      for (int n = 0; n < 4; ++n) {
        v[n] = acc[m][n][r] + bv[n];
        Cb[(size_t)rowg * ldc + colg[n]] = f2bf(v[n]);
      }
      float mx = fmaxf(fmaxf(v[0], v[1]), fmaxf(v[2], v[3]));
      mx = fmaxf(mx, __shfl_xor(mx, 1, 64));
      mx = fmaxf(mx, __shfl_xor(mx, 2, 64));
      mx = fmaxf(mx, __shfl_xor(mx, 4, 64));
      mx = fmaxf(mx, __shfl_xor(mx, 8, 64));
      float se = __expf(v[0] - mx) + __expf(v[1] - mx) +
                 __expf(v[2] - mx) + __expf(v[3] - mx);
      se += __shfl_xor(se, 1, 64);
      se += __shfl_xor(se, 2, 64);
      se += __shfl_xor(se, 4, 64);
      se += __shfl_xor(se, 8, 64);
      if (fr == 0) {
        float2* pp = (float2*)partials;
        pp[(size_t)rowg * pstride + nIdx * 2 + (w & 1)] = make_float2(mx, se);
      }
    }
  }
}

// ---------------------------------------------------------------------------
__global__ __launch_bounds__(256) void cvt_bf16_kernel(
    const float* __restrict__ src, unsigned short* __restrict__ dst) {
  size_t i = ((size_t)blockIdx.x * 256 + threadIdx.x) * 8;
  float4 a = *(const float4*)&src[i];
  float4 b = *(const float4*)&src[i + 4];
  ushort4 lo, hi;
  lo.x = f2bf(a.x); lo.y = f2bf(a.y); lo.z = f2bf(a.z); lo.w = f2bf(a.w);
  hi.x = f2bf(b.x); hi.y = f2bf(b.y); hi.z = f2bf(b.z); hi.w = f2bf(b.w);
  *(ushort4*)&dst[i] = lo;
  *(ushort4*)&dst[i + 4] = hi;
}

// fp32 -> fp8 e4m3, 8 elems/thread
__global__ __launch_bounds__(256) void cvt_fp8_kernel(
    const float* __restrict__ src, unsigned int* __restrict__ dst) {
  size_t i = (size_t)blockIdx.x * 256 + threadIdx.x;   // per 8 elems
  float4 a = ((const float4*)src)[i * 2];
  float4 b = ((const float4*)src)[i * 2 + 1];
  int lo = __builtin_amdgcn_cvt_pk_fp8_f32(a.x, a.y, 0, false);
  lo = __builtin_amdgcn_cvt_pk_fp8_f32(a.z, a.w, lo, true);
  int hi = __builtin_amdgcn_cvt_pk_fp8_f32(b.x, b.y, 0, false);
  hi = __builtin_amdgcn_cvt_pk_fp8_f32(b.z, b.w, hi, true);
  ((int2*)dst)[i] = make_int2(lo, hi);
}

__global__ __launch_bounds__(256) void cvt_split_wih(
    const float* __restrict__ w_ih, unsigned short* __restrict__ Wemb,
    unsigned short* __restrict__ Wctx) {
  size_t base = ((size_t)blockIdx.x * 256 + threadIdx.x) * 8;
  int row = (int)(base >> 11);
  int col = (int)(base & 2047);
  float4 a = *(const float4*)&w_ih[base];
  float4 b = *(const float4*)&w_ih[base + 4];
  ushort4 lo, hi;
  lo.x = f2bf(a.x); lo.y = f2bf(a.y); lo.z = f2bf(a.z); lo.w = f2bf(a.w);
  hi.x = f2bf(b.x); hi.y = f2bf(b.y); hi.z = f2bf(b.z); hi.w = f2bf(b.w);
  unsigned short* dst = (col < H) ? (Wemb + (size_t)row * H + col)
                                  : (Wctx + (size_t)row * H + col - H);
  *(ushort4*)dst = lo;
  *(ushort4*)(dst + 4) = hi;
}

__global__ __launch_bounds__(256) void build_fused_bias(
    const float* __restrict__ Wa_b, const float* __restrict__ b_hh,
    float* __restrict__ fb) {
  int i = blockIdx.x * 256 + threadIdx.x;
  fb[i] = (i < H) ? Wa_b[i] : b_hh[i - H];
}

__global__ __launch_bounds__(256) void embed_all_kernel(
    const int* __restrict__ target, const float* __restrict__ emb,
    unsigned short* __restrict__ embAll) {
  int idx = blockIdx.x * 256 + threadIdx.x;  // over T*B*(H/8)
  int h8 = (idx & 127) * 8;
  int tb = idx >> 7;
  int t = tb >> 8;
  int b = tb & 255;
  int tok = (t == 0) ? 0 : target[b * T + (t - 1)];
  const float* e = emb + (size_t)tok * H + h8;
  float4 a = *(const float4*)e;
  float4 c = *(const float4*)(e + 4);
  ushort4 lo, hi;
  lo.x = f2bf(a.x); lo.y = f2bf(a.y); lo.z = f2bf(a.z); lo.w = f2bf(a.w);
  hi.x = f2bf(c.x); hi.y = f2bf(c.y); hi.z = f2bf(c.z); hi.w = f2bf(c.w);
  unsigned short* d = embAll + (size_t)tb * H + h8;
  *(ushort4*)d = lo;
  *(ushort4*)(d + 4) = hi;
}

// ---------------------------------------------------------------------------
// Fused attention: scores -> softmax -> ctx, one block per b.
// ---------------------------------------------------------------------------
__global__ __launch_bounds__(256) void attn_fused_kernel(
    const float* __restrict__ wqgh, const unsigned short* __restrict__ Uk_bf,
    const unsigned short* __restrict__ keys_bf,
    const float* __restrict__ Va_w, const float* __restrict__ Va_b,
    float* __restrict__ out_attn, unsigned short* __restrict__ ctx_bf, int t) {
  const int b = blockIdx.x;
  const int tid = threadIdx.x;
  __shared__ float wqs[H];
  __shared__ float vas[H];
  __shared__ float sw[S];

  ((float4*)wqs)[tid] = ((const float4*)(wqgh + (size_t)b * 4 * H))[tid];
  ((float4*)vas)[tid] = ((const float4*)Va_w)[tid];
  __syncthreads();

  const int s = tid >> 2;
  const int hc = (tid & 3) * 256;
  const unsigned short* uk = Uk_bf + ((size_t)b * S + s) * H + hc;
  float sum = 0.f;
#pragma unroll 4
  for (int i = 0; i < 256; i += 8) {
    bf16x8 u = *(const bf16x8*)&uk[i];
#pragma unroll
    for (int j = 0; j < 8; ++j) {
      float e = fast_tanh(wqs[hc + i + j] + bf2f((unsigned short)u[j]));
      sum += e * vas[hc + i + j];
    }
  }
  sum += __shfl_xor(sum, 1, 64);
  sum += __shfl_xor(sum, 2, 64);
  if ((tid & 3) == 0) sw[s] = sum + Va_b[0];
  __syncthreads();

  if (tid < 64) {
    float v = sw[tid];
    float m = v;
    for (int off = 32; off > 0; off >>= 1) m = fmaxf(m, __shfl_xor(m, off, 64));
    float e = __expf(v - m);
    float sm = e;
    for (int off = 32; off > 0; off >>= 1) sm += __shfl_xor(sm, off, 64);
    float wv = e / sm;
    sw[tid] = wv;
    out_attn[((size_t)b * T + t) * S + tid] = wv;
  }
  __syncthreads();

  const unsigned short* kb = keys_bf + (size_t)b * S * H + tid * 4;
  float c0 = 0.f, c1 = 0.f, c2 = 0.f, c3 = 0.f;
#pragma unroll 8
  for (int s2 = 0; s2 < S; ++s2) {
    float wv = sw[s2];
    ushort4 kv = *(const ushort4*)&kb[(size_t)s2 * H];
    c0 += wv * bf2f(kv.x);
    c1 += wv * bf2f(kv.y);
    c2 += wv * bf2f(kv.z);
    c3 += wv * bf2f(kv.w);
  }
  ushort4 o;
  o.x = f2bf(c0); o.y = f2bf(c1); o.z = f2bf(c2); o.w = f2bf(c3);
  *(ushort4*)&ctx_bf[(size_t)b * H + tid * 4] = o;
}

// ---------------------------------------------------------------------------
// GRU combine, 4 elems/thread; writes h fp32 + bf16 + fp8 (for vocab GEMM)
// ---------------------------------------------------------------------------
__global__ __launch_bounds__(256) void gru_kernel(
    const float* __restrict__ gi, const float* __restrict__ wqgh,
    const float* __restrict__ h_in, float* __restrict__ h_out,
    unsigned short* __restrict__ h_out_bf, unsigned int* __restrict__ h_out_f8) {
  int idx = (blockIdx.x * 256 + threadIdx.x) * 4;
  int b = idx >> 10;
  int j = idx & (H - 1);
  const float* gib = gi + (size_t)b * 3 * H;
  const float* ghb = wqgh + (size_t)b * 4 * H + H;
  float4 gr4 = *(const float4*)&gib[j];
  float4 gz4 = *(const float4*)&gib[H + j];
  float4 gn4 = *(const float4*)&gib[2 * H + j];
  float4 hr4 = *(const float4*)&ghb[j];
  float4 hz4 = *(const float4*)&ghb[H + j];
  float4 hn4 = *(const float4*)&ghb[2 * H + j];
  float4 hp4 = *(const float4*)&h_in[idx];
  float4 ho4;
  {
    float r0 = fast_sigmoid(gr4.x + hr4.x);
    float z0 = fast_sigmoid(gz4.x + hz4.x);
    float n0 = fast_tanh(gn4.x + r0 * hn4.x);
    ho4.x = (1.f - z0) * n0 + z0 * hp4.x;
    float r1 = fast_sigmoid(gr4.y + hr4.y);
    float z1 = fast_sigmoid(gz4.y + hz4.y);
    float n1 = fast_tanh(gn4.y + r1 * hn4.y);
    ho4.y = (1.f - z1) * n1 + z1 * hp4.y;
    float r2 = fast_sigmoid(gr4.z + hr4.z);
    float z2 = fast_sigmoid(gz4.z + hz4.z);
    float n2 = fast_tanh(gn4.z + r2 * hn4.z);
    ho4.z = (1.f - z2) * n2 + z2 * hp4.z;
    float r3 = fast_sigmoid(gr4.w + hr4.w);
    float z3 = fast_sigmoid(gz4.w + hz4.w);
    float n3 = fast_tanh(gn4.w + r3 * hn4.w);
    ho4.w = (1.f - z3) * n3 + z3 * hp4.w;
  }
  ushort4 hb4;
  hb4.x = f2bf(ho4.x); hb4.y = f2bf(ho4.y);
  hb4.z = f2bf(ho4.z); hb4.w = f2bf(ho4.w);
  int p8 = __builtin_amdgcn_cvt_pk_fp8_f32(ho4.x, ho4.y, 0, false);
  p8 = __builtin_amdgcn_cvt_pk_fp8_f32(ho4.z, ho4.w, p8, true);
  *(float4*)&h_out[idx] = ho4;
  *(ushort4*)&h_out_bf[idx] = hb4;
  h_out_f8[idx >> 2] = (unsigned int)p8;
}

// ---------------------------------------------------------------------------
// batched log-softmax: reduce partials -> ls[row] for all T*B rows
// ---------------------------------------------------------------------------
__global__ __launch_bounds__(256) void logsm_reduce_kernel(
    const float* __restrict__ partials, float* __restrict__ ls, int P) {
  const int row = blockIdx.x;
  const int tid = threadIdx.x;
  const float2* pp = (const float2*)partials + (size_t)row * P;
  __shared__ float red[256];
  float mx = -INFINITY;
  for (int i = tid; i < P; i += 256) mx = fmaxf(mx, pp[i].x);
  red[tid] = mx;
  __syncthreads();
  for (int off = 128; off > 0; off >>= 1) {
    if (tid < off) red[tid] = fmaxf(red[tid], red[tid + off]);
    __syncthreads();
  }
  mx = red[0];
  __syncthreads();
  float sm = 0.f;
  for (int i = tid; i < P; i += 256) sm += pp[i].y * __expf(pp[i].x - mx);
  red[tid] = sm;
  __syncthreads();
  for (int off = 128; off > 0; off >>= 1) {
    if (tid < off) red[tid] += red[tid + off];
    __syncthreads();
  }
  if (tid == 0) ls[row] = mx + __logf(red[0]);
}

// dec[b, t, :] = bf2f(logits_bf[tb, :]) - ls[tb];  tb = t*B + b
__global__ __launch_bounds__(256) void logsm_sub_kernel(
    const unsigned short* __restrict__ logits_bf, const float* __restrict__ ls,
    float* __restrict__ dec) {
  const int tb = blockIdx.y;
  const int t = tb >> 8;         // B = 256
  const int b = tb & 255;
  const int i8 = (blockIdx.x * 256 + threadIdx.x) * 8;
  if (i8 < V) {
    float l = ls[tb];
    const unsigned short* src = logits_bf + (size_t)tb * V + i8;
    bf16x8 u = *(const bf16x8*)src;
    float* d = dec + (size_t)b * T * V + (size_t)t * V + i8;
    float4 o0, o1;
    o0.x = bf2f((unsigned short)u[0]) - l; o0.y = bf2f((unsigned short)u[1]) - l;
    o0.z = bf2f((unsigned short)u[2]) - l; o0.w = bf2f((unsigned short)u[3]) - l;
    o1.x = bf2f((unsigned short)u[4]) - l; o1.y = bf2f((unsigned short)u[5]) - l;
    o1.z = bf2f((unsigned short)u[6]) - l; o1.w = bf2f((unsigned short)u[7]) - l;
    *(float4*)d = o0;
    *(float4*)(d + 4) = o1;
  }
}

__global__ __launch_bounds__(256) void copy_kernel(
    const float* __restrict__ src, float* __restrict__ dst, int n) {
  int i = blockIdx.x * 256 + threadIdx.x;
  if (i < n) dst[i] = src[i];
}

// ---------------------------------------------------------------------------
extern "C" void kernel_launch(void* const* d_in, const int* in_sizes, int n_in,
                              void* d_out, int out_size, void* d_ws, size_t ws_size,
                              hipStream_t stream) {
  const float* keys       = (const float*)d_in[0];
  const float* enc_hidden = (const float*)d_in[1];
  const int*   target     = (const int*)d_in[2];
  const float* embedding  = (const float*)d_in[3];
  const float* Wa_w = (const float*)d_in[4];
  const float* Wa_b = (const float*)d_in[5];
  const float* Ua_w = (const float*)d_in[6];
  const float* Ua_b = (const float*)d_in[7];
  const float* Va_w = (const float*)d_in[8];
  const float* Va_b = (const float*)d_in[9];
  const float* gru_w_ih = (const float*)d_in[10];
  const float* gru_w_hh = (const float*)d_in[11];
  const float* gru_b_ih = (const float*)d_in[12];
  const float* gru_b_hh = (const float*)d_in[13];
  const float* out_w = (const float*)d_in[14];
  const float* out_b = (const float*)d_in[15];

  float* out = (float*)d_out;
  float* out_dec  = out;
  float* out_h    = out + (size_t)B * T * V;
  float* out_attn = out + (size_t)B * T * V + (size_t)B * H;

  // ---- workspace ----
  char* p = (char*)d_ws;
  unsigned short* keys_bf = (unsigned short*)p; p += (size_t)B * S * H * 2;
  unsigned char*  outw8   = (unsigned char*)p;  p += (size_t)V * H;
  unsigned short* Uaw_bf  = (unsigned short*)p; p += (size_t)H * H * 2;
  unsigned short* fusedW  = (unsigned short*)p; p += (size_t)4 * H * H * 2;
  float*          fusedB  = (float*)p;          p += (size_t)4 * H * 4;
  unsigned short* Wemb_bf = (unsigned short*)p; p += (size_t)3 * H * H * 2;
  unsigned short* Wctx_bf = (unsigned short*)p; p += (size_t)3 * H * H * 2;
  unsigned short* embAll  = (unsigned short*)p; p += (size_t)T * B * H * 2;
  unsigned short* Uk_bf   = (unsigned short*)p; p += (size_t)B * S * H * 2;
  float*          giE     = (float*)p;          p += (size_t)T * B * 3 * H * 4;
  float*          wqgh    = (float*)p;          p += (size_t)B * 4 * H * 4;
  unsigned short* ctx_bf  = (unsigned short*)p; p += (size_t)B * H * 2;
  float*          gi      = (float*)p;          p += (size_t)B * 3 * H * 4;
  float*          hA      = (float*)p;          p += (size_t)B * H * 4;
  float*          hB      = (float*)p;          p += (size_t)B * H * 4;
  unsigned short* hAll    = (unsigned short*)p; p += (size_t)(T + 1) * B * H * 2;
  unsigned char*  hAll8   = (unsigned char*)p;  p += (size_t)T * B * H;
  unsigned short* logits_bf = (unsigned short*)p; p += (size_t)T * B * V * 2;
  float*          parts   = (float*)p;          p += (size_t)T * B * 500 * 2 * 4;
  float*          ls      = (float*)p;          p += (size_t)T * B * 4;

  // ---- one-time prep ----
  cvt_bf16_kernel<<<(B * S * H) / 2048, 256, 0, stream>>>(keys, keys_bf);
  cvt_fp8_kernel<<<((size_t)V * H) / 2048, 256, 0, stream>>>(
      out_w, (unsigned int*)outw8);
  cvt_bf16_kernel<<<(H * H) / 2048, 256, 0, stream>>>(Ua_w, Uaw_bf);
  cvt_bf16_kernel<<<(H * H) / 2048, 256, 0, stream>>>(Wa_w, fusedW);
  cvt_bf16_kernel<<<(3 * H * H) / 2048, 256, 0, stream>>>(gru_w_hh,
                                                          fusedW + (size_t)H * H);
  build_fused_bias<<<(4 * H) / 256, 256, 0, stream>>>(Wa_b, gru_b_hh, fusedB);
  cvt_split_wih<<<(3 * H * 2 * H) / 2048, 256, 0, stream>>>(gru_w_ih, Wemb_bf,
                                                            Wctx_bf);
  embed_all_kernel<<<(T * B * H / 8) / 256, 256, 0, stream>>>(target, embedding,
                                                              embAll);
  cvt_bf16_kernel<<<(B * H) / 2048, 256, 0, stream>>>(enc_hidden, hAll);

  // Uk_bf = bf16(keys @ Ua_w^T + Ua_b)
  gemm_mfma<128, 128, 1, 0, 2>
      <<<dim3(H / 128, (B * S) / 128), 256, 0, stream>>>(
          keys_bf, Uaw_bf, Ua_b, nullptr, Uk_bf, B * S, H, H, H);
  // giE = embAll @ Wemb^T + b_ih
  gemm_mfma<128, 128, 0, 1, 2>
      <<<dim3((T * B) / 128, 3 * H / 128), 256, 0, stream>>>(
          embAll, Wemb_bf, gru_b_ih, giE, nullptr, T * B, 3 * H, H, 3 * H);

  const float* h_in = enc_hidden;
  float* hbufs[2] = {hA, hB};

  for (int t = 0; t < T; ++t) {
    const unsigned short* hbf_in = hAll + (size_t)t * B * H;
    unsigned short* hbf_out = hAll + (size_t)(t + 1) * B * H;
    unsigned int* h8_out = (unsigned int*)(hAll8 + (size_t)t * B * H);
    float* h_out = hbufs[t & 1];

    // wq | gh = h @ [Wa_w; w_hh]^T + [Wa_b; b_hh]
    gemm_mfma<64, 64, 0, 1, 5><<<dim3(B / 64, 4 * H / 64), 256, 0, stream>>>(
        hbf_in, fusedW, fusedB, wqgh, nullptr, B, 4 * H, H, 4 * H);
    attn_fused_kernel<<<B, 256, 0, stream>>>(
        wqgh, Uk_bf, keys_bf, Va_w, Va_b, out_attn, ctx_bf, t);
    // gi = giE[t] + ctx @ Wctx^T
    gemm_mfma<64, 64, 2, 1, 5><<<dim3(B / 64, 3 * H / 64), 256, 0, stream>>>(
        ctx_bf, Wctx_bf, giE + (size_t)t * B * 3 * H, gi, nullptr,
        B, 3 * H, H, 3 * H);
    gru_kernel<<<(B * H / 4) / 256, 256, 0, stream>>>(gi, wqgh, h_in, h_out,
                                                      hbf_out, h8_out);

    h_in = h_out;
  }

  // batched vocab projection over all steps, fp8 e4m3 inputs (BK=64, NT=16)
  gemm_fp8_logits<<<dim3((T * B) / 128, V / 128), 256, 0, stream>>>(
      hAll8, outw8, out_b, logits_bf, parts, T * B, V, H, V, 500);
  logsm_reduce_kernel<<<T * B, 256, 0, stream>>>(parts, ls, 500);
  logsm_sub_kernel<<<dim3((V + 2047) / 2048, T * B), 256, 0, stream>>>(
      logits_bf, ls, out_dec);

  copy_kernel<<<(B * H + 255) / 256, 256, 0, stream>>>(h_in, out_h, B * H);
}

// Round 17
// 941.482 us; speedup vs baseline: 2.0704x; 1.0010x over previous
//
#include <hip/hip_runtime.h>
#include <math.h>

#define H 1024
#define V 32000
#define B 256
#define S 64
#define T 10

#define GBK 32

typedef __attribute__((ext_vector_type(8))) short bf16x8;
typedef __attribute__((ext_vector_type(4))) float f32x4;

static __device__ __forceinline__ unsigned short f2bf(float f) {
  unsigned int u = __float_as_uint(f);
  u += 0x7fff + ((u >> 16) & 1);   // round-to-nearest-even
  return (unsigned short)(u >> 16);
}
static __device__ __forceinline__ float bf2f(unsigned short u) {
  return __uint_as_float(((unsigned int)u) << 16);
}
static __device__ __forceinline__ float fast_tanh(float x) {
  float e = __expf(2.f * x);
  return 1.f - 2.f * __builtin_amdgcn_rcpf(e + 1.f);
}
static __device__ __forceinline__ float fast_sigmoid(float x) {
  return __builtin_amdgcn_rcpf(1.f + __expf(-x));
}

static __device__ __forceinline__ void load_lds16(const void* g, void* l) {
  __builtin_amdgcn_global_load_lds(
      (const __attribute__((address_space(1))) unsigned int*)g,
      (__attribute__((address_space(3))) unsigned int*)l, 16, 0, 0);
}

// swizzled element offset within one bf16 LDS tile (row stride 32 elems/64B)
static __device__ __forceinline__ int lds_off(int row, int g) {
  return row * GBK + ((g ^ ((row >> 1) & 3)) * 8);
}

// ---------------------------------------------------------------------------
// bf16 MFMA GEMM, TMxTN tile, BK=32, 4 waves (2x2), STAGES-deep pipeline with
// counted vmcnt + raw barrier.  C = A @ W^T (+ epilogue).
// MODE 0: C fp32 = acc + bias[col]
// MODE 1: Cb bf16 = acc + bias[col]
// MODE 2: C fp32 = acc + aux[row*ldc + col]
// ---------------------------------------------------------------------------
template <int TM, int TN, int MODE, int GRIDMODE, int STAGES>
__global__ __launch_bounds__(256) void gemm_mfma(
    const unsigned short* __restrict__ A, const unsigned short* __restrict__ W,
    const float* __restrict__ aux, float* __restrict__ C,
    unsigned short* __restrict__ Cb,
    int M, int N, int K, int ldc) {
  constexpr int FM = TM / 32;
  constexpr int FN = TN / 32;
  constexpr int CA = TM / 64;
  constexpr int CB = TN / 64;
  constexpr int LOADS = CA + CB;
  constexpr int F = (STAGES >= 3) ? (STAGES - 2) : 0;

  __shared__ unsigned short lsA[STAGES][TM * GBK];
  __shared__ unsigned short lsB[STAGES][TN * GBK];
  const int tid = threadIdx.x;
  const int lane = tid & 63;
  const int w = tid >> 6;

  int mIdx, nIdx;
  if constexpr (GRIDMODE == 1) {
    const int nwg = gridDim.x * gridDim.y;
    const int orig = blockIdx.y * gridDim.x + blockIdx.x;
    const int q = nwg >> 3, rr = nwg & 7;
    const int xcd = orig & 7, rest = orig >> 3;
    const int wgid =
        (xcd < rr ? xcd * (q + 1) : rr * (q + 1) + (xcd - rr) * q) + rest;
    mIdx = wgid % gridDim.x;
    nIdx = wgid / gridDim.x;
  } else {
    mIdx = blockIdx.y;
    nIdx = blockIdx.x;
  }
  const int mBase = mIdx * TM;
  const int nBase = nIdx * TN;
  const int rowBase = (w >> 1) * (TM / 2);
  const int colBase = (w & 1) * (TN / 2);

  const int fr = lane & 15;
  const int fkU = lane >> 4;
  const int fg = lane >> 4;

  f32x4 acc[FM][FN] = {};

  auto STAGE = [&](int buf, int k0) {
#pragma unroll
    for (int i = 0; i < CA; ++i) {
      int chunk = i * 256 + tid;
      int row = chunk >> 2;
      int u = chunk & 3;
      int col = (u ^ ((row >> 1) & 3)) * 8;
      load_lds16(A + (size_t)(mBase + row) * K + k0 + col,
                 &lsA[buf][chunk * 8]);
    }
#pragma unroll
    for (int i = 0; i < CB; ++i) {
      int chunk = i * 256 + tid;
      int row = chunk >> 2;
      int u = chunk & 3;
      int col = (u ^ ((row >> 1) & 3)) * 8;
      load_lds16(W + (size_t)(nBase + row) * K + k0 + col,
                 &lsB[buf][chunk * 8]);
    }
  };

  const int NT = K / GBK;
  for (int s = 0; s <= F && s < NT; ++s) STAGE(s % STAGES, s * GBK);

  for (int t = 0; t < NT; ++t) {
    const int rem = NT - 1 - t;
    if (rem >= F) {
      asm volatile("s_waitcnt vmcnt(%0)\n\ts_barrier" :: "i"(F * LOADS)
                   : "memory");
    } else if (rem == 2) {
      asm volatile("s_waitcnt vmcnt(%0)\n\ts_barrier" :: "i"(2 * LOADS)
                   : "memory");
    } else if (rem == 1) {
      asm volatile("s_waitcnt vmcnt(%0)\n\ts_barrier" :: "i"(1 * LOADS)
                   : "memory");
    } else {
      asm volatile("s_waitcnt vmcnt(0)\n\ts_barrier" ::: "memory");
    }
    if (t + F + 1 < NT) STAGE((t + F + 1) % STAGES, (t + F + 1) * GBK);

    const int cb = t % STAGES;
    bf16x8 af[FM], bfr[FN];
#pragma unroll
    for (int m = 0; m < FM; ++m)
      af[m] = *(const bf16x8*)&lsA[cb][lds_off(rowBase + m * 16 + fr, fkU)];
#pragma unroll
    for (int n = 0; n < FN; ++n)
      bfr[n] = *(const bf16x8*)&lsB[cb][lds_off(colBase + n * 16 + fr, fkU)];
#pragma unroll
    for (int m = 0; m < FM; ++m)
#pragma unroll
      for (int n = 0; n < FN; ++n)
        acc[m][n] = __builtin_amdgcn_mfma_f32_16x16x32_bf16(
            af[m], bfr[n], acc[m][n], 0, 0, 0);
  }

#pragma unroll
  for (int m = 0; m < FM; ++m) {
    int colg[FN];
    float bv[FN];
#pragma unroll
    for (int n = 0; n < FN; ++n) {
      colg[n] = nBase + colBase + n * 16 + fr;
      if constexpr (MODE != 2) bv[n] = aux[colg[n]];
    }
#pragma unroll
    for (int r = 0; r < 4; ++r) {
      const int rowg = mBase + rowBase + m * 16 + fg * 4 + r;
      float v[FN];
#pragma unroll
      for (int n = 0; n < FN; ++n) {
        if constexpr (MODE == 2)
          v[n] = acc[m][n][r] + aux[(size_t)rowg * ldc + colg[n]];
        else
          v[n] = acc[m][n][r] + bv[n];
        if constexpr (MODE == 1)
          Cb[(size_t)rowg * ldc + colg[n]] = f2bf(v[n]);
        else
          C[(size_t)rowg * ldc + colg[n]] = v[n];
      }
    }
  }
}

// ---------------------------------------------------------------------------
// Fused gi-GEMM + GRU, gate-colocating tile. grid (B/64, H/32) = 128 blocks.
// Each block: 64 b-rows x 32 j-cols, all 3 gates (96 W-rows: {j, H+j, 2H+j}).
// Wave grid 4x1: wave w handles A-rows w*16..+15, all 96 W-rows (FN=6).
// Thread (fr) holds gates r/z/n for jj=fr at acc{0,2,4} and jj=16+fr at
// acc{1,3,5} -> GRU entirely in-register in the epilogue.
// BK=64 (128 B rows, 8 16B-units, swizzle f(row)=row&7 -> 2-way free),
// 3-stage counted pipeline (LOADS=5 -> vmcnt(5)).
// ---------------------------------------------------------------------------
__global__ __launch_bounds__(256) void gemm_gru3(
    const unsigned short* __restrict__ A,     // ctx_bf [B,H]
    const unsigned short* __restrict__ W3,    // Wctx_bf [3H,H]
    const float* __restrict__ giE_t,          // [B,3H]
    const float* __restrict__ wqgh,           // [B,4H] (gh at +H)
    const float* __restrict__ h_in,           // [B,H]
    float* __restrict__ h_out,                // [B,H]
    unsigned short* __restrict__ h_out_bf,    // [B,H]
    unsigned char* __restrict__ h_out_f8) {   // [B,H]
  constexpr int BK = 64;
  constexpr int STAGES = 3;
  constexpr int LOADS = 5;                    // 2 A + 3 W iters per thread
  __shared__ unsigned short lsA[STAGES][64 * BK];   // 8 KB/stage
  __shared__ unsigned short lsW[STAGES][96 * BK];   // 12 KB/stage
  const int tid = threadIdx.x;
  const int lane = tid & 63;
  const int w = tid >> 6;
  const int mBase = blockIdx.x * 64;          // b rows (x fastest: share W)
  const int jBase = blockIdx.y * 32;          // j cols
  const int fr = lane & 15;
  const int fkU = lane >> 4;                  // 0..3
  const int fg = lane >> 4;

  f32x4 acc[6] = {};

  auto STAGE = [&](int buf, int k0) {
#pragma unroll
    for (int i = 0; i < 2; ++i) {             // A: 512 chunks of 16B
      int c = i * 256 + tid;
      int row = c >> 3, u = c & 7;
      int col = (u ^ (row & 7)) * 8;          // pre-swizzled global source
      load_lds16(A + (size_t)(mBase + row) * H + k0 + col, &lsA[buf][c * 8]);
    }
#pragma unroll
    for (int i = 0; i < 3; ++i) {             // W: 768 chunks
      int c = i * 256 + tid;
      int wr = c >> 3, u = c & 7;
      int gate = wr >> 5, jj = wr & 31;
      int col = (u ^ (wr & 7)) * 8;
      load_lds16(W3 + (size_t)(gate * H + jBase + jj) * H + k0 + col,
                 &lsW[buf][c * 8]);
    }
  };

  const int NT = H / BK;  // 16
  STAGE(0, 0);
  STAGE(1, BK);
  for (int t = 0; t < NT; ++t) {
    const int rem = NT - 1 - t;
    if (rem >= 1) {
      asm volatile("s_waitcnt vmcnt(%0)\n\ts_barrier" :: "i"(LOADS)
                   : "memory");
    } else {
      asm volatile("s_waitcnt vmcnt(0)\n\ts_barrier" ::: "memory");
    }
    if (t + 2 < NT) STAGE((t + 2) % STAGES, (t + 2) * BK);
    const int cb = t % STAGES;
    const int arow = w * 16 + fr;
#pragma unroll
    for (int ks = 0; ks < 2; ++ks) {
      const int u = ks * 4 + fkU;
      bf16x8 af =
          *(const bf16x8*)&lsA[cb][arow * BK + ((u ^ (arow & 7)) * 8)];
#pragma unroll
      for (int n = 0; n < 6; ++n) {
        int wr = n * 16 + fr;
        bf16x8 bf =
            *(const bf16x8*)&lsW[cb][wr * BK + ((u ^ (wr & 7)) * 8)];
        acc[n] = __builtin_amdgcn_mfma_f32_16x16x32_bf16(af, bf, acc[n],
                                                         0, 0, 0);
      }
    }
  }

  // epilogue: full GRU per element (thread holds all 3 gates)
#pragma unroll
  for (int r = 0; r < 4; ++r) {
    const int b = mBase + w * 16 + fg * 4 + r;
    const float* giE_row = giE_t + (size_t)b * 3 * H;
    const float* gh_row = wqgh + (size_t)b * 4 * H + H;
#pragma unroll
    for (int jjg = 0; jjg < 2; ++jjg) {
      const int col = jBase + jjg * 16 + fr;
      float gr = acc[0 + jjg][r] + giE_row[col];
      float gz = acc[2 + jjg][r] + giE_row[H + col];
      float gn = acc[4 + jjg][r] + giE_row[2 * H + col];
      float rr = fast_sigmoid(gr + gh_row[col]);
      float zz = fast_sigmoid(gz + gh_row[H + col]);
      float nn = fast_tanh(gn + rr * gh_row[2 * H + col]);
      float hp = h_in[(size_t)b * H + col];
      float ho = (1.f - zz) * nn + zz * hp;
      h_out[(size_t)b * H + col] = ho;
      h_out_bf[(size_t)b * H + col] = f2bf(ho);
      int p8 = __builtin_amdgcn_cvt_pk_fp8_f32(ho, ho, 0, false);
      h_out_f8[(size_t)b * H + col] = (unsigned char)(p8 & 0xff);
    }
  }
}

// ---------------------------------------------------------------------------
// fp8 e4m3 MFMA GEMM for the vocab projection. 128x128 tile, BK=64, 2-stage.
// LDS swizzle f(row)=(row>>1)&3 -> 2-way (free).
// ---------------------------------------------------------------------------
__global__ __launch_bounds__(256) void gemm_fp8_logits(
    const unsigned char* __restrict__ A8, const unsigned char* __restrict__ W8,
    const float* __restrict__ bias, unsigned short* __restrict__ Cb,
    float* __restrict__ partials, int M, int N, int K, int ldc, int pstride) {
  constexpr int BK = 64;
  __shared__ __align__(16) unsigned char lsA[2][128 * BK];
  __shared__ __align__(16) unsigned char lsB[2][128 * BK];
  const int tid = threadIdx.x;
  const int lane = tid & 63;
  const int w = tid >> 6;

  const int nwg = gridDim.x * gridDim.y;
  const int orig = blockIdx.y * gridDim.x + blockIdx.x;
  const int q = nwg >> 3, rr = nwg & 7;
  const int xcd = orig & 7, rest = orig >> 3;
  const int wgid =
      (xcd < rr ? xcd * (q + 1) : rr * (q + 1) + (xcd - rr) * q) + rest;
  const int mIdx = wgid % gridDim.x;
  const int nIdx = wgid / gridDim.x;
  const int mBase = mIdx * 128;
  const int nBase = nIdx * 128;
  const int rowBase = (w >> 1) * 64;
  const int colBase = (w & 1) * 64;
  const int fr = lane & 15;
  const int fkU = lane >> 4;
  const int fg = lane >> 4;

  f32x4 acc[4][4] = {};

  auto STAGE = [&](int buf, int k0) {
#pragma unroll
    for (int i = 0; i < 2; ++i) {
      int c = i * 256 + tid;
      int row = c >> 2;
      int u = c & 3;
      int col = (u ^ ((row >> 1) & 3)) * 16;
      load_lds16(A8 + (size_t)(mBase + row) * K + k0 + col, &lsA[buf][c * 16]);
    }
#pragma unroll
    for (int i = 0; i < 2; ++i) {
      int c = i * 256 + tid;
      int row = c >> 2;
      int u = c & 3;
      int col = (u ^ ((row >> 1) & 3)) * 16;
      load_lds16(W8 + (size_t)(nBase + row) * K + k0 + col, &lsB[buf][c * 16]);
    }
  };

  const int NT = K / BK;
  STAGE(0, 0);
  int cb = 0;
  for (int t = 0; t < NT; ++t) {
    asm volatile("s_waitcnt vmcnt(0)\n\ts_barrier" ::: "memory");
    if (t + 1 < NT) STAGE(cb ^ 1, (t + 1) * BK);
#pragma unroll
    for (int ks = 0; ks < 2; ++ks) {
      const int u = ks * 2 + (fkU >> 1);
      const int sub = (fkU & 1) * 8;
      long long af[4], bf[4];
#pragma unroll
      for (int m = 0; m < 4; ++m) {
        int row = rowBase + m * 16 + fr;
        af[m] = *(const long long*)
            &lsA[cb][row * BK + ((u ^ ((row >> 1) & 3)) << 4) + sub];
      }
#pragma unroll
      for (int n = 0; n < 4; ++n) {
        int row = colBase + n * 16 + fr;
        bf[n] = *(const long long*)
            &lsB[cb][row * BK + ((u ^ ((row >> 1) & 3)) << 4) + sub];
      }
#pragma unroll
      for (int m = 0; m < 4; ++m)
#pragma unroll
        for (int n = 0; n < 4; ++n)
          acc[m][n] = __builtin_amdgcn_mfma_f32_16x16x32_fp8_fp8(
              af[m], bf[n], acc[m][n], 0, 0, 0);
    }
    cb ^= 1;
  }

#pragma unroll
  for (int m = 0; m < 4; ++m) {
    int colg[4];
    float bv[4];
#pragma unroll
    for (int n = 0; n < 4; ++n) {
      colg[n] = nBase + colBase + n * 16 + fr;
      bv[n] = bias[colg[n]];
    }
#pragma unroll
    for (int r = 0; r < 4; ++r) {
      const int rowg = mBase + rowBase + m * 16 + fg * 4 + r;
      float v[4];
#pragma unroll
      for (int n = 0; n < 4; ++n) {
        v[n] = acc[m][n][r] + bv[n];
        Cb[(size_t)rowg * ldc + colg[n]] = f2bf(v[n]);
      }
      float mx = fmaxf(fmaxf(v[0], v[1]), fmaxf(v[2], v[3]));
      mx = fmaxf(mx, __shfl_xor(mx, 1, 64));
      mx = fmaxf(mx, __shfl_xor(mx, 2, 64));
      mx = fmaxf(mx, __shfl_xor(mx, 4, 64));
      mx = fmaxf(mx, __shfl_xor(mx, 8, 64));
      float se = __expf(v[0] - mx) + __expf(v[1] - mx) +
                 __expf(v[2] - mx) + __expf(v[3] - mx);
      se += __shfl_xor(se, 1, 64);
      se += __shfl_xor(se, 2, 64);
      se += __shfl_xor(se, 4, 64);
      se += __shfl_xor(se, 8, 64);
      if (fr == 0) {
        float2* pp = (float2*)partials;
        pp[(size_t)rowg * pstride + nIdx * 2 + (w & 1)] = make_float2(mx, se);
      }
    }
  }
}

// ---------------------------------------------------------------------------
__global__ __launch_bounds__(256) void cvt_bf16_kernel(
    const float* __restrict__ src, unsigned short* __restrict__ dst) {
  size_t i = ((size_t)blockIdx.x * 256 + threadIdx.x) * 8;
  float4 a = *(const float4*)&src[i];
  float4 b = *(const float4*)&src[i + 4];
  ushort4 lo, hi;
  lo.x = f2bf(a.x); lo.y = f2bf(a.y); lo.z = f2bf(a.z); lo.w = f2bf(a.w);
  hi.x = f2bf(b.x); hi.y = f2bf(b.y); hi.z = f2bf(b.z); hi.w = f2bf(b.w);
  *(ushort4*)&dst[i] = lo;
  *(ushort4*)&dst[i + 4] = hi;
}

// fp32 -> fp8 e4m3, 8 elems/thread
__global__ __launch_bounds__(256) void cvt_fp8_kernel(
    const float* __restrict__ src, unsigned int* __restrict__ dst) {
  size_t i = (size_t)blockIdx.x * 256 + threadIdx.x;
  float4 a = ((const float4*)src)[i * 2];
  float4 b = ((const float4*)src)[i * 2 + 1];
  int lo = __builtin_amdgcn_cvt_pk_fp8_f32(a.x, a.y, 0, false);
  lo = __builtin_amdgcn_cvt_pk_fp8_f32(a.z, a.w, lo, true);
  int hi = __builtin_amdgcn_cvt_pk_fp8_f32(b.x, b.y, 0, false);
  hi = __builtin_amdgcn_cvt_pk_fp8_f32(b.z, b.w, hi, true);
  ((int2*)dst)[i] = make_int2(lo, hi);
}

__global__ __launch_bounds__(256) void cvt_split_wih(
    const float* __restrict__ w_ih, unsigned short* __restrict__ Wemb,
    unsigned short* __restrict__ Wctx) {
  size_t base = ((size_t)blockIdx.x * 256 + threadIdx.x) * 8;
  int row = (int)(base >> 11);
  int col = (int)(base & 2047);
  float4 a = *(const float4*)&w_ih[base];
  float4 b = *(const float4*)&w_ih[base + 4];
  ushort4 lo, hi;
  lo.x = f2bf(a.x); lo.y = f2bf(a.y); lo.z = f2bf(a.z); lo.w = f2bf(a.w);
  hi.x = f2bf(b.x); hi.y = f2bf(b.y); hi.z = f2bf(b.z); hi.w = f2bf(b.w);
  unsigned short* dst = (col < H) ? (Wemb + (size_t)row * H + col)
                                  : (Wctx + (size_t)row * H + col - H);
  *(ushort4*)dst = lo;
  *(ushort4*)(dst + 4) = hi;
}

__global__ __launch_bounds__(256) void build_fused_bias(
    const float* __restrict__ Wa_b, const float* __restrict__ b_hh,
    float* __restrict__ fb) {
  int i = blockIdx.x * 256 + threadIdx.x;
  fb[i] = (i < H) ? Wa_b[i] : b_hh[i - H];
}

__global__ __launch_bounds__(256) void embed_all_kernel(
    const int* __restrict__ target, const float* __restrict__ emb,
    unsigned short* __restrict__ embAll) {
  int idx = blockIdx.x * 256 + threadIdx.x;
  int h8 = (idx & 127) * 8;
  int tb = idx >> 7;
  int t = tb >> 8;
  int b = tb & 255;
  int tok = (t == 0) ? 0 : target[b * T + (t - 1)];
  const float* e = emb + (size_t)tok * H + h8;
  float4 a = *(const float4*)e;
  float4 c = *(const float4*)(e + 4);
  ushort4 lo, hi;
  lo.x = f2bf(a.x); lo.y = f2bf(a.y); lo.z = f2bf(a.z); lo.w = f2bf(a.w);
  hi.x = f2bf(c.x); hi.y = f2bf(c.y); hi.z = f2bf(c.z); hi.w = f2bf(c.w);
  unsigned short* d = embAll + (size_t)tb * H + h8;
  *(ushort4*)d = lo;
  *(ushort4*)(d + 4) = hi;
}

// ---------------------------------------------------------------------------
// Fused attention: scores -> softmax -> ctx, one block per b.
// ---------------------------------------------------------------------------
__global__ __launch_bounds__(256) void attn_fused_kernel(
    const float* __restrict__ wqgh, const unsigned short* __restrict__ Uk_bf,
    const unsigned short* __restrict__ keys_bf,
    const float* __restrict__ Va_w, const float* __restrict__ Va_b,
    float* __restrict__ out_attn, unsigned short* __restrict__ ctx_bf, int t) {
  const int b = blockIdx.x;
  const int tid = threadIdx.x;
  __shared__ float wqs[H];
  __shared__ float vas[H];
  __shared__ float sw[S];

  ((float4*)wqs)[tid] = ((const float4*)(wqgh + (size_t)b * 4 * H))[tid];
  ((float4*)vas)[tid] = ((const float4*)Va_w)[tid];
  __syncthreads();

  const int s = tid >> 2;
  const int hc = (tid & 3) * 256;
  const unsigned short* uk = Uk_bf + ((size_t)b * S + s) * H + hc;
  float sum = 0.f;
#pragma unroll 4
  for (int i = 0; i < 256; i += 8) {
    bf16x8 u = *(const bf16x8*)&uk[i];
#pragma unroll
    for (int j = 0; j < 8; ++j) {
      float e = fast_tanh(wqs[hc + i + j] + bf2f((unsigned short)u[j]));
      sum += e * vas[hc + i + j];
    }
  }
  sum += __shfl_xor(sum, 1, 64);
  sum += __shfl_xor(sum, 2, 64);
  if ((tid & 3) == 0) sw[s] = sum + Va_b[0];
  __syncthreads();

  if (tid < 64) {
    float v = sw[tid];
    float m = v;
    for (int off = 32; off > 0; off >>= 1) m = fmaxf(m, __shfl_xor(m, off, 64));
    float e = __expf(v - m);
    float sm = e;
    for (int off = 32; off > 0; off >>= 1) sm += __shfl_xor(sm, off, 64);
    float wv = e / sm;
    sw[tid] = wv;
    out_attn[((size_t)b * T + t) * S + tid] = wv;
  }
  __syncthreads();

  const unsigned short* kb = keys_bf + (size_t)b * S * H + tid * 4;
  float c0 = 0.f, c1 = 0.f, c2 = 0.f, c3 = 0.f;
#pragma unroll 8
  for (int s2 = 0; s2 < S; ++s2) {
    float wv = sw[s2];
    ushort4 kv = *(const ushort4*)&kb[(size_t)s2 * H];
    c0 += wv * bf2f(kv.x);
    c1 += wv * bf2f(kv.y);
    c2 += wv * bf2f(kv.z);
    c3 += wv * bf2f(kv.w);
  }
  ushort4 o;
  o.x = f2bf(c0); o.y = f2bf(c1); o.z = f2bf(c2); o.w = f2bf(c3);
  *(ushort4*)&ctx_bf[(size_t)b * H + tid * 4] = o;
}

// ---------------------------------------------------------------------------
// batched log-softmax: reduce partials -> ls[row] for all T*B rows
// ---------------------------------------------------------------------------
__global__ __launch_bounds__(256) void logsm_reduce_kernel(
    const float* __restrict__ partials, float* __restrict__ ls, int P) {
  const int row = blockIdx.x;
  const int tid = threadIdx.x;
  const float2* pp = (const float2*)partials + (size_t)row * P;
  __shared__ float red[256];
  float mx = -INFINITY;
  for (int i = tid; i < P; i += 256) mx = fmaxf(mx, pp[i].x);
  red[tid] = mx;
  __syncthreads();
  for (int off = 128; off > 0; off >>= 1) {
    if (tid < off) red[tid] = fmaxf(red[tid], red[tid + off]);
    __syncthreads();
  }
  mx = red[0];
  __syncthreads();
  float sm = 0.f;
  for (int i = tid; i < P; i += 256) sm += pp[i].y * __expf(pp[i].x - mx);
  red[tid] = sm;
  __syncthreads();
  for (int off = 128; off > 0; off >>= 1) {
    if (tid < off) red[tid] += red[tid + off];
    __syncthreads();
  }
  if (tid == 0) ls[row] = mx + __logf(red[0]);
}

// dec[b, t, :] = bf2f(logits_bf[tb, :]) - ls[tb];  tb = t*B + b
__global__ __launch_bounds__(256) void logsm_sub_kernel(
    const unsigned short* __restrict__ logits_bf, const float* __restrict__ ls,
    float* __restrict__ dec) {
  const int tb = blockIdx.y;
  const int t = tb >> 8;
  const int b = tb & 255;
  const int i8 = (blockIdx.x * 256 + threadIdx.x) * 8;
  if (i8 < V) {
    float l = ls[tb];
    const unsigned short* src = logits_bf + (size_t)tb * V + i8;
    bf16x8 u = *(const bf16x8*)src;
    float* d = dec + (size_t)b * T * V + (size_t)t * V + i8;
    float4 o0, o1;
    o0.x = bf2f((unsigned short)u[0]) - l; o0.y = bf2f((unsigned short)u[1]) - l;
    o0.z = bf2f((unsigned short)u[2]) - l; o0.w = bf2f((unsigned short)u[3]) - l;
    o1.x = bf2f((unsigned short)u[4]) - l; o1.y = bf2f((unsigned short)u[5]) - l;
    o1.z = bf2f((unsigned short)u[6]) - l; o1.w = bf2f((unsigned short)u[7]) - l;
    *(float4*)d = o0;
    *(float4*)(d + 4) = o1;
  }
}

__global__ __launch_bounds__(256) void copy_kernel(
    const float* __restrict__ src, float* __restrict__ dst, int n) {
  int i = blockIdx.x * 256 + threadIdx.x;
  if (i < n) dst[i] = src[i];
}

// ---------------------------------------------------------------------------
extern "C" void kernel_launch(void* const* d_in, const int* in_sizes, int n_in,
                              void* d_out, int out_size, void* d_ws, size_t ws_size,
                              hipStream_t stream) {
  const float* keys       = (const float*)d_in[0];
  const float* enc_hidden = (const float*)d_in[1];
  const int*   target     = (const int*)d_in[2];
  const float* embedding  = (const float*)d_in[3];
  const float* Wa_w = (const float*)d_in[4];
  const float* Wa_b = (const float*)d_in[5];
  const float* Ua_w = (const float*)d_in[6];
  const float* Ua_b = (const float*)d_in[7];
  const float* Va_w = (const float*)d_in[8];
  const float* Va_b = (const float*)d_in[9];
  const float* gru_w_ih = (const float*)d_in[10];
  const float* gru_w_hh = (const float*)d_in[11];
  const float* gru_b_ih = (const float*)d_in[12];
  const float* gru_b_hh = (const float*)d_in[13];
  const float* out_w = (const float*)d_in[14];
  const float* out_b = (const float*)d_in[15];

  float* out = (float*)d_out;
  float* out_dec  = out;
  float* out_h    = out + (size_t)B * T * V;
  float* out_attn = out + (size_t)B * T * V + (size_t)B * H;

  // ---- workspace ----
  char* p = (char*)d_ws;
  unsigned short* keys_bf = (unsigned short*)p; p += (size_t)B * S * H * 2;
  unsigned char*  outw8   = (unsigned char*)p;  p += (size_t)V * H;
  unsigned short* Uaw_bf  = (unsigned short*)p; p += (size_t)H * H * 2;
  unsigned short* fusedW  = (unsigned short*)p; p += (size_t)4 * H * H * 2;
  float*          fusedB  = (float*)p;          p += (size_t)4 * H * 4;
  unsigned short* Wemb_bf = (unsigned short*)p; p += (size_t)3 * H * H * 2;
  unsigned short* Wctx_bf = (unsigned short*)p; p += (size_t)3 * H * H * 2;
  unsigned short* embAll  = (unsigned short*)p; p += (size_t)T * B * H * 2;
  unsigned short* Uk_bf   = (unsigned short*)p; p += (size_t)B * S * H * 2;
  float*          giE     = (float*)p;          p += (size_t)T * B * 3 * H * 4;
  float*          wqgh    = (float*)p;          p += (size_t)B * 4 * H * 4;
  unsigned short* ctx_bf  = (unsigned short*)p; p += (size_t)B * H * 2;
  float*          hA      = (float*)p;          p += (size_t)B * H * 4;
  float*          hB      = (float*)p;          p += (size_t)B * H * 4;
  unsigned short* hAll    = (unsigned short*)p; p += (size_t)(T + 1) * B * H * 2;
  unsigned char*  hAll8   = (unsigned char*)p;  p += (size_t)T * B * H;
  unsigned short* logits_bf = (unsigned short*)p; p += (size_t)T * B * V * 2;
  float*          parts   = (float*)p;          p += (size_t)T * B * 500 * 2 * 4;
  float*          ls      = (float*)p;          p += (size_t)T * B * 4;

  // ---- one-time prep ----
  cvt_bf16_kernel<<<(B * S * H) / 2048, 256, 0, stream>>>(keys, keys_bf);
  cvt_fp8_kernel<<<((size_t)V * H) / 2048, 256, 0, stream>>>(
      out_w, (unsigned int*)outw8);
  cvt_bf16_kernel<<<(H * H) / 2048, 256, 0, stream>>>(Ua_w, Uaw_bf);
  cvt_bf16_kernel<<<(H * H) / 2048, 256, 0, stream>>>(Wa_w, fusedW);
  cvt_bf16_kernel<<<(3 * H * H) / 2048, 256, 0, stream>>>(gru_w_hh,
                                                          fusedW + (size_t)H * H);
  build_fused_bias<<<(4 * H) / 256, 256, 0, stream>>>(Wa_b, gru_b_hh, fusedB);
  cvt_split_wih<<<(3 * H * 2 * H) / 2048, 256, 0, stream>>>(gru_w_ih, Wemb_bf,
                                                            Wctx_bf);
  embed_all_kernel<<<(T * B * H / 8) / 256, 256, 0, stream>>>(target, embedding,
                                                              embAll);
  cvt_bf16_kernel<<<(B * H) / 2048, 256, 0, stream>>>(enc_hidden, hAll);

  // Uk_bf = bf16(keys @ Ua_w^T + Ua_b)
  gemm_mfma<128, 128, 1, 0, 2>
      <<<dim3(H / 128, (B * S) / 128), 256, 0, stream>>>(
          keys_bf, Uaw_bf, Ua_b, nullptr, Uk_bf, B * S, H, H, H);
  // giE = embAll @ Wemb^T + b_ih
  gemm_mfma<128, 128, 0, 1, 2>
      <<<dim3((T * B) / 128, 3 * H / 128), 256, 0, stream>>>(
          embAll, Wemb_bf, gru_b_ih, giE, nullptr, T * B, 3 * H, H, 3 * H);

  const float* h_in = enc_hidden;
  float* hbufs[2] = {hA, hB};

  for (int t = 0; t < T; ++t) {
    const unsigned short* hbf_in = hAll + (size_t)t * B * H;
    unsigned short* hbf_out = hAll + (size_t)(t + 1) * B * H;
    unsigned char* h8_out = hAll8 + (size_t)t * B * H;
    float* h_out = hbufs[t & 1];

    // wq | gh = h @ [Wa_w; w_hh]^T + [Wa_b; b_hh]
    gemm_mfma<64, 64, 0, 1, 5><<<dim3(B / 64, 4 * H / 64), 256, 0, stream>>>(
        hbf_in, fusedW, fusedB, wqgh, nullptr, B, 4 * H, H, 4 * H);
    attn_fused_kernel<<<B, 256, 0, stream>>>(
        wqgh, Uk_bf, keys_bf, Va_w, Va_b, out_attn, ctx_bf, t);
    // fused: gi = giE[t] + ctx @ Wctx^T  AND  GRU combine -> h (fp32/bf16/fp8)
    gemm_gru3<<<dim3(B / 64, H / 32), 256, 0, stream>>>(
        ctx_bf, Wctx_bf, giE + (size_t)t * B * 3 * H, wqgh, h_in, h_out,
        hbf_out, h8_out);

    h_in = h_out;
  }

  // batched vocab projection over all steps, fp8 e4m3 inputs (BK=64, NT=16)
  gemm_fp8_logits<<<dim3((T * B) / 128, V / 128), 256, 0, stream>>>(
      hAll8, outw8, out_b, logits_bf, parts, T * B, V, H, V, 500);
  logsm_reduce_kernel<<<T * B, 256, 0, stream>>>(parts, ls, 500);
  logsm_sub_kernel<<<dim3((V + 2047) / 2048, T * B), 256, 0, stream>>>(
      logits_bf, ls, out_dec);

  copy_kernel<<<(B * H + 255) / 256, 256, 0, stream>>>(h_in, out_h, B * H);
}

// Round 18
// 935.585 us; speedup vs baseline: 2.0834x; 1.0063x over previous
//
#include <hip/hip_runtime.h>
#include <math.h>

#define H 1024
#define V 32000
#define B 256
#define S 64
#define T 10

#define GBK 32

typedef __attribute__((ext_vector_type(8))) short bf16x8;
typedef __attribute__((ext_vector_type(4))) float f32x4;

static __device__ __forceinline__ unsigned short f2bf(float f) {
  unsigned int u = __float_as_uint(f);
  u += 0x7fff + ((u >> 16) & 1);   // round-to-nearest-even
  return (unsigned short)(u >> 16);
}
static __device__ __forceinline__ float bf2f(unsigned short u) {
  return __uint_as_float(((unsigned int)u) << 16);
}
static __device__ __forceinline__ float fast_tanh(float x) {
  float e = __expf(2.f * x);
  return 1.f - 2.f * __builtin_amdgcn_rcpf(e + 1.f);
}
static __device__ __forceinline__ float fast_sigmoid(float x) {
  return __builtin_amdgcn_rcpf(1.f + __expf(-x));
}

static __device__ __forceinline__ void load_lds16(const void* g, void* l) {
  __builtin_amdgcn_global_load_lds(
      (const __attribute__((address_space(1))) unsigned int*)g,
      (__attribute__((address_space(3))) unsigned int*)l, 16, 0, 0);
}

// swizzled element offset within one bf16 LDS tile (row stride 32 elems/64B)
static __device__ __forceinline__ int lds_off(int row, int g) {
  return row * GBK + ((g ^ ((row >> 1) & 3)) * 8);
}

// ---------------------------------------------------------------------------
// bf16 MFMA GEMM, TMxTN tile, BK=32, 4 waves (2x2), STAGES-deep pipeline with
// counted vmcnt + raw barrier.  C = A @ W^T (+ epilogue).
// MODE 0: C fp32 = acc + bias[col]
// MODE 1: Cb bf16 = acc + bias[col]
// MODE 2: C fp32 = acc + aux[row*ldc + col]
// ---------------------------------------------------------------------------
template <int TM, int TN, int MODE, int GRIDMODE, int STAGES>
__global__ __launch_bounds__(256) void gemm_mfma(
    const unsigned short* __restrict__ A, const unsigned short* __restrict__ W,
    const float* __restrict__ aux, float* __restrict__ C,
    unsigned short* __restrict__ Cb,
    int M, int N, int K, int ldc) {
  constexpr int FM = TM / 32;
  constexpr int FN = TN / 32;
  constexpr int CA = TM / 64;
  constexpr int CB = TN / 64;
  constexpr int LOADS = CA + CB;
  constexpr int F = (STAGES >= 3) ? (STAGES - 2) : 0;

  __shared__ unsigned short lsA[STAGES][TM * GBK];
  __shared__ unsigned short lsB[STAGES][TN * GBK];
  const int tid = threadIdx.x;
  const int lane = tid & 63;
  const int w = tid >> 6;

  int mIdx, nIdx;
  if constexpr (GRIDMODE == 1) {
    const int nwg = gridDim.x * gridDim.y;
    const int orig = blockIdx.y * gridDim.x + blockIdx.x;
    const int q = nwg >> 3, rr = nwg & 7;
    const int xcd = orig & 7, rest = orig >> 3;
    const int wgid =
        (xcd < rr ? xcd * (q + 1) : rr * (q + 1) + (xcd - rr) * q) + rest;
    mIdx = wgid % gridDim.x;
    nIdx = wgid / gridDim.x;
  } else {
    mIdx = blockIdx.y;
    nIdx = blockIdx.x;
  }
  const int mBase = mIdx * TM;
  const int nBase = nIdx * TN;
  const int rowBase = (w >> 1) * (TM / 2);
  const int colBase = (w & 1) * (TN / 2);

  const int fr = lane & 15;
  const int fkU = lane >> 4;
  const int fg = lane >> 4;

  f32x4 acc[FM][FN] = {};

  auto STAGE = [&](int buf, int k0) {
#pragma unroll
    for (int i = 0; i < CA; ++i) {
      int chunk = i * 256 + tid;
      int row = chunk >> 2;
      int u = chunk & 3;
      int col = (u ^ ((row >> 1) & 3)) * 8;
      load_lds16(A + (size_t)(mBase + row) * K + k0 + col,
                 &lsA[buf][chunk * 8]);
    }
#pragma unroll
    for (int i = 0; i < CB; ++i) {
      int chunk = i * 256 + tid;
      int row = chunk >> 2;
      int u = chunk & 3;
      int col = (u ^ ((row >> 1) & 3)) * 8;
      load_lds16(W + (size_t)(nBase + row) * K + k0 + col,
                 &lsB[buf][chunk * 8]);
    }
  };

  const int NT = K / GBK;
  for (int s = 0; s <= F && s < NT; ++s) STAGE(s % STAGES, s * GBK);

  for (int t = 0; t < NT; ++t) {
    const int rem = NT - 1 - t;
    if (rem >= F) {
      asm volatile("s_waitcnt vmcnt(%0)\n\ts_barrier" :: "i"(F * LOADS)
                   : "memory");
    } else if (rem == 2) {
      asm volatile("s_waitcnt vmcnt(%0)\n\ts_barrier" :: "i"(2 * LOADS)
                   : "memory");
    } else if (rem == 1) {
      asm volatile("s_waitcnt vmcnt(%0)\n\ts_barrier" :: "i"(1 * LOADS)
                   : "memory");
    } else {
      asm volatile("s_waitcnt vmcnt(0)\n\ts_barrier" ::: "memory");
    }
    if (t + F + 1 < NT) STAGE((t + F + 1) % STAGES, (t + F + 1) * GBK);

    const int cb = t % STAGES;
    bf16x8 af[FM], bfr[FN];
#pragma unroll
    for (int m = 0; m < FM; ++m)
      af[m] = *(const bf16x8*)&lsA[cb][lds_off(rowBase + m * 16 + fr, fkU)];
#pragma unroll
    for (int n = 0; n < FN; ++n)
      bfr[n] = *(const bf16x8*)&lsB[cb][lds_off(colBase + n * 16 + fr, fkU)];
#pragma unroll
    for (int m = 0; m < FM; ++m)
#pragma unroll
      for (int n = 0; n < FN; ++n)
        acc[m][n] = __builtin_amdgcn_mfma_f32_16x16x32_bf16(
            af[m], bfr[n], acc[m][n], 0, 0, 0);
  }

#pragma unroll
  for (int m = 0; m < FM; ++m) {
    int colg[FN];
    float bv[FN];
#pragma unroll
    for (int n = 0; n < FN; ++n) {
      colg[n] = nBase + colBase + n * 16 + fr;
      if constexpr (MODE != 2) bv[n] = aux[colg[n]];
    }
#pragma unroll
    for (int r = 0; r < 4; ++r) {
      const int rowg = mBase + rowBase + m * 16 + fg * 4 + r;
      float v[FN];
#pragma unroll
      for (int n = 0; n < FN; ++n) {
        if constexpr (MODE == 2)
          v[n] = acc[m][n][r] + aux[(size_t)rowg * ldc + colg[n]];
        else
          v[n] = acc[m][n][r] + bv[n];
        if constexpr (MODE == 1)
          Cb[(size_t)rowg * ldc + colg[n]] = f2bf(v[n]);
        else
          C[(size_t)rowg * ldc + colg[n]] = v[n];
      }
    }
  }
}

// ---------------------------------------------------------------------------
// Fused gi-GEMM + GRU, gate-colocating tile. grid (B/64, H/32) = 128 blocks.
// ---------------------------------------------------------------------------
__global__ __launch_bounds__(256) void gemm_gru3(
    const unsigned short* __restrict__ A,     // ctx_bf [B,H]
    const unsigned short* __restrict__ W3,    // Wctx_bf [3H,H]
    const float* __restrict__ giE_t,          // [B,3H]
    const float* __restrict__ wqgh,           // [B,4H] (gh at +H)
    const float* __restrict__ h_in,           // [B,H]
    float* __restrict__ h_out,                // [B,H]
    unsigned short* __restrict__ h_out_bf,    // [B,H]
    unsigned char* __restrict__ h_out_f8) {   // [B,H]
  constexpr int BK = 64;
  constexpr int STAGES = 3;
  constexpr int LOADS = 5;
  __shared__ unsigned short lsA[STAGES][64 * BK];
  __shared__ unsigned short lsW[STAGES][96 * BK];
  const int tid = threadIdx.x;
  const int lane = tid & 63;
  const int w = tid >> 6;
  const int mBase = blockIdx.x * 64;
  const int jBase = blockIdx.y * 32;
  const int fr = lane & 15;
  const int fkU = lane >> 4;
  const int fg = lane >> 4;

  f32x4 acc[6] = {};

  auto STAGE = [&](int buf, int k0) {
#pragma unroll
    for (int i = 0; i < 2; ++i) {
      int c = i * 256 + tid;
      int row = c >> 3, u = c & 7;
      int col = (u ^ (row & 7)) * 8;
      load_lds16(A + (size_t)(mBase + row) * H + k0 + col, &lsA[buf][c * 8]);
    }
#pragma unroll
    for (int i = 0; i < 3; ++i) {
      int c = i * 256 + tid;
      int wr = c >> 3, u = c & 7;
      int gate = wr >> 5, jj = wr & 31;
      int col = (u ^ (wr & 7)) * 8;
      load_lds16(W3 + (size_t)(gate * H + jBase + jj) * H + k0 + col,
                 &lsW[buf][c * 8]);
    }
  };

  const int NT = H / BK;
  STAGE(0, 0);
  STAGE(1, BK);
  for (int t = 0; t < NT; ++t) {
    const int rem = NT - 1 - t;
    if (rem >= 1) {
      asm volatile("s_waitcnt vmcnt(%0)\n\ts_barrier" :: "i"(LOADS)
                   : "memory");
    } else {
      asm volatile("s_waitcnt vmcnt(0)\n\ts_barrier" ::: "memory");
    }
    if (t + 2 < NT) STAGE((t + 2) % STAGES, (t + 2) * BK);
    const int cb = t % STAGES;
    const int arow = w * 16 + fr;
#pragma unroll
    for (int ks = 0; ks < 2; ++ks) {
      const int u = ks * 4 + fkU;
      bf16x8 af =
          *(const bf16x8*)&lsA[cb][arow * BK + ((u ^ (arow & 7)) * 8)];
#pragma unroll
      for (int n = 0; n < 6; ++n) {
        int wr = n * 16 + fr;
        bf16x8 bf =
            *(const bf16x8*)&lsW[cb][wr * BK + ((u ^ (wr & 7)) * 8)];
        acc[n] = __builtin_amdgcn_mfma_f32_16x16x32_bf16(af, bf, acc[n],
                                                         0, 0, 0);
      }
    }
  }

#pragma unroll
  for (int r = 0; r < 4; ++r) {
    const int b = mBase + w * 16 + fg * 4 + r;
    const float* giE_row = giE_t + (size_t)b * 3 * H;
    const float* gh_row = wqgh + (size_t)b * 4 * H + H;
#pragma unroll
    for (int jjg = 0; jjg < 2; ++jjg) {
      const int col = jBase + jjg * 16 + fr;
      float gr = acc[0 + jjg][r] + giE_row[col];
      float gz = acc[2 + jjg][r] + giE_row[H + col];
      float gn = acc[4 + jjg][r] + giE_row[2 * H + col];
      float rr = fast_sigmoid(gr + gh_row[col]);
      float zz = fast_sigmoid(gz + gh_row[H + col]);
      float nn = fast_tanh(gn + rr * gh_row[2 * H + col]);
      float hp = h_in[(size_t)b * H + col];
      float ho = (1.f - zz) * nn + zz * hp;
      h_out[(size_t)b * H + col] = ho;
      h_out_bf[(size_t)b * H + col] = f2bf(ho);
      int p8 = __builtin_amdgcn_cvt_pk_fp8_f32(ho, ho, 0, false);
      h_out_f8[(size_t)b * H + col] = (unsigned char)(p8 & 0xff);
    }
  }
}

// ---------------------------------------------------------------------------
// fp8 e4m3 MFMA GEMM for the vocab projection. 128x128 tile, BK=64,
// STAGES=3 counted pipeline (vmcnt(4): one stage always in flight — covers
// the ~600-900cy L3 latency of W-panel loads that a vmcnt(0) drain exposed).
// LDS swizzle f(row)=(row>>1)&3 -> 2-way (free). 48 KB LDS -> 3 blocks/CU.
// ---------------------------------------------------------------------------
__global__ __launch_bounds__(256) void gemm_fp8_logits(
    const unsigned char* __restrict__ A8, const unsigned char* __restrict__ W8,
    const float* __restrict__ bias, unsigned short* __restrict__ Cb,
    float* __restrict__ partials, int M, int N, int K, int ldc, int pstride) {
  constexpr int BK = 64;
  constexpr int STAGES = 3;
  constexpr int LOADS = 4;
  __shared__ __align__(16) unsigned char lsA[STAGES][128 * BK];
  __shared__ __align__(16) unsigned char lsB[STAGES][128 * BK];
  const int tid = threadIdx.x;
  const int lane = tid & 63;
  const int w = tid >> 6;

  const int nwg = gridDim.x * gridDim.y;
  const int orig = blockIdx.y * gridDim.x + blockIdx.x;
  const int q = nwg >> 3, rr = nwg & 7;
  const int xcd = orig & 7, rest = orig >> 3;
  const int wgid =
      (xcd < rr ? xcd * (q + 1) : rr * (q + 1) + (xcd - rr) * q) + rest;
  const int mIdx = wgid % gridDim.x;
  const int nIdx = wgid / gridDim.x;
  const int mBase = mIdx * 128;
  const int nBase = nIdx * 128;
  const int rowBase = (w >> 1) * 64;
  const int colBase = (w & 1) * 64;
  const int fr = lane & 15;
  const int fkU = lane >> 4;
  const int fg = lane >> 4;

  f32x4 acc[4][4] = {};

  auto STAGE = [&](int buf, int k0) {
#pragma unroll
    for (int i = 0; i < 2; ++i) {
      int c = i * 256 + tid;
      int row = c >> 2;
      int u = c & 3;
      int col = (u ^ ((row >> 1) & 3)) * 16;
      load_lds16(A8 + (size_t)(mBase + row) * K + k0 + col, &lsA[buf][c * 16]);
    }
#pragma unroll
    for (int i = 0; i < 2; ++i) {
      int c = i * 256 + tid;
      int row = c >> 2;
      int u = c & 3;
      int col = (u ^ ((row >> 1) & 3)) * 16;
      load_lds16(W8 + (size_t)(nBase + row) * K + k0 + col, &lsB[buf][c * 16]);
    }
  };

  const int NT = K / BK;   // 16
  STAGE(0, 0);
  STAGE(1, BK);
  for (int t = 0; t < NT; ++t) {
    const int rem = NT - 1 - t;
    if (rem >= 1) {
      asm volatile("s_waitcnt vmcnt(%0)\n\ts_barrier" :: "i"(LOADS)
                   : "memory");
    } else {
      asm volatile("s_waitcnt vmcnt(0)\n\ts_barrier" ::: "memory");
    }
    if (t + 2 < NT) STAGE((t + 2) % STAGES, (t + 2) * BK);
    const int cb = t % STAGES;
#pragma unroll
    for (int ks = 0; ks < 2; ++ks) {
      const int u = ks * 2 + (fkU >> 1);
      const int sub = (fkU & 1) * 8;
      long long af[4], bf[4];
#pragma unroll
      for (int m = 0; m < 4; ++m) {
        int row = rowBase + m * 16 + fr;
        af[m] = *(const long long*)
            &lsA[cb][row * BK + ((u ^ ((row >> 1) & 3)) << 4) + sub];
      }
#pragma unroll
      for (int n = 0; n < 4; ++n) {
        int row = colBase + n * 16 + fr;
        bf[n] = *(const long long*)
            &lsB[cb][row * BK + ((u ^ ((row >> 1) & 3)) << 4) + sub];
      }
#pragma unroll
      for (int m = 0; m < 4; ++m)
#pragma unroll
        for (int n = 0; n < 4; ++n)
          acc[m][n] = __builtin_amdgcn_mfma_f32_16x16x32_fp8_fp8(
              af[m], bf[n], acc[m][n], 0, 0, 0);
    }
  }

#pragma unroll
  for (int m = 0; m < 4; ++m) {
    int colg[4];
    float bv[4];
#pragma unroll
    for (int n = 0; n < 4; ++n) {
      colg[n] = nBase + colBase + n * 16 + fr;
      bv[n] = bias[colg[n]];
    }
#pragma unroll
    for (int r = 0; r < 4; ++r) {
      const int rowg = mBase + rowBase + m * 16 + fg * 4 + r;
      float v[4];
#pragma unroll
      for (int n = 0; n < 4; ++n) {
        v[n] = acc[m][n][r] + bv[n];
        Cb[(size_t)rowg * ldc + colg[n]] = f2bf(v[n]);
      }
      float mx = fmaxf(fmaxf(v[0], v[1]), fmaxf(v[2], v[3]));
      mx = fmaxf(mx, __shfl_xor(mx, 1, 64));
      mx = fmaxf(mx, __shfl_xor(mx, 2, 64));
      mx = fmaxf(mx, __shfl_xor(mx, 4, 64));
      mx = fmaxf(mx, __shfl_xor(mx, 8, 64));
      float se = __expf(v[0] - mx) + __expf(v[1] - mx) +
                 __expf(v[2] - mx) + __expf(v[3] - mx);
      se += __shfl_xor(se, 1, 64);
      se += __shfl_xor(se, 2, 64);
      se += __shfl_xor(se, 4, 64);
      se += __shfl_xor(se, 8, 64);
      if (fr == 0) {
        float2* pp = (float2*)partials;
        pp[(size_t)rowg * pstride + nIdx * 2 + (w & 1)] = make_float2(mx, se);
      }
    }
  }
}

// ---------------------------------------------------------------------------
static __device__ __forceinline__ void cvt8(const float* src,
                                            unsigned short* dst, size_t i) {
  float4 a = *(const float4*)&src[i];
  float4 b = *(const float4*)&src[i + 4];
  ushort4 lo, hi;
  lo.x = f2bf(a.x); lo.y = f2bf(a.y); lo.z = f2bf(a.z); lo.w = f2bf(a.w);
  hi.x = f2bf(b.x); hi.y = f2bf(b.y); hi.z = f2bf(b.z); hi.w = f2bf(b.w);
  *(ushort4*)&dst[i] = lo;
  *(ushort4*)&dst[i + 4] = hi;
}

__global__ __launch_bounds__(256) void cvt_bf16_kernel(
    const float* __restrict__ src, unsigned short* __restrict__ dst) {
  cvt8(src, dst, ((size_t)blockIdx.x * 256 + threadIdx.x) * 8);
}

// one kernel for all small weight converts (saves 3 launches):
// blocks [0,512): Ua_w -> Uaw_bf; [512,1024): Wa_w -> fusedW;
// [1024,2560): w_hh -> fusedW+H*H; [2560,5632): w_ih split -> Wemb/Wctx
__global__ __launch_bounds__(256) void prep_weights(
    const float* __restrict__ Ua_w, const float* __restrict__ Wa_w,
    const float* __restrict__ w_hh, const float* __restrict__ w_ih,
    unsigned short* __restrict__ Uaw_bf, unsigned short* __restrict__ fusedW,
    unsigned short* __restrict__ Wemb, unsigned short* __restrict__ Wctx) {
  const int blk = blockIdx.x;
  if (blk < 512) {
    cvt8(Ua_w, Uaw_bf, ((size_t)blk * 256 + threadIdx.x) * 8);
  } else if (blk < 1024) {
    cvt8(Wa_w, fusedW, ((size_t)(blk - 512) * 256 + threadIdx.x) * 8);
  } else if (blk < 2560) {
    cvt8(w_hh, fusedW + (size_t)H * H,
         ((size_t)(blk - 1024) * 256 + threadIdx.x) * 8);
  } else {
    size_t base = ((size_t)(blk - 2560) * 256 + threadIdx.x) * 8;
    int row = (int)(base >> 11);
    int col = (int)(base & 2047);
    float4 a = *(const float4*)&w_ih[base];
    float4 b = *(const float4*)&w_ih[base + 4];
    ushort4 lo, hi;
    lo.x = f2bf(a.x); lo.y = f2bf(a.y); lo.z = f2bf(a.z); lo.w = f2bf(a.w);
    hi.x = f2bf(b.x); hi.y = f2bf(b.y); hi.z = f2bf(b.z); hi.w = f2bf(b.w);
    unsigned short* dst = (col < H) ? (Wemb + (size_t)row * H + col)
                                    : (Wctx + (size_t)row * H + col - H);
    *(ushort4*)dst = lo;
    *(ushort4*)(dst + 4) = hi;
  }
}

// fp32 -> fp8 e4m3, 8 elems/thread
__global__ __launch_bounds__(256) void cvt_fp8_kernel(
    const float* __restrict__ src, unsigned int* __restrict__ dst) {
  size_t i = (size_t)blockIdx.x * 256 + threadIdx.x;
  float4 a = ((const float4*)src)[i * 2];
  float4 b = ((const float4*)src)[i * 2 + 1];
  int lo = __builtin_amdgcn_cvt_pk_fp8_f32(a.x, a.y, 0, false);
  lo = __builtin_amdgcn_cvt_pk_fp8_f32(a.z, a.w, lo, true);
  int hi = __builtin_amdgcn_cvt_pk_fp8_f32(b.x, b.y, 0, false);
  hi = __builtin_amdgcn_cvt_pk_fp8_f32(b.z, b.w, hi, true);
  ((int2*)dst)[i] = make_int2(lo, hi);
}

__global__ __launch_bounds__(256) void build_fused_bias(
    const float* __restrict__ Wa_b, const float* __restrict__ b_hh,
    float* __restrict__ fb) {
  int i = blockIdx.x * 256 + threadIdx.x;
  fb[i] = (i < H) ? Wa_b[i] : b_hh[i - H];
}

__global__ __launch_bounds__(256) void embed_all_kernel(
    const int* __restrict__ target, const float* __restrict__ emb,
    unsigned short* __restrict__ embAll) {
  int idx = blockIdx.x * 256 + threadIdx.x;
  int h8 = (idx & 127) * 8;
  int tb = idx >> 7;
  int t = tb >> 8;
  int b = tb & 255;
  int tok = (t == 0) ? 0 : target[b * T + (t - 1)];
  const float* e = emb + (size_t)tok * H + h8;
  float4 a = *(const float4*)e;
  float4 c = *(const float4*)(e + 4);
  ushort4 lo, hi;
  lo.x = f2bf(a.x); lo.y = f2bf(a.y); lo.z = f2bf(a.z); lo.w = f2bf(a.w);
  hi.x = f2bf(c.x); hi.y = f2bf(c.y); hi.z = f2bf(c.z); hi.w = f2bf(c.w);
  unsigned short* d = embAll + (size_t)tb * H + h8;
  *(ushort4*)d = lo;
  *(ushort4*)(d + 4) = hi;
}

// ---------------------------------------------------------------------------
// Fused attention: scores -> softmax -> ctx, one block per b.
// ---------------------------------------------------------------------------
__global__ __launch_bounds__(256) void attn_fused_kernel(
    const float* __restrict__ wqgh, const unsigned short* __restrict__ Uk_bf,
    const unsigned short* __restrict__ keys_bf,
    const float* __restrict__ Va_w, const float* __restrict__ Va_b,
    float* __restrict__ out_attn, unsigned short* __restrict__ ctx_bf, int t) {
  const int b = blockIdx.x;
  const int tid = threadIdx.x;
  __shared__ float wqs[H];
  __shared__ float vas[H];
  __shared__ float sw[S];

  ((float4*)wqs)[tid] = ((const float4*)(wqgh + (size_t)b * 4 * H))[tid];
  ((float4*)vas)[tid] = ((const float4*)Va_w)[tid];
  __syncthreads();

  const int s = tid >> 2;
  const int hc = (tid & 3) * 256;
  const unsigned short* uk = Uk_bf + ((size_t)b * S + s) * H + hc;
  float sum = 0.f;
#pragma unroll 4
  for (int i = 0; i < 256; i += 8) {
    bf16x8 u = *(const bf16x8*)&uk[i];
#pragma unroll
    for (int j = 0; j < 8; ++j) {
      float e = fast_tanh(wqs[hc + i + j] + bf2f((unsigned short)u[j]));
      sum += e * vas[hc + i + j];
    }
  }
  sum += __shfl_xor(sum, 1, 64);
  sum += __shfl_xor(sum, 2, 64);
  if ((tid & 3) == 0) sw[s] = sum + Va_b[0];
  __syncthreads();

  if (tid < 64) {
    float v = sw[tid];
    float m = v;
    for (int off = 32; off > 0; off >>= 1) m = fmaxf(m, __shfl_xor(m, off, 64));
    float e = __expf(v - m);
    float sm = e;
    for (int off = 32; off > 0; off >>= 1) sm += __shfl_xor(sm, off, 64);
    float wv = e / sm;
    sw[tid] = wv;
    out_attn[((size_t)b * T + t) * S + tid] = wv;
  }
  __syncthreads();

  const unsigned short* kb = keys_bf + (size_t)b * S * H + tid * 4;
  float c0 = 0.f, c1 = 0.f, c2 = 0.f, c3 = 0.f;
#pragma unroll 8
  for (int s2 = 0; s2 < S; ++s2) {
    float wv = sw[s2];
    ushort4 kv = *(const ushort4*)&kb[(size_t)s2 * H];
    c0 += wv * bf2f(kv.x);
    c1 += wv * bf2f(kv.y);
    c2 += wv * bf2f(kv.z);
    c3 += wv * bf2f(kv.w);
  }
  ushort4 o;
  o.x = f2bf(c0); o.y = f2bf(c1); o.z = f2bf(c2); o.w = f2bf(c3);
  *(ushort4*)&ctx_bf[(size_t)b * H + tid * 4] = o;
}

// ---------------------------------------------------------------------------
// batched log-softmax: reduce partials -> ls[row] for all T*B rows
// ---------------------------------------------------------------------------
__global__ __launch_bounds__(256) void logsm_reduce_kernel(
    const float* __restrict__ partials, float* __restrict__ ls, int P) {
  const int row = blockIdx.x;
  const int tid = threadIdx.x;
  const float2* pp = (const float2*)partials + (size_t)row * P;
  __shared__ float red[256];
  float mx = -INFINITY;
  for (int i = tid; i < P; i += 256) mx = fmaxf(mx, pp[i].x);
  red[tid] = mx;
  __syncthreads();
  for (int off = 128; off > 0; off >>= 1) {
    if (tid < off) red[tid] = fmaxf(red[tid], red[tid + off]);
    __syncthreads();
  }
  mx = red[0];
  __syncthreads();
  float sm = 0.f;
  for (int i = tid; i < P; i += 256) sm += pp[i].y * __expf(pp[i].x - mx);
  red[tid] = sm;
  __syncthreads();
  for (int off = 128; off > 0; off >>= 1) {
    if (tid < off) red[tid] += red[tid + off];
    __syncthreads();
  }
  if (tid == 0) ls[row] = mx + __logf(red[0]);
}

// dec[b, t, :] = bf2f(logits_bf[tb, :]) - ls[tb];  tb = t*B + b
__global__ __launch_bounds__(256) void logsm_sub_kernel(
    const unsigned short* __restrict__ logits_bf, const float* __restrict__ ls,
    float* __restrict__ dec) {
  const int tb = blockIdx.y;
  const int t = tb >> 8;
  const int b = tb & 255;
  const int i8 = (blockIdx.x * 256 + threadIdx.x) * 8;
  if (i8 < V) {
    float l = ls[tb];
    const unsigned short* src = logits_bf + (size_t)tb * V + i8;
    bf16x8 u = *(const bf16x8*)src;
    float* d = dec + (size_t)b * T * V + (size_t)t * V + i8;
    float4 o0, o1;
    o0.x = bf2f((unsigned short)u[0]) - l; o0.y = bf2f((unsigned short)u[1]) - l;
    o0.z = bf2f((unsigned short)u[2]) - l; o0.w = bf2f((unsigned short)u[3]) - l;
    o1.x = bf2f((unsigned short)u[4]) - l; o1.y = bf2f((unsigned short)u[5]) - l;
    o1.z = bf2f((unsigned short)u[6]) - l; o1.w = bf2f((unsigned short)u[7]) - l;
    *(float4*)d = o0;
    *(float4*)(d + 4) = o1;
  }
}

__global__ __launch_bounds__(256) void copy_kernel(
    const float* __restrict__ src, float* __restrict__ dst, int n) {
  int i = blockIdx.x * 256 + threadIdx.x;
  if (i < n) dst[i] = src[i];
}

// ---------------------------------------------------------------------------
extern "C" void kernel_launch(void* const* d_in, const int* in_sizes, int n_in,
                              void* d_out, int out_size, void* d_ws, size_t ws_size,
                              hipStream_t stream) {
  const float* keys       = (const float*)d_in[0];
  const float* enc_hidden = (const float*)d_in[1];
  const int*   target     = (const int*)d_in[2];
  const float* embedding  = (const float*)d_in[3];
  const float* Wa_w = (const float*)d_in[4];
  const float* Wa_b = (const float*)d_in[5];
  const float* Ua_w = (const float*)d_in[6];
  const float* Ua_b = (const float*)d_in[7];
  const float* Va_w = (const float*)d_in[8];
  const float* Va_b = (const float*)d_in[9];
  const float* gru_w_ih = (const float*)d_in[10];
  const float* gru_w_hh = (const float*)d_in[11];
  const float* gru_b_ih = (const float*)d_in[12];
  const float* gru_b_hh = (const float*)d_in[13];
  const float* out_w = (const float*)d_in[14];
  const float* out_b = (const float*)d_in[15];

  float* out = (float*)d_out;
  float* out_dec  = out;
  float* out_h    = out + (size_t)B * T * V;
  float* out_attn = out + (size_t)B * T * V + (size_t)B * H;

  // ---- workspace ----
  char* p = (char*)d_ws;
  unsigned short* keys_bf = (unsigned short*)p; p += (size_t)B * S * H * 2;
  unsigned char*  outw8   = (unsigned char*)p;  p += (size_t)V * H;
  unsigned short* Uaw_bf  = (unsigned short*)p; p += (size_t)H * H * 2;
  unsigned short* fusedW  = (unsigned short*)p; p += (size_t)4 * H * H * 2;
  float*          fusedB  = (float*)p;          p += (size_t)4 * H * 4;
  unsigned short* Wemb_bf = (unsigned short*)p; p += (size_t)3 * H * H * 2;
  unsigned short* Wctx_bf = (unsigned short*)p; p += (size_t)3 * H * H * 2;
  unsigned short* embAll  = (unsigned short*)p; p += (size_t)T * B * H * 2;
  unsigned short* Uk_bf   = (unsigned short*)p; p += (size_t)B * S * H * 2;
  float*          giE     = (float*)p;          p += (size_t)T * B * 3 * H * 4;
  float*          wqgh    = (float*)p;          p += (size_t)B * 4 * H * 4;
  unsigned short* ctx_bf  = (unsigned short*)p; p += (size_t)B * H * 2;
  float*          hA      = (float*)p;          p += (size_t)B * H * 4;
  float*          hB      = (float*)p;          p += (size_t)B * H * 4;
  unsigned short* hAll    = (unsigned short*)p; p += (size_t)(T + 1) * B * H * 2;
  unsigned char*  hAll8   = (unsigned char*)p;  p += (size_t)T * B * H;
  unsigned short* logits_bf = (unsigned short*)p; p += (size_t)T * B * V * 2;
  float*          parts   = (float*)p;          p += (size_t)T * B * 500 * 2 * 4;
  float*          ls      = (float*)p;          p += (size_t)T * B * 4;

  // ---- one-time prep ----
  cvt_bf16_kernel<<<(B * S * H) / 2048, 256, 0, stream>>>(keys, keys_bf);
  cvt_fp8_kernel<<<((size_t)V * H) / 2048, 256, 0, stream>>>(
      out_w, (unsigned int*)outw8);
  prep_weights<<<5632, 256, 0, stream>>>(Ua_w, Wa_w, gru_w_hh, gru_w_ih,
                                         Uaw_bf, fusedW, Wemb_bf, Wctx_bf);
  build_fused_bias<<<(4 * H) / 256, 256, 0, stream>>>(Wa_b, gru_b_hh, fusedB);
  embed_all_kernel<<<(T * B * H / 8) / 256, 256, 0, stream>>>(target, embedding,
                                                              embAll);
  cvt_bf16_kernel<<<(B * H) / 2048, 256, 0, stream>>>(enc_hidden, hAll);

  // Uk_bf = bf16(keys @ Ua_w^T + Ua_b)
  gemm_mfma<128, 128, 1, 0, 2>
      <<<dim3(H / 128, (B * S) / 128), 256, 0, stream>>>(
          keys_bf, Uaw_bf, Ua_b, nullptr, Uk_bf, B * S, H, H, H);
  // giE = embAll @ Wemb^T + b_ih
  gemm_mfma<128, 128, 0, 1, 2>
      <<<dim3((T * B) / 128, 3 * H / 128), 256, 0, stream>>>(
          embAll, Wemb_bf, gru_b_ih, giE, nullptr, T * B, 3 * H, H, 3 * H);

  const float* h_in = enc_hidden;
  float* hbufs[2] = {hA, hB};

  for (int t = 0; t < T; ++t) {
    const unsigned short* hbf_in = hAll + (size_t)t * B * H;
    unsigned short* hbf_out = hAll + (size_t)(t + 1) * B * H;
    unsigned char* h8_out = hAll8 + (size_t)t * B * H;
    float* h_out = hbufs[t & 1];

    // wq | gh = h @ [Wa_w; w_hh]^T + [Wa_b; b_hh]
    gemm_mfma<64, 64, 0, 1, 5><<<dim3(B / 64, 4 * H / 64), 256, 0, stream>>>(
        hbf_in, fusedW, fusedB, wqgh, nullptr, B, 4 * H, H, 4 * H);
    attn_fused_kernel<<<B, 256, 0, stream>>>(
        wqgh, Uk_bf, keys_bf, Va_w, Va_b, out_attn, ctx_bf, t);
    // fused: gi = giE[t] + ctx @ Wctx^T  AND  GRU combine -> h (fp32/bf16/fp8)
    gemm_gru3<<<dim3(B / 64, H / 32), 256, 0, stream>>>(
        ctx_bf, Wctx_bf, giE + (size_t)t * B * 3 * H, wqgh, h_in, h_out,
        hbf_out, h8_out);

    h_in = h_out;
  }

  // batched vocab projection over all steps, fp8 e4m3 (3-stage counted)
  gemm_fp8_logits<<<dim3((T * B) / 128, V / 128), 256, 0, stream>>>(
      hAll8, outw8, out_b, logits_bf, parts, T * B, V, H, V, 500);
  logsm_reduce_kernel<<<T * B, 256, 0, stream>>>(parts, ls, 500);
  logsm_sub_kernel<<<dim3((V + 2047) / 2048, T * B), 256, 0, stream>>>(
      logits_bf, ls, out_dec);

  copy_kernel<<<(B * H + 255) / 256, 256, 0, stream>>>(h_in, out_h, B * H);
}

// Round 19
// 895.394 us; speedup vs baseline: 2.1770x; 1.0449x over previous
//
#include <hip/hip_runtime.h>
#include <math.h>

#define H 1024
#define V 32000
#define B 256
#define S 64
#define T 10

#define GBK 32

typedef __attribute__((ext_vector_type(8))) short bf16x8;
typedef __attribute__((ext_vector_type(4))) float f32x4;

static __device__ __forceinline__ unsigned short f2bf(float f) {
  unsigned int u = __float_as_uint(f);
  u += 0x7fff + ((u >> 16) & 1);   // round-to-nearest-even
  return (unsigned short)(u >> 16);
}
static __device__ __forceinline__ float bf2f(unsigned short u) {
  return __uint_as_float(((unsigned int)u) << 16);
}
static __device__ __forceinline__ float fast_tanh(float x) {
  float e = __expf(2.f * x);
  return 1.f - 2.f * __builtin_amdgcn_rcpf(e + 1.f);
}
static __device__ __forceinline__ float fast_sigmoid(float x) {
  return __builtin_amdgcn_rcpf(1.f + __expf(-x));
}

static __device__ __forceinline__ void load_lds16(const void* g, void* l) {
  __builtin_amdgcn_global_load_lds(
      (const __attribute__((address_space(1))) unsigned int*)g,
      (__attribute__((address_space(3))) unsigned int*)l, 16, 0, 0);
}

// swizzled element offset within one bf16 LDS tile (row stride 32 elems/64B)
static __device__ __forceinline__ int lds_off(int row, int g) {
  return row * GBK + ((g ^ ((row >> 1) & 3)) * 8);
}

// ---------------------------------------------------------------------------
// bf16 MFMA GEMM, TMxTN tile, BK=32, 4 waves (2x2), STAGES-deep pipeline.
// MODE 0: C fp32 = acc + bias[col]
// MODE 2: C fp32 = acc + aux[row*ldc + col]
// ---------------------------------------------------------------------------
template <int TM, int TN, int MODE, int GRIDMODE, int STAGES>
__global__ __launch_bounds__(256) void gemm_mfma(
    const unsigned short* __restrict__ A, const unsigned short* __restrict__ W,
    const float* __restrict__ aux, float* __restrict__ C,
    int M, int N, int K, int ldc) {
  constexpr int FM = TM / 32;
  constexpr int FN = TN / 32;
  constexpr int CA = TM / 64;
  constexpr int CB = TN / 64;
  constexpr int LOADS = CA + CB;
  constexpr int F = (STAGES >= 3) ? (STAGES - 2) : 0;

  __shared__ unsigned short lsA[STAGES][TM * GBK];
  __shared__ unsigned short lsB[STAGES][TN * GBK];
  const int tid = threadIdx.x;
  const int lane = tid & 63;
  const int w = tid >> 6;

  int mIdx, nIdx;
  if constexpr (GRIDMODE == 1) {
    const int nwg = gridDim.x * gridDim.y;
    const int orig = blockIdx.y * gridDim.x + blockIdx.x;
    const int q = nwg >> 3, rr = nwg & 7;
    const int xcd = orig & 7, rest = orig >> 3;
    const int wgid =
        (xcd < rr ? xcd * (q + 1) : rr * (q + 1) + (xcd - rr) * q) + rest;
    mIdx = wgid % gridDim.x;
    nIdx = wgid / gridDim.x;
  } else {
    mIdx = blockIdx.y;
    nIdx = blockIdx.x;
  }
  const int mBase = mIdx * TM;
  const int nBase = nIdx * TN;
  const int rowBase = (w >> 1) * (TM / 2);
  const int colBase = (w & 1) * (TN / 2);

  const int fr = lane & 15;
  const int fkU = lane >> 4;
  const int fg = lane >> 4;

  f32x4 acc[FM][FN] = {};

  auto STAGE = [&](int buf, int k0) {
#pragma unroll
    for (int i = 0; i < CA; ++i) {
      int chunk = i * 256 + tid;
      int row = chunk >> 2;
      int u = chunk & 3;
      int col = (u ^ ((row >> 1) & 3)) * 8;
      load_lds16(A + (size_t)(mBase + row) * K + k0 + col,
                 &lsA[buf][chunk * 8]);
    }
#pragma unroll
    for (int i = 0; i < CB; ++i) {
      int chunk = i * 256 + tid;
      int row = chunk >> 2;
      int u = chunk & 3;
      int col = (u ^ ((row >> 1) & 3)) * 8;
      load_lds16(W + (size_t)(nBase + row) * K + k0 + col,
                 &lsB[buf][chunk * 8]);
    }
  };

  const int NT = K / GBK;
  for (int s = 0; s <= F && s < NT; ++s) STAGE(s % STAGES, s * GBK);

  for (int t = 0; t < NT; ++t) {
    const int rem = NT - 1 - t;
    if (rem >= F) {
      asm volatile("s_waitcnt vmcnt(%0)\n\ts_barrier" :: "i"(F * LOADS)
                   : "memory");
    } else if (rem == 2) {
      asm volatile("s_waitcnt vmcnt(%0)\n\ts_barrier" :: "i"(2 * LOADS)
                   : "memory");
    } else if (rem == 1) {
      asm volatile("s_waitcnt vmcnt(%0)\n\ts_barrier" :: "i"(1 * LOADS)
                   : "memory");
    } else {
      asm volatile("s_waitcnt vmcnt(0)\n\ts_barrier" ::: "memory");
    }
    if (t + F + 1 < NT) STAGE((t + F + 1) % STAGES, (t + F + 1) * GBK);

    const int cb = t % STAGES;
    bf16x8 af[FM], bfr[FN];
#pragma unroll
    for (int m = 0; m < FM; ++m)
      af[m] = *(const bf16x8*)&lsA[cb][lds_off(rowBase + m * 16 + fr, fkU)];
#pragma unroll
    for (int n = 0; n < FN; ++n)
      bfr[n] = *(const bf16x8*)&lsB[cb][lds_off(colBase + n * 16 + fr, fkU)];
#pragma unroll
    for (int m = 0; m < FM; ++m)
#pragma unroll
      for (int n = 0; n < FN; ++n)
        acc[m][n] = __builtin_amdgcn_mfma_f32_16x16x32_bf16(
            af[m], bfr[n], acc[m][n], 0, 0, 0);
  }

#pragma unroll
  for (int m = 0; m < FM; ++m) {
    int colg[FN];
    float bv[FN];
#pragma unroll
    for (int n = 0; n < FN; ++n) {
      colg[n] = nBase + colBase + n * 16 + fr;
      if constexpr (MODE != 2) bv[n] = aux[colg[n]];
    }
#pragma unroll
    for (int r = 0; r < 4; ++r) {
      const int rowg = mBase + rowBase + m * 16 + fg * 4 + r;
      float v[FN];
#pragma unroll
      for (int n = 0; n < FN; ++n) {
        if constexpr (MODE == 2)
          v[n] = acc[m][n][r] + aux[(size_t)rowg * ldc + colg[n]];
        else
          v[n] = acc[m][n][r] + bv[n];
        C[(size_t)rowg * ldc + colg[n]] = v[n];
      }
    }
  }
}

// ---------------------------------------------------------------------------
// Fused gi-GEMM + GRU, gate-colocating tile. grid (B/64, H/32) = 128 blocks.
// ---------------------------------------------------------------------------
__global__ __launch_bounds__(256) void gemm_gru3(
    const unsigned short* __restrict__ A,     // ctx_bf [B,H]
    const unsigned short* __restrict__ W3,    // Wctx_bf [3H,H]
    const float* __restrict__ giE_t,          // [B,3H]
    const float* __restrict__ wqgh,           // [B,4H] (gh at +H)
    const float* __restrict__ h_in,           // [B,H]
    float* __restrict__ h_out,                // [B,H]
    unsigned short* __restrict__ h_out_bf,    // [B,H]
    unsigned char* __restrict__ h_out_f8) {   // [B,H]
  constexpr int BK = 64;
  constexpr int STAGES = 3;
  constexpr int LOADS = 5;
  __shared__ unsigned short lsA[STAGES][64 * BK];
  __shared__ unsigned short lsW[STAGES][96 * BK];
  const int tid = threadIdx.x;
  const int lane = tid & 63;
  const int w = tid >> 6;
  const int mBase = blockIdx.x * 64;
  const int jBase = blockIdx.y * 32;
  const int fr = lane & 15;
  const int fkU = lane >> 4;
  const int fg = lane >> 4;

  f32x4 acc[6] = {};

  auto STAGE = [&](int buf, int k0) {
#pragma unroll
    for (int i = 0; i < 2; ++i) {
      int c = i * 256 + tid;
      int row = c >> 3, u = c & 7;
      int col = (u ^ (row & 7)) * 8;
      load_lds16(A + (size_t)(mBase + row) * H + k0 + col, &lsA[buf][c * 8]);
    }
#pragma unroll
    for (int i = 0; i < 3; ++i) {
      int c = i * 256 + tid;
      int wr = c >> 3, u = c & 7;
      int gate = wr >> 5, jj = wr & 31;
      int col = (u ^ (wr & 7)) * 8;
      load_lds16(W3 + (size_t)(gate * H + jBase + jj) * H + k0 + col,
                 &lsW[buf][c * 8]);
    }
  };

  const int NT = H / BK;
  STAGE(0, 0);
  STAGE(1, BK);
  for (int t = 0; t < NT; ++t) {
    const int rem = NT - 1 - t;
    if (rem >= 1) {
      asm volatile("s_waitcnt vmcnt(%0)\n\ts_barrier" :: "i"(LOADS)
                   : "memory");
    } else {
      asm volatile("s_waitcnt vmcnt(0)\n\ts_barrier" ::: "memory");
    }
    if (t + 2 < NT) STAGE((t + 2) % STAGES, (t + 2) * BK);
    const int cb = t % STAGES;
    const int arow = w * 16 + fr;
#pragma unroll
    for (int ks = 0; ks < 2; ++ks) {
      const int u = ks * 4 + fkU;
      bf16x8 af =
          *(const bf16x8*)&lsA[cb][arow * BK + ((u ^ (arow & 7)) * 8)];
#pragma unroll
      for (int n = 0; n < 6; ++n) {
        int wr = n * 16 + fr;
        bf16x8 bf =
            *(const bf16x8*)&lsW[cb][wr * BK + ((u ^ (wr & 7)) * 8)];
        acc[n] = __builtin_amdgcn_mfma_f32_16x16x32_bf16(af, bf, acc[n],
                                                         0, 0, 0);
      }
    }
  }

#pragma unroll
  for (int r = 0; r < 4; ++r) {
    const int b = mBase + w * 16 + fg * 4 + r;
    const float* giE_row = giE_t + (size_t)b * 3 * H;
    const float* gh_row = wqgh + (size_t)b * 4 * H + H;
#pragma unroll
    for (int jjg = 0; jjg < 2; ++jjg) {
      const int col = jBase + jjg * 16 + fr;
      float gr = acc[0 + jjg][r] + giE_row[col];
      float gz = acc[2 + jjg][r] + giE_row[H + col];
      float gn = acc[4 + jjg][r] + giE_row[2 * H + col];
      float rr = fast_sigmoid(gr + gh_row[col]);
      float zz = fast_sigmoid(gz + gh_row[H + col]);
      float nn = fast_tanh(gn + rr * gh_row[2 * H + col]);
      float hp = h_in[(size_t)b * H + col];
      float ho = (1.f - zz) * nn + zz * hp;
      h_out[(size_t)b * H + col] = ho;
      h_out_bf[(size_t)b * H + col] = f2bf(ho);
      int p8 = __builtin_amdgcn_cvt_pk_fp8_f32(ho, ho, 0, false);
      h_out_f8[(size_t)b * H + col] = (unsigned char)(p8 & 0xff);
    }
  }
}

// ---------------------------------------------------------------------------
// fp8 e4m3 MFMA GEMM. 128x128 tile, BK=64, 2-stage (round-16 best).
// LDS swizzle f(row)=(row>>1)&3 -> 2-way (free). GRIDMODE-1 XCD swizzle.
// MODE 3: Cb bf16 = acc + bias + per-row (max,sumexp) partials (vocab)
// MODE 4: C8 fp8 = acc + bias                                    (Uk)
// ---------------------------------------------------------------------------
template <int MODE>
__global__ __launch_bounds__(256) void gemm_fp8(
    const unsigned char* __restrict__ A8, const unsigned char* __restrict__ W8,
    const float* __restrict__ bias, unsigned short* __restrict__ Cb,
    unsigned char* __restrict__ C8, float* __restrict__ partials,
    int M, int N, int K, int ldc, int pstride) {
  constexpr int BK = 64;
  __shared__ __align__(16) unsigned char lsA[2][128 * BK];
  __shared__ __align__(16) unsigned char lsB[2][128 * BK];
  const int tid = threadIdx.x;
  const int lane = tid & 63;
  const int w = tid >> 6;

  const int nwg = gridDim.x * gridDim.y;
  const int orig = blockIdx.y * gridDim.x + blockIdx.x;
  const int q = nwg >> 3, rr = nwg & 7;
  const int xcd = orig & 7, rest = orig >> 3;
  const int wgid =
      (xcd < rr ? xcd * (q + 1) : rr * (q + 1) + (xcd - rr) * q) + rest;
  const int mIdx = wgid % gridDim.x;
  const int nIdx = wgid / gridDim.x;
  const int mBase = mIdx * 128;
  const int nBase = nIdx * 128;
  const int rowBase = (w >> 1) * 64;
  const int colBase = (w & 1) * 64;
  const int fr = lane & 15;
  const int fkU = lane >> 4;
  const int fg = lane >> 4;

  f32x4 acc[4][4] = {};

  auto STAGE = [&](int buf, int k0) {
#pragma unroll
    for (int i = 0; i < 2; ++i) {
      int c = i * 256 + tid;
      int row = c >> 2;
      int u = c & 3;
      int col = (u ^ ((row >> 1) & 3)) * 16;
      load_lds16(A8 + (size_t)(mBase + row) * K + k0 + col, &lsA[buf][c * 16]);
    }
#pragma unroll
    for (int i = 0; i < 2; ++i) {
      int c = i * 256 + tid;
      int row = c >> 2;
      int u = c & 3;
      int col = (u ^ ((row >> 1) & 3)) * 16;
      load_lds16(W8 + (size_t)(nBase + row) * K + k0 + col, &lsB[buf][c * 16]);
    }
  };

  const int NT = K / BK;
  STAGE(0, 0);
  int cb = 0;
  for (int t = 0; t < NT; ++t) {
    asm volatile("s_waitcnt vmcnt(0)\n\ts_barrier" ::: "memory");
    if (t + 1 < NT) STAGE(cb ^ 1, (t + 1) * BK);
#pragma unroll
    for (int ks = 0; ks < 2; ++ks) {
      const int u = ks * 2 + (fkU >> 1);
      const int sub = (fkU & 1) * 8;
      long long af[4], bf[4];
#pragma unroll
      for (int m = 0; m < 4; ++m) {
        int row = rowBase + m * 16 + fr;
        af[m] = *(const long long*)
            &lsA[cb][row * BK + ((u ^ ((row >> 1) & 3)) << 4) + sub];
      }
#pragma unroll
      for (int n = 0; n < 4; ++n) {
        int row = colBase + n * 16 + fr;
        bf[n] = *(const long long*)
            &lsB[cb][row * BK + ((u ^ ((row >> 1) & 3)) << 4) + sub];
      }
#pragma unroll
      for (int m = 0; m < 4; ++m)
#pragma unroll
        for (int n = 0; n < 4; ++n)
          acc[m][n] = __builtin_amdgcn_mfma_f32_16x16x32_fp8_fp8(
              af[m], bf[n], acc[m][n], 0, 0, 0);
    }
    cb ^= 1;
  }

#pragma unroll
  for (int m = 0; m < 4; ++m) {
    int colg[4];
    float bv[4];
#pragma unroll
    for (int n = 0; n < 4; ++n) {
      colg[n] = nBase + colBase + n * 16 + fr;
      bv[n] = bias[colg[n]];
    }
#pragma unroll
    for (int r = 0; r < 4; ++r) {
      const int rowg = mBase + rowBase + m * 16 + fg * 4 + r;
      float v[4];
#pragma unroll
      for (int n = 0; n < 4; ++n) {
        v[n] = acc[m][n][r] + bv[n];
        if constexpr (MODE == 3) {
          Cb[(size_t)rowg * ldc + colg[n]] = f2bf(v[n]);
        } else {
          int pk = __builtin_amdgcn_cvt_pk_fp8_f32(v[n], v[n], 0, false);
          C8[(size_t)rowg * ldc + colg[n]] = (unsigned char)(pk & 0xff);
        }
      }
      if constexpr (MODE == 3) {
        float mx = fmaxf(fmaxf(v[0], v[1]), fmaxf(v[2], v[3]));
        mx = fmaxf(mx, __shfl_xor(mx, 1, 64));
        mx = fmaxf(mx, __shfl_xor(mx, 2, 64));
        mx = fmaxf(mx, __shfl_xor(mx, 4, 64));
        mx = fmaxf(mx, __shfl_xor(mx, 8, 64));
        float se = __expf(v[0] - mx) + __expf(v[1] - mx) +
                   __expf(v[2] - mx) + __expf(v[3] - mx);
        se += __shfl_xor(se, 1, 64);
        se += __shfl_xor(se, 2, 64);
        se += __shfl_xor(se, 4, 64);
        se += __shfl_xor(se, 8, 64);
        if (fr == 0) {
          float2* pp = (float2*)partials;
          pp[(size_t)rowg * pstride + nIdx * 2 + (w & 1)] =
              make_float2(mx, se);
        }
      }
    }
  }
}

// ---------------------------------------------------------------------------
static __device__ __forceinline__ void cvt8(const float* src,
                                            unsigned short* dst, size_t i) {
  float4 a = *(const float4*)&src[i];
  float4 b = *(const float4*)&src[i + 4];
  ushort4 lo, hi;
  lo.x = f2bf(a.x); lo.y = f2bf(a.y); lo.z = f2bf(a.z); lo.w = f2bf(a.w);
  hi.x = f2bf(b.x); hi.y = f2bf(b.y); hi.z = f2bf(b.z); hi.w = f2bf(b.w);
  *(ushort4*)&dst[i] = lo;
  *(ushort4*)&dst[i + 4] = hi;
}

__global__ __launch_bounds__(256) void cvt_bf16_kernel(
    const float* __restrict__ src, unsigned short* __restrict__ dst) {
  cvt8(src, dst, ((size_t)blockIdx.x * 256 + threadIdx.x) * 8);
}

// weight converts in one launch:
// [0,512): Wa_w -> fusedW; [512,2048): w_hh -> fusedW+H*H;
// [2048,5120): w_ih split -> Wemb/Wctx
__global__ __launch_bounds__(256) void prep_weights(
    const float* __restrict__ Wa_w, const float* __restrict__ w_hh,
    const float* __restrict__ w_ih, unsigned short* __restrict__ fusedW,
    unsigned short* __restrict__ Wemb, unsigned short* __restrict__ Wctx) {
  const int blk = blockIdx.x;
  if (blk < 512) {
    cvt8(Wa_w, fusedW, ((size_t)blk * 256 + threadIdx.x) * 8);
  } else if (blk < 2048) {
    cvt8(w_hh, fusedW + (size_t)H * H,
         ((size_t)(blk - 512) * 256 + threadIdx.x) * 8);
  } else {
    size_t base = ((size_t)(blk - 2048) * 256 + threadIdx.x) * 8;
    int row = (int)(base >> 11);
    int col = (int)(base & 2047);
    float4 a = *(const float4*)&w_ih[base];
    float4 b = *(const float4*)&w_ih[base + 4];
    ushort4 lo, hi;
    lo.x = f2bf(a.x); lo.y = f2bf(a.y); lo.z = f2bf(a.z); lo.w = f2bf(a.w);
    hi.x = f2bf(b.x); hi.y = f2bf(b.y); hi.z = f2bf(b.z); hi.w = f2bf(b.w);
    unsigned short* dst = (col < H) ? (Wemb + (size_t)row * H + col)
                                    : (Wctx + (size_t)row * H + col - H);
    *(ushort4*)dst = lo;
    *(ushort4*)(dst + 4) = hi;
  }
}

// fp32 -> fp8 e4m3, 8 elems/thread
__global__ __launch_bounds__(256) void cvt_fp8_kernel(
    const float* __restrict__ src, unsigned int* __restrict__ dst) {
  size_t i = (size_t)blockIdx.x * 256 + threadIdx.x;
  float4 a = ((const float4*)src)[i * 2];
  float4 b = ((const float4*)src)[i * 2 + 1];
  int lo = __builtin_amdgcn_cvt_pk_fp8_f32(a.x, a.y, 0, false);
  lo = __builtin_amdgcn_cvt_pk_fp8_f32(a.z, a.w, lo, true);
  int hi = __builtin_amdgcn_cvt_pk_fp8_f32(b.x, b.y, 0, false);
  hi = __builtin_amdgcn_cvt_pk_fp8_f32(b.z, b.w, hi, true);
  ((int2*)dst)[i] = make_int2(lo, hi);
}

__global__ __launch_bounds__(256) void build_fused_bias(
    const float* __restrict__ Wa_b, const float* __restrict__ b_hh,
    float* __restrict__ fb) {
  int i = blockIdx.x * 256 + threadIdx.x;
  fb[i] = (i < H) ? Wa_b[i] : b_hh[i - H];
}

__global__ __launch_bounds__(256) void embed_all_kernel(
    const int* __restrict__ target, const float* __restrict__ emb,
    unsigned short* __restrict__ embAll) {
  int idx = blockIdx.x * 256 + threadIdx.x;
  int h8 = (idx & 127) * 8;
  int tb = idx >> 7;
  int t = tb >> 8;
  int b = tb & 255;
  int tok = (t == 0) ? 0 : target[b * T + (t - 1)];
  const float* e = emb + (size_t)tok * H + h8;
  float4 a = *(const float4*)e;
  float4 c = *(const float4*)(e + 4);
  ushort4 lo, hi;
  lo.x = f2bf(a.x); lo.y = f2bf(a.y); lo.z = f2bf(a.z); lo.w = f2bf(a.w);
  hi.x = f2bf(c.x); hi.y = f2bf(c.y); hi.z = f2bf(c.z); hi.w = f2bf(c.w);
  unsigned short* d = embAll + (size_t)tb * H + h8;
  *(ushort4*)d = lo;
  *(ushort4*)(d + 4) = hi;
}

// ---------------------------------------------------------------------------
// Fused attention: scores -> softmax -> ctx, one block per b.
// Uk and keys in fp8 e4m3 (halves the per-step attn read traffic).
// ---------------------------------------------------------------------------
__global__ __launch_bounds__(256) void attn_fused_kernel(
    const float* __restrict__ wqgh, const unsigned char* __restrict__ Uk_f8,
    const unsigned char* __restrict__ keys_f8,
    const float* __restrict__ Va_w, const float* __restrict__ Va_b,
    float* __restrict__ out_attn, unsigned short* __restrict__ ctx_bf, int t) {
  const int b = blockIdx.x;
  const int tid = threadIdx.x;
  __shared__ float wqs[H];
  __shared__ float vas[H];
  __shared__ float sw[S];

  ((float4*)wqs)[tid] = ((const float4*)(wqgh + (size_t)b * 4 * H))[tid];
  ((float4*)vas)[tid] = ((const float4*)Va_w)[tid];
  __syncthreads();

  const int s = tid >> 2;
  const int hc = (tid & 3) * 256;
  const unsigned char* uk = Uk_f8 + ((size_t)b * S + s) * H + hc;
  float sum = 0.f;
#pragma unroll 4
  for (int i = 0; i < 256; i += 8) {
    uint2 u = *(const uint2*)&uk[i];
    float uv[8];
    uv[0] = __builtin_amdgcn_cvt_f32_fp8(u.x, 0);
    uv[1] = __builtin_amdgcn_cvt_f32_fp8(u.x, 1);
    uv[2] = __builtin_amdgcn_cvt_f32_fp8(u.x, 2);
    uv[3] = __builtin_amdgcn_cvt_f32_fp8(u.x, 3);
    uv[4] = __builtin_amdgcn_cvt_f32_fp8(u.y, 0);
    uv[5] = __builtin_amdgcn_cvt_f32_fp8(u.y, 1);
    uv[6] = __builtin_amdgcn_cvt_f32_fp8(u.y, 2);
    uv[7] = __builtin_amdgcn_cvt_f32_fp8(u.y, 3);
#pragma unroll
    for (int j = 0; j < 8; ++j) {
      float e = fast_tanh(wqs[hc + i + j] + uv[j]);
      sum += e * vas[hc + i + j];
    }
  }
  sum += __shfl_xor(sum, 1, 64);
  sum += __shfl_xor(sum, 2, 64);
  if ((tid & 3) == 0) sw[s] = sum + Va_b[0];
  __syncthreads();

  if (tid < 64) {
    float v = sw[tid];
    float m = v;
    for (int off = 32; off > 0; off >>= 1) m = fmaxf(m, __shfl_xor(m, off, 64));
    float e = __expf(v - m);
    float sm = e;
    for (int off = 32; off > 0; off >>= 1) sm += __shfl_xor(sm, off, 64);
    float wv = e / sm;
    sw[tid] = wv;
    out_attn[((size_t)b * T + t) * S + tid] = wv;
  }
  __syncthreads();

  const unsigned char* kb = keys_f8 + (size_t)b * S * H + tid * 4;
  float c0 = 0.f, c1 = 0.f, c2 = 0.f, c3 = 0.f;
#pragma unroll 8
  for (int s2 = 0; s2 < S; ++s2) {
    float wv = sw[s2];
    unsigned int kv = *(const unsigned int*)&kb[(size_t)s2 * H];
    c0 += wv * __builtin_amdgcn_cvt_f32_fp8(kv, 0);
    c1 += wv * __builtin_amdgcn_cvt_f32_fp8(kv, 1);
    c2 += wv * __builtin_amdgcn_cvt_f32_fp8(kv, 2);
    c3 += wv * __builtin_amdgcn_cvt_f32_fp8(kv, 3);
  }
  ushort4 o;
  o.x = f2bf(c0); o.y = f2bf(c1); o.z = f2bf(c2); o.w = f2bf(c3);
  *(ushort4*)&ctx_bf[(size_t)b * H + tid * 4] = o;
}

// ---------------------------------------------------------------------------
// batched log-softmax: reduce partials -> ls[row] for all T*B rows
// ---------------------------------------------------------------------------
__global__ __launch_bounds__(256) void logsm_reduce_kernel(
    const float* __restrict__ partials, float* __restrict__ ls, int P) {
  const int row = blockIdx.x;
  const int tid = threadIdx.x;
  const float2* pp = (const float2*)partials + (size_t)row * P;
  __shared__ float red[256];
  float mx = -INFINITY;
  for (int i = tid; i < P; i += 256) mx = fmaxf(mx, pp[i].x);
  red[tid] = mx;
  __syncthreads();
  for (int off = 128; off > 0; off >>= 1) {
    if (tid < off) red[tid] = fmaxf(red[tid], red[tid + off]);
    __syncthreads();
  }
  mx = red[0];
  __syncthreads();
  float sm = 0.f;
  for (int i = tid; i < P; i += 256) sm += pp[i].y * __expf(pp[i].x - mx);
  red[tid] = sm;
  __syncthreads();
  for (int off = 128; off > 0; off >>= 1) {
    if (tid < off) red[tid] += red[tid + off];
    __syncthreads();
  }
  if (tid == 0) ls[row] = mx + __logf(red[0]);
}

// dec[b, t, :] = bf2f(logits_bf[tb, :]) - ls[tb];  tb = t*B + b
__global__ __launch_bounds__(256) void logsm_sub_kernel(
    const unsigned short* __restrict__ logits_bf, const float* __restrict__ ls,
    float* __restrict__ dec) {
  const int tb = blockIdx.y;
  const int t = tb >> 8;
  const int b = tb & 255;
  const int i8 = (blockIdx.x * 256 + threadIdx.x) * 8;
  if (i8 < V) {
    float l = ls[tb];
    const unsigned short* src = logits_bf + (size_t)tb * V + i8;
    bf16x8 u = *(const bf16x8*)src;
    float* d = dec + (size_t)b * T * V + (size_t)t * V + i8;
    float4 o0, o1;
    o0.x = bf2f((unsigned short)u[0]) - l; o0.y = bf2f((unsigned short)u[1]) - l;
    o0.z = bf2f((unsigned short)u[2]) - l; o0.w = bf2f((unsigned short)u[3]) - l;
    o1.x = bf2f((unsigned short)u[4]) - l; o1.y = bf2f((unsigned short)u[5]) - l;
    o1.z = bf2f((unsigned short)u[6]) - l; o1.w = bf2f((unsigned short)u[7]) - l;
    *(float4*)d = o0;
    *(float4*)(d + 4) = o1;
  }
}

__global__ __launch_bounds__(256) void copy_kernel(
    const float* __restrict__ src, float* __restrict__ dst, int n) {
  int i = blockIdx.x * 256 + threadIdx.x;
  if (i < n) dst[i] = src[i];
}

// ---------------------------------------------------------------------------
extern "C" void kernel_launch(void* const* d_in, const int* in_sizes, int n_in,
                              void* d_out, int out_size, void* d_ws, size_t ws_size,
                              hipStream_t stream) {
  const float* keys       = (const float*)d_in[0];
  const float* enc_hidden = (const float*)d_in[1];
  const int*   target     = (const int*)d_in[2];
  const float* embedding  = (const float*)d_in[3];
  const float* Wa_w = (const float*)d_in[4];
  const float* Wa_b = (const float*)d_in[5];
  const float* Ua_w = (const float*)d_in[6];
  const float* Ua_b = (const float*)d_in[7];
  const float* Va_w = (const float*)d_in[8];
  const float* Va_b = (const float*)d_in[9];
  const float* gru_w_ih = (const float*)d_in[10];
  const float* gru_w_hh = (const float*)d_in[11];
  const float* gru_b_ih = (const float*)d_in[12];
  const float* gru_b_hh = (const float*)d_in[13];
  const float* out_w = (const float*)d_in[14];
  const float* out_b = (const float*)d_in[15];

  float* out = (float*)d_out;
  float* out_dec  = out;
  float* out_h    = out + (size_t)B * T * V;
  float* out_attn = out + (size_t)B * T * V + (size_t)B * H;

  // ---- workspace ----
  char* p = (char*)d_ws;
  unsigned char*  keys_f8 = (unsigned char*)p;  p += (size_t)B * S * H;
  unsigned char*  outw8   = (unsigned char*)p;  p += (size_t)V * H;
  unsigned char*  Uaw8    = (unsigned char*)p;  p += (size_t)H * H;
  unsigned short* fusedW  = (unsigned short*)p; p += (size_t)4 * H * H * 2;
  float*          fusedB  = (float*)p;          p += (size_t)4 * H * 4;
  unsigned short* Wemb_bf = (unsigned short*)p; p += (size_t)3 * H * H * 2;
  unsigned short* Wctx_bf = (unsigned short*)p; p += (size_t)3 * H * H * 2;
  unsigned short* embAll  = (unsigned short*)p; p += (size_t)T * B * H * 2;
  unsigned char*  Uk_f8   = (unsigned char*)p;  p += (size_t)B * S * H;
  float*          giE     = (float*)p;          p += (size_t)T * B * 3 * H * 4;
  float*          wqgh    = (float*)p;          p += (size_t)B * 4 * H * 4;
  unsigned short* ctx_bf  = (unsigned short*)p; p += (size_t)B * H * 2;
  float*          hA      = (float*)p;          p += (size_t)B * H * 4;
  float*          hB      = (float*)p;          p += (size_t)B * H * 4;
  unsigned short* hAll    = (unsigned short*)p; p += (size_t)(T + 1) * B * H * 2;
  unsigned char*  hAll8   = (unsigned char*)p;  p += (size_t)T * B * H;
  unsigned short* logits_bf = (unsigned short*)p; p += (size_t)T * B * V * 2;
  float*          parts   = (float*)p;          p += (size_t)T * B * 500 * 2 * 4;
  float*          ls      = (float*)p;          p += (size_t)T * B * 4;

  // ---- one-time prep ----
  cvt_fp8_kernel<<<(B * S * H) / 2048, 256, 0, stream>>>(
      keys, (unsigned int*)keys_f8);
  cvt_fp8_kernel<<<((size_t)V * H) / 2048, 256, 0, stream>>>(
      out_w, (unsigned int*)outw8);
  cvt_fp8_kernel<<<(H * H) / 2048, 256, 0, stream>>>(
      Ua_w, (unsigned int*)Uaw8);
  prep_weights<<<5120, 256, 0, stream>>>(Wa_w, gru_w_hh, gru_w_ih,
                                         fusedW, Wemb_bf, Wctx_bf);
  build_fused_bias<<<(4 * H) / 256, 256, 0, stream>>>(Wa_b, gru_b_hh, fusedB);
  embed_all_kernel<<<(T * B * H / 8) / 256, 256, 0, stream>>>(target, embedding,
                                                              embAll);
  cvt_bf16_kernel<<<(B * H) / 2048, 256, 0, stream>>>(enc_hidden, hAll);

  // Uk_f8 = fp8(keys @ Ua_w^T + Ua_b)   (fp8 inputs, fp8 output)
  gemm_fp8<4><<<dim3((B * S) / 128, H / 128), 256, 0, stream>>>(
      keys_f8, Uaw8, Ua_b, nullptr, Uk_f8, nullptr, B * S, H, H, H, 0);
  // giE = embAll @ Wemb^T + b_ih
  gemm_mfma<128, 128, 0, 1, 2>
      <<<dim3((T * B) / 128, 3 * H / 128), 256, 0, stream>>>(
          embAll, Wemb_bf, gru_b_ih, giE, T * B, 3 * H, H, 3 * H);

  const float* h_in = enc_hidden;
  float* hbufs[2] = {hA, hB};

  for (int t = 0; t < T; ++t) {
    const unsigned short* hbf_in = hAll + (size_t)t * B * H;
    unsigned short* hbf_out = hAll + (size_t)(t + 1) * B * H;
    unsigned char* h8_out = hAll8 + (size_t)t * B * H;
    float* h_out = hbufs[t & 1];

    // wq | gh = h @ [Wa_w; w_hh]^T + [Wa_b; b_hh]
    gemm_mfma<64, 64, 0, 1, 5><<<dim3(B / 64, 4 * H / 64), 256, 0, stream>>>(
        hbf_in, fusedW, fusedB, wqgh, B, 4 * H, H, 4 * H);
    attn_fused_kernel<<<B, 256, 0, stream>>>(
        wqgh, Uk_f8, keys_f8, Va_w, Va_b, out_attn, ctx_bf, t);
    // fused: gi = giE[t] + ctx @ Wctx^T  AND  GRU combine -> h (fp32/bf16/fp8)
    gemm_gru3<<<dim3(B / 64, H / 32), 256, 0, stream>>>(
        ctx_bf, Wctx_bf, giE + (size_t)t * B * 3 * H, wqgh, h_in, h_out,
        hbf_out, h8_out);

    h_in = h_out;
  }

  // batched vocab projection over all steps, fp8 e4m3 (2-stage, round-16 best)
  gemm_fp8<3><<<dim3((T * B) / 128, V / 128), 256, 0, stream>>>(
      hAll8, outw8, out_b, logits_bf, nullptr, parts, T * B, V, H, V, 500);
  logsm_reduce_kernel<<<T * B, 256, 0, stream>>>(parts, ls, 500);
  logsm_sub_kernel<<<dim3((V + 2047) / 2048, T * B), 256, 0, stream>>>(
      logits_bf, ls, out_dec);

  copy_kernel<<<(B * H + 255) / 256, 256, 0, stream>>>(h_in, out_h, B * H);
}

// Round 20
// 892.108 us; speedup vs baseline: 2.1850x; 1.0037x over previous
//
#include <hip/hip_runtime.h>
#include <math.h>

#define H 1024
#define V 32000
#define B 256
#define S 64
#define T 10

#define GBK 32

typedef __attribute__((ext_vector_type(8))) short bf16x8;
typedef __attribute__((ext_vector_type(4))) float f32x4;

static __device__ __forceinline__ unsigned short f2bf(float f) {
  unsigned int u = __float_as_uint(f);
  u += 0x7fff + ((u >> 16) & 1);   // round-to-nearest-even
  return (unsigned short)(u >> 16);
}
static __device__ __forceinline__ float bf2f(unsigned short u) {
  return __uint_as_float(((unsigned int)u) << 16);
}
static __device__ __forceinline__ float fast_tanh(float x) {
  float e = __expf(2.f * x);
  return 1.f - 2.f * __builtin_amdgcn_rcpf(e + 1.f);
}
static __device__ __forceinline__ float fast_sigmoid(float x) {
  return __builtin_amdgcn_rcpf(1.f + __expf(-x));
}

static __device__ __forceinline__ void load_lds16(const void* g, void* l) {
  __builtin_amdgcn_global_load_lds(
      (const __attribute__((address_space(1))) unsigned int*)g,
      (__attribute__((address_space(3))) unsigned int*)l, 16, 0, 0);
}

// swizzled element offset within one bf16 LDS tile (row stride 32 elems/64B)
static __device__ __forceinline__ int lds_off(int row, int g) {
  return row * GBK + ((g ^ ((row >> 1) & 3)) * 8);
}

// interleaved fp8 A layout for the vocab GEMM: byte(row, k) lives at
// ((row>>4)*128 + (k>>3))*128 + (row&15)*8 + (k&7)   [K=1024 -> 128 kk]
static __device__ __forceinline__ size_t a8i_off(int row, int k) {
  return ((size_t)(row >> 4) * 128 + (k >> 3)) * 128 + (row & 15) * 8 +
         (k & 7);
}

// ---------------------------------------------------------------------------
// bf16 MFMA GEMM, TMxTN tile, BK=32, 4 waves (2x2), STAGES-deep pipeline.
// MODE 0: C fp32 = acc + bias[col]
// MODE 2: C fp32 = acc + aux[row*ldc + col]
// ---------------------------------------------------------------------------
template <int TM, int TN, int MODE, int GRIDMODE, int STAGES>
__global__ __launch_bounds__(256) void gemm_mfma(
    const unsigned short* __restrict__ A, const unsigned short* __restrict__ W,
    const float* __restrict__ aux, float* __restrict__ C,
    int M, int N, int K, int ldc) {
  constexpr int FM = TM / 32;
  constexpr int FN = TN / 32;
  constexpr int CA = TM / 64;
  constexpr int CB = TN / 64;
  constexpr int LOADS = CA + CB;
  constexpr int F = (STAGES >= 3) ? (STAGES - 2) : 0;

  __shared__ unsigned short lsA[STAGES][TM * GBK];
  __shared__ unsigned short lsB[STAGES][TN * GBK];
  const int tid = threadIdx.x;
  const int lane = tid & 63;
  const int w = tid >> 6;

  int mIdx, nIdx;
  if constexpr (GRIDMODE == 1) {
    const int nwg = gridDim.x * gridDim.y;
    const int orig = blockIdx.y * gridDim.x + blockIdx.x;
    const int q = nwg >> 3, rr = nwg & 7;
    const int xcd = orig & 7, rest = orig >> 3;
    const int wgid =
        (xcd < rr ? xcd * (q + 1) : rr * (q + 1) + (xcd - rr) * q) + rest;
    mIdx = wgid % gridDim.x;
    nIdx = wgid / gridDim.x;
  } else {
    mIdx = blockIdx.y;
    nIdx = blockIdx.x;
  }
  const int mBase = mIdx * TM;
  const int nBase = nIdx * TN;
  const int rowBase = (w >> 1) * (TM / 2);
  const int colBase = (w & 1) * (TN / 2);

  const int fr = lane & 15;
  const int fkU = lane >> 4;
  const int fg = lane >> 4;

  f32x4 acc[FM][FN] = {};

  auto STAGE = [&](int buf, int k0) {
#pragma unroll
    for (int i = 0; i < CA; ++i) {
      int chunk = i * 256 + tid;
      int row = chunk >> 2;
      int u = chunk & 3;
      int col = (u ^ ((row >> 1) & 3)) * 8;
      load_lds16(A + (size_t)(mBase + row) * K + k0 + col,
                 &lsA[buf][chunk * 8]);
    }
#pragma unroll
    for (int i = 0; i < CB; ++i) {
      int chunk = i * 256 + tid;
      int row = chunk >> 2;
      int u = chunk & 3;
      int col = (u ^ ((row >> 1) & 3)) * 8;
      load_lds16(W + (size_t)(nBase + row) * K + k0 + col,
                 &lsB[buf][chunk * 8]);
    }
  };

  const int NT = K / GBK;
  for (int s = 0; s <= F && s < NT; ++s) STAGE(s % STAGES, s * GBK);

  for (int t = 0; t < NT; ++t) {
    const int rem = NT - 1 - t;
    if (rem >= F) {
      asm volatile("s_waitcnt vmcnt(%0)\n\ts_barrier" :: "i"(F * LOADS)
                   : "memory");
    } else if (rem == 2) {
      asm volatile("s_waitcnt vmcnt(%0)\n\ts_barrier" :: "i"(2 * LOADS)
                   : "memory");
    } else if (rem == 1) {
      asm volatile("s_waitcnt vmcnt(%0)\n\ts_barrier" :: "i"(1 * LOADS)
                   : "memory");
    } else {
      asm volatile("s_waitcnt vmcnt(0)\n\ts_barrier" ::: "memory");
    }
    if (t + F + 1 < NT) STAGE((t + F + 1) % STAGES, (t + F + 1) * GBK);

    const int cb = t % STAGES;
    bf16x8 af[FM], bfr[FN];
#pragma unroll
    for (int m = 0; m < FM; ++m)
      af[m] = *(const bf16x8*)&lsA[cb][lds_off(rowBase + m * 16 + fr, fkU)];
#pragma unroll
    for (int n = 0; n < FN; ++n)
      bfr[n] = *(const bf16x8*)&lsB[cb][lds_off(colBase + n * 16 + fr, fkU)];
#pragma unroll
    for (int m = 0; m < FM; ++m)
#pragma unroll
      for (int n = 0; n < FN; ++n)
        acc[m][n] = __builtin_amdgcn_mfma_f32_16x16x32_bf16(
            af[m], bfr[n], acc[m][n], 0, 0, 0);
  }

#pragma unroll
  for (int m = 0; m < FM; ++m) {
    int colg[FN];
    float bv[FN];
#pragma unroll
    for (int n = 0; n < FN; ++n) {
      colg[n] = nBase + colBase + n * 16 + fr;
      if constexpr (MODE != 2) bv[n] = aux[colg[n]];
    }
#pragma unroll
    for (int r = 0; r < 4; ++r) {
      const int rowg = mBase + rowBase + m * 16 + fg * 4 + r;
      float v[FN];
#pragma unroll
      for (int n = 0; n < FN; ++n) {
        if constexpr (MODE == 2)
          v[n] = acc[m][n][r] + aux[(size_t)rowg * ldc + colg[n]];
        else
          v[n] = acc[m][n][r] + bv[n];
        C[(size_t)rowg * ldc + colg[n]] = v[n];
      }
    }
  }
}

// ---------------------------------------------------------------------------
// Fused gi-GEMM + GRU, gate-colocating tile. grid (B/64, H/32) = 128 blocks.
// Writes h fp32 + bf16 + fp8-interleaved (vocab GEMM A layout).
// ---------------------------------------------------------------------------
__global__ __launch_bounds__(256) void gemm_gru3(
    const unsigned short* __restrict__ A,     // ctx_bf [B,H]
    const unsigned short* __restrict__ W3,    // Wctx_bf [3H,H]
    const float* __restrict__ giE_t,          // [B,3H]
    const float* __restrict__ wqgh,           // [B,4H] (gh at +H)
    const float* __restrict__ h_in,           // [B,H]
    float* __restrict__ h_out,                // [B,H]
    unsigned short* __restrict__ h_out_bf,    // [B,H]
    unsigned char* __restrict__ hAll8i,       // interleaved, full M=T*B
    int t) {
  constexpr int BK = 64;
  constexpr int STAGES = 3;
  constexpr int LOADS = 5;
  __shared__ unsigned short lsA[STAGES][64 * BK];
  __shared__ unsigned short lsW[STAGES][96 * BK];
  const int tid = threadIdx.x;
  const int lane = tid & 63;
  const int w = tid >> 6;
  const int mBase = blockIdx.x * 64;
  const int jBase = blockIdx.y * 32;
  const int fr = lane & 15;
  const int fkU = lane >> 4;
  const int fg = lane >> 4;

  f32x4 acc[6] = {};

  auto STAGE = [&](int buf, int k0) {
#pragma unroll
    for (int i = 0; i < 2; ++i) {
      int c = i * 256 + tid;
      int row = c >> 3, u = c & 7;
      int col = (u ^ (row & 7)) * 8;
      load_lds16(A + (size_t)(mBase + row) * H + k0 + col, &lsA[buf][c * 8]);
    }
#pragma unroll
    for (int i = 0; i < 3; ++i) {
      int c = i * 256 + tid;
      int wr = c >> 3, u = c & 7;
      int gate = wr >> 5, jj = wr & 31;
      int col = (u ^ (wr & 7)) * 8;
      load_lds16(W3 + (size_t)(gate * H + jBase + jj) * H + k0 + col,
                 &lsW[buf][c * 8]);
    }
  };

  const int NT = H / BK;
  STAGE(0, 0);
  STAGE(1, BK);
  for (int tt = 0; tt < NT; ++tt) {
    const int rem = NT - 1 - tt;
    if (rem >= 1) {
      asm volatile("s_waitcnt vmcnt(%0)\n\ts_barrier" :: "i"(LOADS)
                   : "memory");
    } else {
      asm volatile("s_waitcnt vmcnt(0)\n\ts_barrier" ::: "memory");
    }
    if (tt + 2 < NT) STAGE((tt + 2) % STAGES, (tt + 2) * BK);
    const int cb = tt % STAGES;
    const int arow = w * 16 + fr;
#pragma unroll
    for (int ks = 0; ks < 2; ++ks) {
      const int u = ks * 4 + fkU;
      bf16x8 af =
          *(const bf16x8*)&lsA[cb][arow * BK + ((u ^ (arow & 7)) * 8)];
#pragma unroll
      for (int n = 0; n < 6; ++n) {
        int wr = n * 16 + fr;
        bf16x8 bf =
            *(const bf16x8*)&lsW[cb][wr * BK + ((u ^ (wr & 7)) * 8)];
        acc[n] = __builtin_amdgcn_mfma_f32_16x16x32_bf16(af, bf, acc[n],
                                                         0, 0, 0);
      }
    }
  }

#pragma unroll
  for (int r = 0; r < 4; ++r) {
    const int b = mBase + w * 16 + fg * 4 + r;
    const int tb = t * B + b;
    const float* giE_row = giE_t + (size_t)b * 3 * H;
    const float* gh_row = wqgh + (size_t)b * 4 * H + H;
#pragma unroll
    for (int jjg = 0; jjg < 2; ++jjg) {
      const int col = jBase + jjg * 16 + fr;
      float gr = acc[0 + jjg][r] + giE_row[col];
      float gz = acc[2 + jjg][r] + giE_row[H + col];
      float gn = acc[4 + jjg][r] + giE_row[2 * H + col];
      float rr = fast_sigmoid(gr + gh_row[col]);
      float zz = fast_sigmoid(gz + gh_row[H + col]);
      float nn = fast_tanh(gn + rr * gh_row[2 * H + col]);
      float hp = h_in[(size_t)b * H + col];
      float ho = (1.f - zz) * nn + zz * hp;
      h_out[(size_t)b * H + col] = ho;
      h_out_bf[(size_t)b * H + col] = f2bf(ho);
      int p8 = __builtin_amdgcn_cvt_pk_fp8_f32(ho, ho, 0, false);
      hAll8i[a8i_off(tb, col)] = (unsigned char)(p8 & 0xff);
    }
  }
}

// ---------------------------------------------------------------------------
// fp8 e4m3 GEMM for Uk (linear A/W). 128x128 tile, BK=64, 2-stage.
// C8 fp8 = acc + bias[col]. XCD swizzle, M fastest.
// ---------------------------------------------------------------------------
__global__ __launch_bounds__(256) void gemm_fp8_uk(
    const unsigned char* __restrict__ A8, const unsigned char* __restrict__ W8,
    const float* __restrict__ bias, unsigned char* __restrict__ C8,
    int M, int N, int K, int ldc) {
  constexpr int BK = 64;
  __shared__ __align__(16) unsigned char lsA[2][128 * BK];
  __shared__ __align__(16) unsigned char lsB[2][128 * BK];
  const int tid = threadIdx.x;
  const int lane = tid & 63;
  const int w = tid >> 6;

  const int nwg = gridDim.x * gridDim.y;
  const int orig = blockIdx.y * gridDim.x + blockIdx.x;
  const int q = nwg >> 3, rr = nwg & 7;
  const int xcd = orig & 7, rest = orig >> 3;
  const int wgid =
      (xcd < rr ? xcd * (q + 1) : rr * (q + 1) + (xcd - rr) * q) + rest;
  const int mIdx = wgid % gridDim.x;
  const int nIdx = wgid / gridDim.x;
  const int mBase = mIdx * 128;
  const int nBase = nIdx * 128;
  const int rowBase = (w >> 1) * 64;
  const int colBase = (w & 1) * 64;
  const int fr = lane & 15;
  const int fkU = lane >> 4;
  const int fg = lane >> 4;

  f32x4 acc[4][4] = {};

  auto STAGE = [&](int buf, int k0) {
#pragma unroll
    for (int i = 0; i < 2; ++i) {
      int c = i * 256 + tid;
      int row = c >> 2;
      int u = c & 3;
      int col = (u ^ ((row >> 1) & 3)) * 16;
      load_lds16(A8 + (size_t)(mBase + row) * K + k0 + col, &lsA[buf][c * 16]);
    }
#pragma unroll
    for (int i = 0; i < 2; ++i) {
      int c = i * 256 + tid;
      int row = c >> 2;
      int u = c & 3;
      int col = (u ^ ((row >> 1) & 3)) * 16;
      load_lds16(W8 + (size_t)(nBase + row) * K + k0 + col, &lsB[buf][c * 16]);
    }
  };

  const int NT = K / BK;
  STAGE(0, 0);
  int cb = 0;
  for (int t = 0; t < NT; ++t) {
    asm volatile("s_waitcnt vmcnt(0)\n\ts_barrier" ::: "memory");
    if (t + 1 < NT) STAGE(cb ^ 1, (t + 1) * BK);
#pragma unroll
    for (int ks = 0; ks < 2; ++ks) {
      const int u = ks * 2 + (fkU >> 1);
      const int sub = (fkU & 1) * 8;
      long long af[4], bf[4];
#pragma unroll
      for (int m = 0; m < 4; ++m) {
        int row = rowBase + m * 16 + fr;
        af[m] = *(const long long*)
            &lsA[cb][row * BK + ((u ^ ((row >> 1) & 3)) << 4) + sub];
      }
#pragma unroll
      for (int n = 0; n < 4; ++n) {
        int row = colBase + n * 16 + fr;
        bf[n] = *(const long long*)
            &lsB[cb][row * BK + ((u ^ ((row >> 1) & 3)) << 4) + sub];
      }
#pragma unroll
      for (int m = 0; m < 4; ++m)
#pragma unroll
        for (int n = 0; n < 4; ++n)
          acc[m][n] = __builtin_amdgcn_mfma_f32_16x16x32_fp8_fp8(
              af[m], bf[n], acc[m][n], 0, 0, 0);
    }
    cb ^= 1;
  }

#pragma unroll
  for (int m = 0; m < 4; ++m) {
#pragma unroll
    for (int r = 0; r < 4; ++r) {
      const int rowg = mBase + rowBase + m * 16 + fg * 4 + r;
#pragma unroll
      for (int n = 0; n < 4; ++n) {
        const int colg = nBase + colBase + n * 16 + fr;
        float v = acc[m][n][r] + bias[colg];
        int pk = __builtin_amdgcn_cvt_pk_fp8_f32(v, v, 0, false);
        C8[(size_t)rowg * ldc + colg] = (unsigned char)(pk & 0xff);
      }
    }
  }
}

// ---------------------------------------------------------------------------
// fp8 vocab GEMM, A in REGISTERS (coalesced loads from interleaved layout),
// LDS stages only W -> halves LDS reads per K-step (the measured bottleneck).
// 128x128 tile, BK=64, 2-stage W staging, 2x-unrolled K loop with
// double-buffered A registers (afA/afB, static indexing only).
// Writes bf16 logits + per-row (max,sumexp) partials.
// ---------------------------------------------------------------------------
__global__ __launch_bounds__(256) void gemm_fp8_vocab(
    const unsigned char* __restrict__ A8i, const unsigned char* __restrict__ W8,
    const float* __restrict__ bias, unsigned short* __restrict__ Cb,
    float* __restrict__ partials, int M, int N, int K, int ldc, int pstride) {
  constexpr int BK = 64;
  __shared__ __align__(16) unsigned char lsB[2][128 * BK];
  const int tid = threadIdx.x;
  const int lane = tid & 63;
  const int w = tid >> 6;

  const int nwg = gridDim.x * gridDim.y;
  const int orig = blockIdx.y * gridDim.x + blockIdx.x;
  const int q = nwg >> 3, rr = nwg & 7;
  const int xcd = orig & 7, rest = orig >> 3;
  const int wgid =
      (xcd < rr ? xcd * (q + 1) : rr * (q + 1) + (xcd - rr) * q) + rest;
  const int mIdx = wgid % gridDim.x;
  const int nIdx = wgid / gridDim.x;
  const int mBase = mIdx * 128;
  const int nBase = nIdx * 128;
  const int rowBase = (w >> 1) * 64;
  const int colBase = (w & 1) * 64;
  const int fr = lane & 15;
  const int fkU = lane >> 4;
  const int fg = lane >> 4;
  const int mtile = (mBase + rowBase) >> 4;   // A row-tile base for this wave

  f32x4 acc[4][4] = {};

  auto STAGE_W = [&](int buf, int k0) {
#pragma unroll
    for (int i = 0; i < 2; ++i) {
      int c = i * 256 + tid;
      int row = c >> 2;
      int u = c & 3;
      int col = (u ^ ((row >> 1) & 3)) * 16;
      load_lds16(W8 + (size_t)(nBase + row) * K + k0 + col, &lsB[buf][c * 16]);
    }
  };

  long long afA[2][4], afB[2][4];
  // loadA: af[ks][m] = A8i bytes for row mtile+m (lane fr), kk-block
  auto LOADA_A = [&](int k0) {
#pragma unroll
    for (int ks = 0; ks < 2; ++ks) {
      const int kk = (k0 >> 3) + ks * 4 + fkU;
#pragma unroll
      for (int m = 0; m < 4; ++m)
        afA[ks][m] = *(const long long*)
            &A8i[((size_t)(mtile + m) * 128 + kk) * 128 + fr * 8];
    }
  };
  auto LOADA_B = [&](int k0) {
#pragma unroll
    for (int ks = 0; ks < 2; ++ks) {
      const int kk = (k0 >> 3) + ks * 4 + fkU;
#pragma unroll
      for (int m = 0; m < 4; ++m)
        afB[ks][m] = *(const long long*)
            &A8i[((size_t)(mtile + m) * 128 + kk) * 128 + fr * 8];
    }
  };

  const int NT = K / BK;   // 16 (even)
  LOADA_A(0);
  STAGE_W(0, 0);
  for (int t = 0; t < NT; t += 2) {
    // ---- sub-step t: compute with afA + lsB[0]
    asm volatile("s_waitcnt vmcnt(0)\n\ts_barrier" ::: "memory");
    if (t + 1 < NT) {
      STAGE_W(1, (t + 1) * BK);
      LOADA_B((t + 1) * BK);
    }
#pragma unroll
    for (int ks = 0; ks < 2; ++ks) {
      const int u = ks * 2 + (fkU >> 1);
      const int sub = (fkU & 1) * 8;
      long long bf[4];
#pragma unroll
      for (int n = 0; n < 4; ++n) {
        int row = colBase + n * 16 + fr;
        bf[n] = *(const long long*)
            &lsB[0][row * BK + ((u ^ ((row >> 1) & 3)) << 4) + sub];
      }
#pragma unroll
      for (int m = 0; m < 4; ++m)
#pragma unroll
        for (int n = 0; n < 4; ++n)
          acc[m][n] = __builtin_amdgcn_mfma_f32_16x16x32_fp8_fp8(
              afA[ks][m], bf[n], acc[m][n], 0, 0, 0);
    }
    // ---- sub-step t+1: compute with afB + lsB[1]
    asm volatile("s_waitcnt vmcnt(0)\n\ts_barrier" ::: "memory");
    if (t + 2 < NT) {
      STAGE_W(0, (t + 2) * BK);
      LOADA_A((t + 2) * BK);
    }
#pragma unroll
    for (int ks = 0; ks < 2; ++ks) {
      const int u = ks * 2 + (fkU >> 1);
      const int sub = (fkU & 1) * 8;
      long long bf[4];
#pragma unroll
      for (int n = 0; n < 4; ++n) {
        int row = colBase + n * 16 + fr;
        bf[n] = *(const long long*)
            &lsB[1][row * BK + ((u ^ ((row >> 1) & 3)) << 4) + sub];
      }
#pragma unroll
      for (int m = 0; m < 4; ++m)
#pragma unroll
        for (int n = 0; n < 4; ++n)
          acc[m][n] = __builtin_amdgcn_mfma_f32_16x16x32_fp8_fp8(
              afB[ks][m], bf[n], acc[m][n], 0, 0, 0);
    }
  }

#pragma unroll
  for (int m = 0; m < 4; ++m) {
    int colg[4];
    float bv[4];
#pragma unroll
    for (int n = 0; n < 4; ++n) {
      colg[n] = nBase + colBase + n * 16 + fr;
      bv[n] = bias[colg[n]];
    }
#pragma unroll
    for (int r = 0; r < 4; ++r) {
      const int rowg = mBase + rowBase + m * 16 + fg * 4 + r;
      float v[4];
#pragma unroll
      for (int n = 0; n < 4; ++n) {
        v[n] = acc[m][n][r] + bv[n];
        Cb[(size_t)rowg * ldc + colg[n]] = f2bf(v[n]);
      }
      float mx = fmaxf(fmaxf(v[0], v[1]), fmaxf(v[2], v[3]));
      mx = fmaxf(mx, __shfl_xor(mx, 1, 64));
      mx = fmaxf(mx, __shfl_xor(mx, 2, 64));
      mx = fmaxf(mx, __shfl_xor(mx, 4, 64));
      mx = fmaxf(mx, __shfl_xor(mx, 8, 64));
      float se = __expf(v[0] - mx) + __expf(v[1] - mx) +
                 __expf(v[2] - mx) + __expf(v[3] - mx);
      se += __shfl_xor(se, 1, 64);
      se += __shfl_xor(se, 2, 64);
      se += __shfl_xor(se, 4, 64);
      se += __shfl_xor(se, 8, 64);
      if (fr == 0) {
        float2* pp = (float2*)partials;
        pp[(size_t)rowg * pstride + nIdx * 2 + (w & 1)] = make_float2(mx, se);
      }
    }
  }
}

// ---------------------------------------------------------------------------
static __device__ __forceinline__ void cvt8(const float* src,
                                            unsigned short* dst, size_t i) {
  float4 a = *(const float4*)&src[i];
  float4 b = *(const float4*)&src[i + 4];
  ushort4 lo, hi;
  lo.x = f2bf(a.x); lo.y = f2bf(a.y); lo.z = f2bf(a.z); lo.w = f2bf(a.w);
  hi.x = f2bf(b.x); hi.y = f2bf(b.y); hi.z = f2bf(b.z); hi.w = f2bf(b.w);
  *(ushort4*)&dst[i] = lo;
  *(ushort4*)&dst[i + 4] = hi;
}

__global__ __launch_bounds__(256) void cvt_bf16_kernel(
    const float* __restrict__ src, unsigned short* __restrict__ dst) {
  cvt8(src, dst, ((size_t)blockIdx.x * 256 + threadIdx.x) * 8);
}

// weight converts in one launch:
// [0,512): Wa_w -> fusedW; [512,2048): w_hh -> fusedW+H*H;
// [2048,5120): w_ih split -> Wemb/Wctx
__global__ __launch_bounds__(256) void prep_weights(
    const float* __restrict__ Wa_w, const float* __restrict__ w_hh,
    const float* __restrict__ w_ih, unsigned short* __restrict__ fusedW,
    unsigned short* __restrict__ Wemb, unsigned short* __restrict__ Wctx) {
  const int blk = blockIdx.x;
  if (blk < 512) {
    cvt8(Wa_w, fusedW, ((size_t)blk * 256 + threadIdx.x) * 8);
  } else if (blk < 2048) {
    cvt8(w_hh, fusedW + (size_t)H * H,
         ((size_t)(blk - 512) * 256 + threadIdx.x) * 8);
  } else {
    size_t base = ((size_t)(blk - 2048) * 256 + threadIdx.x) * 8;
    int row = (int)(base >> 11);
    int col = (int)(base & 2047);
    float4 a = *(const float4*)&w_ih[base];
    float4 b = *(const float4*)&w_ih[base + 4];
    ushort4 lo, hi;
    lo.x = f2bf(a.x); lo.y = f2bf(a.y); lo.z = f2bf(a.z); lo.w = f2bf(a.w);
    hi.x = f2bf(b.x); hi.y = f2bf(b.y); hi.z = f2bf(b.z); hi.w = f2bf(b.w);
    unsigned short* dst = (col < H) ? (Wemb + (size_t)row * H + col)
                                    : (Wctx + (size_t)row * H + col - H);
    *(ushort4*)dst = lo;
    *(ushort4*)(dst + 4) = hi;
  }
}

// fp32 -> fp8 e4m3, 8 elems/thread
__global__ __launch_bounds__(256) void cvt_fp8_kernel(
    const float* __restrict__ src, unsigned int* __restrict__ dst) {
  size_t i = (size_t)blockIdx.x * 256 + threadIdx.x;
  float4 a = ((const float4*)src)[i * 2];
  float4 b = ((const float4*)src)[i * 2 + 1];
  int lo = __builtin_amdgcn_cvt_pk_fp8_f32(a.x, a.y, 0, false);
  lo = __builtin_amdgcn_cvt_pk_fp8_f32(a.z, a.w, lo, true);
  int hi = __builtin_amdgcn_cvt_pk_fp8_f32(b.x, b.y, 0, false);
  hi = __builtin_amdgcn_cvt_pk_fp8_f32(b.z, b.w, hi, true);
  ((int2*)dst)[i] = make_int2(lo, hi);
}

__global__ __launch_bounds__(256) void build_fused_bias(
    const float* __restrict__ Wa_b, const float* __restrict__ b_hh,
    float* __restrict__ fb) {
  int i = blockIdx.x * 256 + threadIdx.x;
  fb[i] = (i < H) ? Wa_b[i] : b_hh[i - H];
}

__global__ __launch_bounds__(256) void embed_all_kernel(
    const int* __restrict__ target, const float* __restrict__ emb,
    unsigned short* __restrict__ embAll) {
  int idx = blockIdx.x * 256 + threadIdx.x;
  int h8 = (idx & 127) * 8;
  int tb = idx >> 7;
  int t = tb >> 8;
  int b = tb & 255;
  int tok = (t == 0) ? 0 : target[b * T + (t - 1)];
  const float* e = emb + (size_t)tok * H + h8;
  float4 a = *(const float4*)e;
  float4 c = *(const float4*)(e + 4);
  ushort4 lo, hi;
  lo.x = f2bf(a.x); lo.y = f2bf(a.y); lo.z = f2bf(a.z); lo.w = f2bf(a.w);
  hi.x = f2bf(c.x); hi.y = f2bf(c.y); hi.z = f2bf(c.z); hi.w = f2bf(c.w);
  unsigned short* d = embAll + (size_t)tb * H + h8;
  *(ushort4*)d = lo;
  *(ushort4*)(d + 4) = hi;
}

// ---------------------------------------------------------------------------
// Fused attention: scores -> softmax -> ctx, one block per b. fp8 Uk/keys.
// ---------------------------------------------------------------------------
__global__ __launch_bounds__(256) void attn_fused_kernel(
    const float* __restrict__ wqgh, const unsigned char* __restrict__ Uk_f8,
    const unsigned char* __restrict__ keys_f8,
    const float* __restrict__ Va_w, const float* __restrict__ Va_b,
    float* __restrict__ out_attn, unsigned short* __restrict__ ctx_bf, int t) {
  const int b = blockIdx.x;
  const int tid = threadIdx.x;
  __shared__ float wqs[H];
  __shared__ float vas[H];
  __shared__ float sw[S];

  ((float4*)wqs)[tid] = ((const float4*)(wqgh + (size_t)b * 4 * H))[tid];
  ((float4*)vas)[tid] = ((const float4*)Va_w)[tid];
  __syncthreads();

  const int s = tid >> 2;
  const int hc = (tid & 3) * 256;
  const unsigned char* uk = Uk_f8 + ((size_t)b * S + s) * H + hc;
  float sum = 0.f;
#pragma unroll 4
  for (int i = 0; i < 256; i += 8) {
    uint2 u = *(const uint2*)&uk[i];
    float uv[8];
    uv[0] = __builtin_amdgcn_cvt_f32_fp8(u.x, 0);
    uv[1] = __builtin_amdgcn_cvt_f32_fp8(u.x, 1);
    uv[2] = __builtin_amdgcn_cvt_f32_fp8(u.x, 2);
    uv[3] = __builtin_amdgcn_cvt_f32_fp8(u.x, 3);
    uv[4] = __builtin_amdgcn_cvt_f32_fp8(u.y, 0);
    uv[5] = __builtin_amdgcn_cvt_f32_fp8(u.y, 1);
    uv[6] = __builtin_amdgcn_cvt_f32_fp8(u.y, 2);
    uv[7] = __builtin_amdgcn_cvt_f32_fp8(u.y, 3);
#pragma unroll
    for (int j = 0; j < 8; ++j) {
      float e = fast_tanh(wqs[hc + i + j] + uv[j]);
      sum += e * vas[hc + i + j];
    }
  }
  sum += __shfl_xor(sum, 1, 64);
  sum += __shfl_xor(sum, 2, 64);
  if ((tid & 3) == 0) sw[s] = sum + Va_b[0];
  __syncthreads();

  if (tid < 64) {
    float v = sw[tid];
    float m = v;
    for (int off = 32; off > 0; off >>= 1) m = fmaxf(m, __shfl_xor(m, off, 64));
    float e = __expf(v - m);
    float sm = e;
    for (int off = 32; off > 0; off >>= 1) sm += __shfl_xor(sm, off, 64);
    float wv = e / sm;
    sw[tid] = wv;
    out_attn[((size_t)b * T + t) * S + tid] = wv;
  }
  __syncthreads();

  const unsigned char* kb = keys_f8 + (size_t)b * S * H + tid * 4;
  float c0 = 0.f, c1 = 0.f, c2 = 0.f, c3 = 0.f;
#pragma unroll 8
  for (int s2 = 0; s2 < S; ++s2) {
    float wv = sw[s2];
    unsigned int kv = *(const unsigned int*)&kb[(size_t)s2 * H];
    c0 += wv * __builtin_amdgcn_cvt_f32_fp8(kv, 0);
    c1 += wv * __builtin_amdgcn_cvt_f32_fp8(kv, 1);
    c2 += wv * __builtin_amdgcn_cvt_f32_fp8(kv, 2);
    c3 += wv * __builtin_amdgcn_cvt_f32_fp8(kv, 3);
  }
  ushort4 o;
  o.x = f2bf(c0); o.y = f2bf(c1); o.z = f2bf(c2); o.w = f2bf(c3);
  *(ushort4*)&ctx_bf[(size_t)b * H + tid * 4] = o;
}

// ---------------------------------------------------------------------------
// batched log-softmax: reduce partials -> ls[row] for all T*B rows
// ---------------------------------------------------------------------------
__global__ __launch_bounds__(256) void logsm_reduce_kernel(
    const float* __restrict__ partials, float* __restrict__ ls, int P) {
  const int row = blockIdx.x;
  const int tid = threadIdx.x;
  const float2* pp = (const float2*)partials + (size_t)row * P;
  __shared__ float red[256];
  float mx = -INFINITY;
  for (int i = tid; i < P; i += 256) mx = fmaxf(mx, pp[i].x);
  red[tid] = mx;
  __syncthreads();
  for (int off = 128; off > 0; off >>= 1) {
    if (tid < off) red[tid] = fmaxf(red[tid], red[tid + off]);
    __syncthreads();
  }
  mx = red[0];
  __syncthreads();
  float sm = 0.f;
  for (int i = tid; i < P; i += 256) sm += pp[i].y * __expf(pp[i].x - mx);
  red[tid] = sm;
  __syncthreads();
  for (int off = 128; off > 0; off >>= 1) {
    if (tid < off) red[tid] += red[tid + off];
    __syncthreads();
  }
  if (tid == 0) ls[row] = mx + __logf(red[0]);
}

// dec[b, t, :] = bf2f(logits_bf[tb, :]) - ls[tb];  tb = t*B + b
__global__ __launch_bounds__(256) void logsm_sub_kernel(
    const unsigned short* __restrict__ logits_bf, const float* __restrict__ ls,
    float* __restrict__ dec) {
  const int tb = blockIdx.y;
  const int t = tb >> 8;
  const int b = tb & 255;
  const int i8 = (blockIdx.x * 256 + threadIdx.x) * 8;
  if (i8 < V) {
    float l = ls[tb];
    const unsigned short* src = logits_bf + (size_t)tb * V + i8;
    bf16x8 u = *(const bf16x8*)src;
    float* d = dec + (size_t)b * T * V + (size_t)t * V + i8;
    float4 o0, o1;
    o0.x = bf2f((unsigned short)u[0]) - l; o0.y = bf2f((unsigned short)u[1]) - l;
    o0.z = bf2f((unsigned short)u[2]) - l; o0.w = bf2f((unsigned short)u[3]) - l;
    o1.x = bf2f((unsigned short)u[4]) - l; o1.y = bf2f((unsigned short)u[5]) - l;
    o1.z = bf2f((unsigned short)u[6]) - l; o1.w = bf2f((unsigned short)u[7]) - l;
    *(float4*)d = o0;
    *(float4*)(d + 4) = o1;
  }
}

__global__ __launch_bounds__(256) void copy_kernel(
    const float* __restrict__ src, float* __restrict__ dst, int n) {
  int i = blockIdx.x * 256 + threadIdx.x;
  if (i < n) dst[i] = src[i];
}

// ---------------------------------------------------------------------------
extern "C" void kernel_launch(void* const* d_in, const int* in_sizes, int n_in,
                              void* d_out, int out_size, void* d_ws, size_t ws_size,
                              hipStream_t stream) {
  const float* keys       = (const float*)d_in[0];
  const float* enc_hidden = (const float*)d_in[1];
  const int*   target     = (const int*)d_in[2];
  const float* embedding  = (const float*)d_in[3];
  const float* Wa_w = (const float*)d_in[4];
  const float* Wa_b = (const float*)d_in[5];
  const float* Ua_w = (const float*)d_in[6];
  const float* Ua_b = (const float*)d_in[7];
  const float* Va_w = (const float*)d_in[8];
  const float* Va_b = (const float*)d_in[9];
  const float* gru_w_ih = (const float*)d_in[10];
  const float* gru_w_hh = (const float*)d_in[11];
  const float* gru_b_ih = (const float*)d_in[12];
  const float* gru_b_hh = (const float*)d_in[13];
  const float* out_w = (const float*)d_in[14];
  const float* out_b = (const float*)d_in[15];

  float* out = (float*)d_out;
  float* out_dec  = out;
  float* out_h    = out + (size_t)B * T * V;
  float* out_attn = out + (size_t)B * T * V + (size_t)B * H;

  // ---- workspace ----
  char* p = (char*)d_ws;
  unsigned char*  keys_f8 = (unsigned char*)p;  p += (size_t)B * S * H;
  unsigned char*  outw8   = (unsigned char*)p;  p += (size_t)V * H;
  unsigned char*  Uaw8    = (unsigned char*)p;  p += (size_t)H * H;
  unsigned short* fusedW  = (unsigned short*)p; p += (size_t)4 * H * H * 2;
  float*          fusedB  = (float*)p;          p += (size_t)4 * H * 4;
  unsigned short* Wemb_bf = (unsigned short*)p; p += (size_t)3 * H * H * 2;
  unsigned short* Wctx_bf = (unsigned short*)p; p += (size_t)3 * H * H * 2;
  unsigned short* embAll  = (unsigned short*)p; p += (size_t)T * B * H * 2;
  unsigned char*  Uk_f8   = (unsigned char*)p;  p += (size_t)B * S * H;
  float*          giE     = (float*)p;          p += (size_t)T * B * 3 * H * 4;
  float*          wqgh    = (float*)p;          p += (size_t)B * 4 * H * 4;
  unsigned short* ctx_bf  = (unsigned short*)p; p += (size_t)B * H * 2;
  float*          hA      = (float*)p;          p += (size_t)B * H * 4;
  float*          hB      = (float*)p;          p += (size_t)B * H * 4;
  unsigned short* hAll    = (unsigned short*)p; p += (size_t)(T + 1) * B * H * 2;
  unsigned char*  hAll8i  = (unsigned char*)p;  p += (size_t)T * B * H;  // interleaved
  unsigned short* logits_bf = (unsigned short*)p; p += (size_t)T * B * V * 2;
  float*          parts   = (float*)p;          p += (size_t)T * B * 500 * 2 * 4;
  float*          ls      = (float*)p;          p += (size_t)T * B * 4;

  // ---- one-time prep ----
  cvt_fp8_kernel<<<(B * S * H) / 2048, 256, 0, stream>>>(
      keys, (unsigned int*)keys_f8);
  cvt_fp8_kernel<<<((size_t)V * H) / 2048, 256, 0, stream>>>(
      out_w, (unsigned int*)outw8);
  cvt_fp8_kernel<<<(H * H) / 2048, 256, 0, stream>>>(
      Ua_w, (unsigned int*)Uaw8);
  prep_weights<<<5120, 256, 0, stream>>>(Wa_w, gru_w_hh, gru_w_ih,
                                         fusedW, Wemb_bf, Wctx_bf);
  build_fused_bias<<<(4 * H) / 256, 256, 0, stream>>>(Wa_b, gru_b_hh, fusedB);
  embed_all_kernel<<<(T * B * H / 8) / 256, 256, 0, stream>>>(target, embedding,
                                                              embAll);
  cvt_bf16_kernel<<<(B * H) / 2048, 256, 0, stream>>>(enc_hidden, hAll);

  // Uk_f8 = fp8(keys @ Ua_w^T + Ua_b)
  gemm_fp8_uk<<<dim3((B * S) / 128, H / 128), 256, 0, stream>>>(
      keys_f8, Uaw8, Ua_b, Uk_f8, B * S, H, H, H);
  // giE = embAll @ Wemb^T + b_ih
  gemm_mfma<128, 128, 0, 1, 2>
      <<<dim3((T * B) / 128, 3 * H / 128), 256, 0, stream>>>(
          embAll, Wemb_bf, gru_b_ih, giE, T * B, 3 * H, H, 3 * H);

  const float* h_in = enc_hidden;
  float* hbufs[2] = {hA, hB};

  for (int t = 0; t < T; ++t) {
    const unsigned short* hbf_in = hAll + (size_t)t * B * H;
    unsigned short* hbf_out = hAll + (size_t)(t + 1) * B * H;
    float* h_out = hbufs[t & 1];

    // wq | gh = h @ [Wa_w; w_hh]^T + [Wa_b; b_hh]
    gemm_mfma<64, 64, 0, 1, 5><<<dim3(B / 64, 4 * H / 64), 256, 0, stream>>>(
        hbf_in, fusedW, fusedB, wqgh, B, 4 * H, H, 4 * H);
    attn_fused_kernel<<<B, 256, 0, stream>>>(
        wqgh, Uk_f8, keys_f8, Va_w, Va_b, out_attn, ctx_bf, t);
    // fused: gi = giE[t] + ctx @ Wctx^T  AND  GRU -> h (fp32/bf16/fp8-interlv)
    gemm_gru3<<<dim3(B / 64, H / 32), 256, 0, stream>>>(
        ctx_bf, Wctx_bf, giE + (size_t)t * B * 3 * H, wqgh, h_in, h_out,
        hbf_out, hAll8i, t);

    h_in = h_out;
  }

  // batched vocab projection: A in registers (interleaved layout), W in LDS
  gemm_fp8_vocab<<<dim3((T * B) / 128, V / 128), 256, 0, stream>>>(
      hAll8i, outw8, out_b, logits_bf, parts, T * B, V, H, V, 500);
  logsm_reduce_kernel<<<T * B, 256, 0, stream>>>(parts, ls, 500);
  logsm_sub_kernel<<<dim3((V + 2047) / 2048, T * B), 256, 0, stream>>>(
      logits_bf, ls, out_dec);

  copy_kernel<<<(B * H + 255) / 256, 256, 0, stream>>>(h_in, out_h, B * H);
}